// Round 13
// baseline (662.084 us; speedup 1.0000x reference)
//
#include <hip/hip_runtime.h>
#include <math.h>

// ---------------- workspace layout (float indices) ----------------
#define WS_OFF_U     0
#define WS_OFF_T     4096
#define WS_OFF_TN    6400
#define WS_OFF_S2    6408
#define WS_OFF_BBOX  6416
#define WS_OFF_W     8192
#define WS_OFF_C     3152896  // out_8 normalized (2,097,152)
#define WS_OFF_D     5250048  // out_16 normalized (1,048,576)

// ---------------- d_out layout (float offsets) ----------------
#define OUT_X    0          // 8*2048*8*8     = 1,048,576
#define OUT_X1   1048576    // 8*2048*18*18   = 5,308,416
#define OUT_X2   6356992    // 8*2048*34*34   = 18,939,904 (hosts bufA/bufB scratch)
#define OUT_IMG  25296896   // 8*24*256*256   = 12,582,912

struct Ptr6 { const float* p[6]; };

typedef short s16x8 __attribute__((ext_vector_type(8)));
typedef float f32x4 __attribute__((ext_vector_type(4)));
typedef unsigned int u32x4 __attribute__((ext_vector_type(4)));

// =================== parallel MT19937 + Marsaglia polar (numpy RandomState) ===================
#define MT_UP 0x80000000u
#define MT_LO 0x7fffffffu

__global__ __launch_bounds__(256) void gen_u_par(float* ws){
  const int os[6]   = {64,128,256,512,1024,2048};
  const int uoff[6] = {0,64,192,448,960,1984};
  int l = blockIdx.x;
  int n = os[l];
  int tid = threadIdx.x;

  __shared__ unsigned mt[624];
  __shared__ unsigned draws[8192];
  __shared__ float px[2048], py[2048];
  __shared__ unsigned char accf[2048];
  __shared__ int scan[256];

  if (tid == 0){
    unsigned seed = (unsigned)(l + 1);
    for (int i = 0; i < 624; i++){
      mt[i] = seed;
      seed = 1812433253u * (seed ^ (seed >> 30)) + (unsigned)(i + 1);
    }
  }
  __syncthreads();

  int need = 4 * n;
  int twists = (need + 623) / 624;
  for (int t = 0; t < twists; t++){
    unsigned yA = 0, vA = 0;
    if (tid < 227){ yA = (mt[tid] & MT_UP) | (mt[tid+1] & MT_LO); vA = mt[tid+397]; }
    __syncthreads();
    if (tid < 227){ mt[tid] = vA ^ (yA >> 1) ^ ((yA & 1u) ? 0x9908b0dfu : 0u); }
    __syncthreads();
    unsigned yB = 0, vB = 0; int iB = 227 + tid;
    if (tid < 227){ yB = (mt[iB] & MT_UP) | (mt[iB+1] & MT_LO); vB = mt[iB-227]; }
    __syncthreads();
    if (tid < 227){ mt[iB] = vB ^ (yB >> 1) ^ ((yB & 1u) ? 0x9908b0dfu : 0u); }
    __syncthreads();
    unsigned yC = 0, vC = 0; int iC = 454 + tid;
    if (tid < 169){ yC = (mt[iC] & MT_UP) | (mt[iC+1] & MT_LO); vC = mt[iC-227]; }
    __syncthreads();
    if (tid < 169){ mt[iC] = vC ^ (yC >> 1) ^ ((yC & 1u) ? 0x9908b0dfu : 0u); }
    __syncthreads();
    if (tid == 0){
      unsigned y = (mt[623] & MT_UP) | (mt[0] & MT_LO);
      mt[623] = mt[396] ^ (y >> 1) ^ ((y & 1u) ? 0x9908b0dfu : 0u);
    }
    __syncthreads();
    for (int i = tid; i < 624; i += 256){
      int pos = t * 624 + i;
      if (pos < need){
        unsigned y = mt[i];
        y ^= y >> 11; y ^= (y << 7) & 0x9d2c5680u; y ^= (y << 15) & 0xefc60000u; y ^= y >> 18;
        draws[pos] = y;
      }
    }
    __syncthreads();
  }

  int A = (n + 255) / 256;
  int local = 0;
  for (int a = 0; a < A; a++){
    int k = tid * A + a;
    if (k < n){
      double u1 = ((draws[4*k]   >> 5) * 67108864.0 + (draws[4*k+1] >> 6)) / 9007199254740992.0;
      double u2 = ((draws[4*k+2] >> 5) * 67108864.0 + (draws[4*k+3] >> 6)) / 9007199254740992.0;
      double x1 = 2.0*u1 - 1.0, x2 = 2.0*u2 - 1.0;
      double r2 = x1*x1 + x2*x2;
      int ok = (r2 < 1.0 && r2 != 0.0);
      accf[k] = (unsigned char)ok;
      if (ok){
        double f = sqrt(-2.0 * log(r2) / r2);
        px[k] = (float)(f * x2);
        py[k] = (float)(f * x1);
      }
      local += ok;
    }
  }
  scan[tid] = local;
  __syncthreads();
  if (tid == 0){
    int run = 0;
    for (int i = 0; i < 256; i++){ int c = scan[i]; scan[i] = run; run += c; }
  }
  __syncthreads();
  int j = scan[tid];
  float* u = ws + WS_OFF_U + uoff[l];
  for (int a = 0; a < A; a++){
    int k = tid * A + a;
    if (k < n && accf[k]){
      if (2*j + 1 < n){ u[2*j] = px[k]; u[2*j+1] = py[k]; }
      j++;
    }
  }
}

// =================== spectral norm: t = M^T u ===================
__global__ __launch_bounds__(256) void sn_t_kernel(Ptr6 wp, float* ws){
  const int cols[6] = {27,72,144,288,576,1152};
  const int uoff[6] = {0,64,192,448,960,1984};
  const int toff[6] = {0,27,99,243,531,1107};
  const int cstart[7] = {0,4,12,28,60,124,252};   // 16-row chunks per layer
  int b = blockIdx.x;
  int l = 0; while (l < 5 && b >= cstart[l+1]) l++;
  int chunk = b - cstart[l];
  int r0 = chunk * 16;
  int C = cols[l];
  const float* m = wp.p[l];
  const float* u = ws + WS_OFF_U + uoff[l];
  float* t = ws + WS_OFF_T + toff[l];
  __shared__ float us[16];
  if (threadIdx.x < 16) us[threadIdx.x] = u[r0 + threadIdx.x];
  __syncthreads();
  for (int j = threadIdx.x; j < C; j += 256){
    float acc = 0.f;
    #pragma unroll
    for (int r = 0; r < 16; r++) acc += m[(size_t)(r0 + r) * C + j] * us[r];
    atomicAdd(&t[j], acc);
  }
}

__global__ void sn_tn_kernel(float* ws){
  const int cols[6] = {27,72,144,288,576,1152};
  const int toff[6] = {0,27,99,243,531,1107};
  int l = blockIdx.x;
  const float* t = ws + WS_OFF_T + toff[l];
  float s = 0.f;
  for (int j = threadIdx.x; j < cols[l]; j += 256){ float v = t[j]; s += v*v; }
  __shared__ float sb[4];
  int lane = threadIdx.x & 63, wid = threadIdx.x >> 6;
  for (int o = 32; o; o >>= 1) s += __shfl_down(s, o, 64);
  if (lane == 0) sb[wid] = s;
  __syncthreads();
  if (threadIdx.x == 0) ws[WS_OFF_TN + l] = sb[0] + sb[1] + sb[2] + sb[3];
}

// =================== spectral norm: s2 += ||M t||^2, wave-per-row ===================
__global__ __launch_bounds__(256) void sn_z_kernel(Ptr6 wp, float* ws){
  const int cols[6] = {27,72,144,288,576,1152};
  const int toff[6] = {0,27,99,243,531,1107};
  const int rstart[7] = {0,64,192,448,960,1984,4032};
  __shared__ float part[6];
  if (threadIdx.x < 6) part[threadIdx.x] = 0.f;
  __syncthreads();
  int gr = blockIdx.x * 4 + (threadIdx.x >> 6);
  int lane = threadIdx.x & 63;
  if (gr < 4032){
    int l = 0; while (l < 5 && gr >= rstart[l+1]) l++;
    int row = gr - rstart[l];
    int C = cols[l];
    const float* m = wp.p[l] + (size_t)row * C;
    const float* t = ws + WS_OFF_T + toff[l];
    float acc = 0.f;
    for (int c = lane; c < C; c += 64) acc += m[c] * t[c];
    for (int o = 32; o; o >>= 1) acc += __shfl_down(acc, o, 64);
    if (lane == 0) atomicAdd(&part[l], acc * acc);
  }
  __syncthreads();
  if (threadIdx.x < 6 && part[threadIdx.x] != 0.f)
    atomicAdd(&ws[WS_OFF_S2 + threadIdx.x], part[threadIdx.x]);
}

__global__ void wscale_kernel(const float* __restrict__ src, float* __restrict__ dst,
                              int n, const float* __restrict__ tn, const float* __restrict__ s2){
  int i = blockIdx.x * 256 + threadIdx.x;
  if (i >= n) return;
  float inv = sqrtf(tn[0] / s2[0]);
  dst[i] = src[i] * inv;
}

// =================== crop/resize bbox (2-stage, 512-block streaming) ===================
__global__ __launch_bounds__(256) void bbox_stage1(const float* __restrict__ img,
                                                   const float* __restrict__ sem,
                                                   int* __restrict__ colpart,
                                                   int* __restrict__ rowflag){
  int chunk = blockIdx.x;      // 0..7 -> rows [chunk*32, chunk*32+32)
  int s = blockIdx.y;
  int b = blockIdx.z;
  int w = threadIdx.x;         // column
  int h0 = chunk * 32;
  const float* i0 = img + (size_t)(b*3 + 0) * 65536;
  const float* i1 = i0 + 65536;
  const float* i2 = i1 + 65536;
  const float* mk = sem + (size_t)(b*8 + s) * 65536;
  __shared__ int rflags[32];
  if (w < 32) rflags[w] = 0;
  __syncthreads();
  int lane = w & 63;
  int myflag = 0;
  #pragma unroll 4
  for (int r = 0; r < 32; r++){
    int off = (h0 + r)*256 + w;
    float v = (i0[off] + i1[off] + i2[off]) * mk[off];
    int nz = (v != 0.f);
    myflag |= nz;
    unsigned long long bal = __ballot(nz);
    if (lane == 0 && bal) rflags[r] = 1;
  }
  __syncthreads();
  int bs = b*8 + s;
  colpart[(bs*8 + chunk)*256 + w] = myflag;
  if (w < 32) rowflag[bs*256 + h0 + w] = rflags[w];
}

__global__ __launch_bounds__(256) void bbox_stage2(const int* __restrict__ colpart,
                                                   const int* __restrict__ rowflag,
                                                   int* __restrict__ bbox){
  int bs = blockIdx.x;
  int w = threadIdx.x;
  int colnz = 0;
  #pragma unroll
  for (int c = 0; c < 8; c++) colnz |= colpart[(bs*8 + c)*256 + w];
  int rownz = rowflag[bs*256 + w];
  __shared__ int red[256];
  red[w] = colnz ? w : 256; __syncthreads();
  for (int st = 128; st; st >>= 1){ if (w < st) red[w] = min(red[w], red[w+st]); __syncthreads(); }
  int y0 = red[0]; __syncthreads();
  red[w] = colnz ? w : -1; __syncthreads();
  for (int st = 128; st; st >>= 1){ if (w < st) red[w] = max(red[w], red[w+st]); __syncthreads(); }
  int y1 = red[0]; __syncthreads();
  red[w] = rownz ? w : 256; __syncthreads();
  for (int st = 128; st; st >>= 1){ if (w < st) red[w] = min(red[w], red[w+st]); __syncthreads(); }
  int x0 = red[0]; __syncthreads();
  red[w] = rownz ? w : -1; __syncthreads();
  for (int st = 128; st; st >>= 1){ if (w < st) red[w] = max(red[w], red[w+st]); __syncthreads(); }
  int x1 = red[0];
  if (w == 0){
    int ok = (y0 < 256) && (x0 < 256);
    int base = bs * 4;
    bbox[base+0] = ok ? x0 : 0;
    bbox[base+1] = ok ? (x1 - x0 + 1) : 256;
    bbox[base+2] = ok ? y0 : 0;
    bbox[base+3] = ok ? (y1 - y0 + 1) : 256;
  }
}

__global__ void transimg_kernel(const float* __restrict__ img, const float* __restrict__ sem,
                                const int* __restrict__ bbox, float* __restrict__ out){
  int idx = blockIdx.x * 256 + threadIdx.x;
  int j = idx & 255;
  int i = (idx >> 8) & 255;
  int c = idx >> 16;
  int b = c / 24, ch24 = c % 24;
  int s = ch24 / 3, ch = ch24 % 3;
  const int* bb = bbox + (b*8 + s) * 4;
  int ri = bb[0] + ((i * bb[1]) >> 8);
  int cj = bb[2] + ((j * bb[3]) >> 8);
  float m = sem[((size_t)(b*8 + s) * 256 + ri) * 256 + cj];
  float v = img[((size_t)(b*3 + ch) * 256 + ri) * 256 + cj];
  out[idx] = v * m;
}

// =================== stencil-tiled grouped 3x3 conv (conv1, stride 2) ===================
template<int CIN_G, int CIN_CHUNK, int COUT_G, int OCC, int RELU_IN>
__global__ __launch_bounds__(256) void conv3x3_tile(const float* __restrict__ in,
                                                    const float* __restrict__ wt,
                                                    float* __restrict__ out,
                                                    int Hin, int Hout){
  constexpr int TIH = 65, TIW = 65, RS = 66;
  constexpr int NOC = COUT_G / OCC;
  constexpr int NSTAGE = CIN_G / CIN_CHUNK;
  __shared__ float xs[CIN_CHUNK][TIH][RS];
  __shared__ float wsh[OCC][CIN_CHUNK*9];
  int tid = threadIdx.x;
  int g = blockIdx.y, b = blockIdx.z;
  int ocChunk = blockIdx.x % NOC;
  int tileId  = blockIdx.x / NOC;
  int tilesX = Hout >> 5;
  int tileX = tileId % tilesX, tileY = tileId / tilesX;
  int oh0 = tileY*32, ow0 = tileX*32;
  int ih0 = oh0*2 - 1, iw0 = ow0*2 - 1;
  int sx = tid & 15, sy = tid >> 4;
  const int Cin_tot = CIN_G*8;

  float acc[OCC][2][2];
  #pragma unroll
  for (int o = 0; o < OCC; o++)
    #pragma unroll
    for (int i2 = 0; i2 < 2; i2++)
      #pragma unroll
      for (int j2 = 0; j2 < 2; j2++) acc[o][i2][j2] = 0.f;

  for (int st = 0; st < NSTAGE; st++){
    int icb = st*CIN_CHUNK;
    for (int i = tid; i < CIN_CHUNK*TIH*TIW; i += 256){
      int ic = i / (TIH*TIW);
      int rem = i - ic*(TIH*TIW);
      int r = rem / TIW, c = rem - r*TIW;
      int ih = ih0 + r, iw = iw0 + c;
      float v = 0.f;
      if ((unsigned)ih < (unsigned)Hin && (unsigned)iw < (unsigned)Hin){
        v = in[((size_t)(b*Cin_tot + g*CIN_G + icb + ic)*Hin + ih)*Hin + iw];
        if (RELU_IN) v = (v >= 0.f) ? v : 0.2f*v;
      }
      xs[ic][r][c] = v;
    }
    for (int i = tid; i < OCC*CIN_CHUNK*9; i += 256){
      int o = i / (CIN_CHUNK*9);
      int rr = i - o*(CIN_CHUNK*9);
      int ic = rr / 9, tap = rr - ic*9;
      wsh[o][rr] = wt[((size_t)(g*COUT_G + ocChunk*OCC + o)*CIN_G + icb + ic)*9 + tap];
    }
    __syncthreads();
    #pragma unroll
    for (int ic = 0; ic < CIN_CHUNK; ic++){
      #pragma unroll
      for (int kh = 0; kh < 3; kh++){
        #pragma unroll
        for (int kw = 0; kw < 3; kw++){
          float wv[OCC];
          #pragma unroll
          for (int o = 0; o < OCC; o++) wv[o] = wsh[o][ic*9 + kh*3 + kw];
          #pragma unroll
          for (int i2 = 0; i2 < 2; i2++){
            #pragma unroll
            for (int j2 = 0; j2 < 2; j2++){
              float x = xs[ic][2*(sy + 16*i2) + kh][2*(sx + 16*j2) + kw];
              #pragma unroll
              for (int o = 0; o < OCC; o++) acc[o][i2][j2] += wv[o]*x;
            }
          }
        }
      }
    }
    if (st + 1 < NSTAGE) __syncthreads();
  }

  #pragma unroll
  for (int o = 0; o < OCC; o++){
    int oc = g*COUT_G + ocChunk*OCC + o;
    #pragma unroll
    for (int i2 = 0; i2 < 2; i2++)
      #pragma unroll
      for (int j2 = 0; j2 < 2; j2++){
        int oh = oh0 + sy + 16*i2, ow = ow0 + sx + 16*j2;
        out[((size_t)(b*COUT_G*8 + oc)*Hout + oh)*Hout + ow] = acc[o][i2][j2];
      }
  }
}

// =================== instance norm ===================
__global__ void inorm_kernel(const float* __restrict__ in, float* __restrict__ out,
                             int N, int relu_out){
  int bc = blockIdx.x;
  const float* p = in + (size_t)bc * N;
  float* q = out + (size_t)bc * N;
  float s = 0.f, ss = 0.f;
  for (int i = threadIdx.x; i < N; i += blockDim.x){ float x = p[i]; s += x; ss += x*x; }
  __shared__ float sb[8];
  int lane = threadIdx.x & 63, wid = threadIdx.x >> 6;
  for (int o = 32; o; o >>= 1){ s += __shfl_down(s, o, 64); ss += __shfl_down(ss, o, 64); }
  if (lane == 0){ sb[wid] = s; sb[4 + wid] = ss; }
  __syncthreads();
  if (threadIdx.x == 0){
    int nw = blockDim.x >> 6;
    float S = 0.f, SS = 0.f;
    for (int i = 0; i < nw; i++){ S += sb[i]; SS += sb[4+i]; }
    float mean = S / N;
    float var = SS / N - mean*mean;
    sb[0] = mean;
    sb[4] = rsqrtf(var + 1e-5f);
  }
  __syncthreads();
  float mean = sb[0], r = sb[4];
  for (int i = threadIdx.x; i < N; i += blockDim.x){
    float y = (p[i] - mean) * r;
    if (relu_out) y = (y >= 0.f) ? y : 0.2f*y;
    q[i] = y;
  }
}

// instance norm over the sum of P partial buffers (K-split reduction folded in)
template<int P>
__global__ void inorm_sum(const float* __restrict__ in, float* __restrict__ out,
                          int N, size_t pstride, int relu_out){
  int bc = blockIdx.x;
  const float* p = in + (size_t)bc * N;
  float* q = out + (size_t)bc * N;
  float s = 0.f, ss = 0.f;
  for (int i = threadIdx.x; i < N; i += blockDim.x){
    float x = 0.f;
    #pragma unroll
    for (int pp = 0; pp < P; pp++) x += p[(size_t)pp*pstride + i];
    q[i] = x;                 // stash sum; normalized in second pass
    s += x; ss += x*x;
  }
  __shared__ float sb[8];
  int lane = threadIdx.x & 63, wid = threadIdx.x >> 6;
  for (int o = 32; o; o >>= 1){ s += __shfl_down(s, o, 64); ss += __shfl_down(ss, o, 64); }
  if (lane == 0){ sb[wid] = s; sb[4 + wid] = ss; }
  __syncthreads();
  if (threadIdx.x == 0){
    int nw = blockDim.x >> 6;
    float S = 0.f, SS = 0.f;
    for (int i = 0; i < nw; i++){ S += sb[i]; SS += sb[4+i]; }
    float mean = S / N;
    float var = SS / N - mean*mean;
    sb[0] = mean;
    sb[4] = rsqrtf(var + 1e-5f);
  }
  __syncthreads();
  float mean = sb[0], r = sb[4];
  for (int i = threadIdx.x; i < N; i += blockDim.x){
    float y = (q[i] - mean) * r;
    if (relu_out) y = (y >= 0.f) ? y : 0.2f*y;
    q[i] = y;
  }
}

// =================== bf16 hi/lo split helpers & conversion pre-passes ===================
__device__ __forceinline__ void split_bf16(float v, unsigned short& h, unsigned short& l){
  unsigned u = __float_as_uint(v);
  unsigned r = (u + 0x7FFFu + ((u >> 16) & 1u)) >> 16;   // RNE to bf16
  h = (unsigned short)r;
  float hf = __uint_as_float(r << 16);
  float lo = v - hf;
  unsigned u2 = __float_as_uint(lo);
  unsigned r2 = (u2 + 0x7FFFu + ((u2 >> 16) & 1u)) >> 16;
  l = (unsigned short)r2;
}

// src [8][C][HW] f32 -> dst [8][HW][3C] bf16, lrelu applied. blocks: 64ch x 64pix tiles
template<int C, int HW>
__global__ __launch_bounds__(256) void cvt_x_kernel(const float* __restrict__ src,
                                                    unsigned short* __restrict__ dst){
  __shared__ float tile[64][65];
  int b = blockIdx.z;
  int c0 = blockIdx.y * 64, p0 = blockIdx.x * 64;
  const float* sp = src + ((size_t)b*C + c0)*HW + p0;
  for (int i = threadIdx.x; i < 64*64; i += 256){
    int ch = i >> 6, px = i & 63;
    float v = sp[(size_t)ch*HW + px];
    tile[ch][px] = (v >= 0.f) ? v : 0.2f*v;
  }
  __syncthreads();
  unsigned short* dp = dst + ((size_t)b*HW + p0)*(3*C) + c0;
  for (int i = threadIdx.x; i < 64*64; i += 256){
    int px = i >> 6, ch = i & 63;
    float v = tile[ch][px];
    unsigned short h, l; split_bf16(v, h, l);
    unsigned short* row = dp + (size_t)px*(3*C);
    row[ch] = h; row[C + ch] = l; row[2*C + ch] = h;
  }
}

// wt [2048][C] f32 -> dst [2048][3C] bf16: [k]=h, [C+k]=h, [2C+k]=l   (C pow2)
template<int C>
__global__ __launch_bounds__(256) void cvt_w_kernel(const float* __restrict__ wt,
                                                    unsigned short* __restrict__ dst){
  int i = blockIdx.x * 256 + threadIdx.x;
  int oc = i / C, k = i & (C - 1);
  float v = wt[i];
  unsigned short h, l; split_bf16(v, h, l);
  unsigned short* row = dst + (size_t)oc * 3 * C;
  row[k] = h; row[C + k] = h; row[2*C + k] = l;
}

// grouped-conv weight split, K not pow2: wt [Ctot][K] -> dst [Ctot][3K]
template<int K>
__global__ __launch_bounds__(256) void cvt_w_g(const float* __restrict__ wt,
                                               unsigned short* __restrict__ dst, int total){
  int i = blockIdx.x * 256 + threadIdx.x;
  if (i >= total) return;
  int oc = i / K, k = i - oc*K;
  float v = wt[i];
  unsigned short h, l; split_bf16(v, h, l);
  unsigned short* row = dst + (size_t)oc * 3 * K;
  row[k] = h; row[K + k] = h; row[2*K + k] = l;
}

// gather-form padded weight split: dst[oc][kk] for kk<K:h, <2K:h, <3K:l, else 0
template<int K, int K3PAD>
__global__ __launch_bounds__(256) void cvt_w_pad(const float* __restrict__ wt,
                                                 unsigned short* __restrict__ dst, int total){
  int i = blockIdx.x * 256 + threadIdx.x;
  if (i >= total) return;
  int oc = i / K3PAD, kk = i - oc*K3PAD;
  unsigned short o = 0;
  if (kk < 3*K){
    int which = kk / K, k = kk - which*K;
    float v = wt[(size_t)oc*K + k];
    unsigned short h, l; split_bf16(v, h, l);
    o = (which == 2) ? l : h;
  }
  dst[i] = o;
}

// im2col + lrelu + hi/lo split: in [b][CIN_G*8][Hin][Hin] -> XT[g][b*64+pix][3K], Hout=8
template<int CIN_G, int Hin, int STRIDE>
__global__ __launch_bounds__(256) void cvt_im2col(const float* __restrict__ in,
                                                  unsigned short* __restrict__ dst){
  constexpr int K = CIN_G*9;
  constexpr int K3 = 3*K;
  int g = blockIdx.x, b = blockIdx.y, pc = blockIdx.z;   // pc: 16-pixel chunk
  const float* src = in + (size_t)(b*CIN_G*8 + g*CIN_G)*Hin*Hin;
  unsigned short* drow = dst + ((size_t)g*512 + b*64 + pc*16)*K3;
  for (int idx = threadIdx.x; idx < 16*K; idx += 256){
    int pixl = idx / K, k = idx - pixl*K;
    int ic = k / 9, tap = k - ic*9;
    int dh = tap / 3, dw = tap - dh*3;
    int gp = pc*16 + pixl;
    int oh = gp >> 3, ow = gp & 7;
    int ih = oh*STRIDE - 1 + dh, iw = ow*STRIDE - 1 + dw;
    float v = 0.f;
    if ((unsigned)ih < (unsigned)Hin && (unsigned)iw < (unsigned)Hin){
      v = src[((size_t)ic*Hin + ih)*Hin + iw];
      v = (v >= 0.f) ? v : 0.2f*v;
    }
    unsigned short h, l; split_bf16(v, h, l);
    unsigned short* row = drow + (size_t)pixl*K3;
    row[k] = h; row[K + k] = l; row[2*K + k] = h;
  }
}

// general im2col + lrelu + hi/lo split with K-pad, batch-sliced:
// in [b][CIN_G*8][Hin][Hin] -> dst[g][(b-b0)*HW + px][K3PAD];  grid (8, NB, HW/64)
template<int CIN_G, int Hin, int HOSH, int STRIDE, int K3PAD, int NB>
__global__ __launch_bounds__(256) void cvt_im2col_g(const float* __restrict__ in,
                                                    unsigned short* __restrict__ dst, int b0){
  constexpr int K = CIN_G*9;
  constexpr int Hout = 1 << HOSH;
  constexpr int HW = Hout*Hout;
  int g = blockIdx.x, bl = blockIdx.y, pc = blockIdx.z;   // pc: 64-px chunk
  int b = b0 + bl;
  const float* src = in + (size_t)(b*CIN_G*8 + g*CIN_G)*Hin*Hin;
  unsigned short* drow = dst + ((size_t)g*(NB*HW) + (size_t)bl*HW + pc*64)*K3PAD;
  for (int idx = threadIdx.x; idx < 64*K; idx += 256){
    int pixl = idx / K, k = idx - pixl*K;
    int ic = k / 9, tap = k - ic*9;
    int dh = tap / 3, dw = tap - dh*3;
    int gp = pc*64 + pixl;
    int oh = gp >> HOSH, ow = gp & (Hout - 1);
    int ih = oh*STRIDE - 1 + dh, iw = ow*STRIDE - 1 + dw;
    float v = 0.f;
    if ((unsigned)ih < (unsigned)Hin && (unsigned)iw < (unsigned)Hin){
      v = src[((size_t)ic*Hin + ih)*Hin + iw];
      v = (v >= 0.f) ? v : 0.2f*v;
    }
    unsigned short h, l; split_bf16(v, h, l);
    unsigned short* row = drow + (size_t)pixl*K3PAD;
    row[k] = h; row[K + k] = l; row[2*K + k] = h;
  }
  // zero the pad region [3K, K3PAD)
  for (int idx = threadIdx.x; idx < 64*(K3PAD - 3*K); idx += 256){
    int pixl = idx / (K3PAD - 3*K), k = idx - pixl*(K3PAD - 3*K);
    drow[(size_t)pixl*K3PAD + 3*K + k] = 0;
  }
}

// =================== 1x1 conv as bf16x2-split MFMA GEMM (128x128 tile) ===================
// XOR-swizzled LDS (write rr^sc8 / read row^cb, same involution both sides).
template<int K3, int HW, int H>
__global__ __launch_bounds__(256) void conv1x1_mfma(const unsigned short* __restrict__ XT,
                                                    const unsigned short* __restrict__ WT,
                                                    const float* __restrict__ bias,
                                                    float* __restrict__ out){
  constexpr int Wp = H + 2;
  constexpr int NKT = K3 / 64;
  __shared__ unsigned short As[8*128*8];   // [c8][row(oc)^c8][8k]
  __shared__ unsigned short Bs[8*128*8];   // [c8][row(pix)^c8][8k]
  int tid = threadIdx.x;
  int b = blockIdx.z;
  int oc0 = blockIdx.y * 128;
  int px0 = blockIdx.x * 128;
  int lane = tid & 63;
  int wv = tid >> 6;
  int wy = wv >> 1, wx = wv & 1;

  int srow = tid >> 3;       // 0..31, +32 per pass
  int sc8  = tid & 7;
  const unsigned short* Ag = WT + (size_t)(oc0 + srow)*K3 + sc8*8;
  const unsigned short* Bg = XT + ((size_t)b*HW + px0 + srow)*K3 + sc8*8;

  f32x4 acc[4][4];
  #pragma unroll
  for (int i = 0; i < 4; i++)
    #pragma unroll
    for (int j = 0; j < 4; j++) acc[i][j] = (f32x4){0.f,0.f,0.f,0.f};

  for (int kt = 0; kt < NKT; kt++){
    int k0 = kt * 64;
    #pragma unroll
    for (int q = 0; q < 4; q++){
      u32x4 av = *(const u32x4*)(Ag + (size_t)(32*q)*K3 + k0);
      u32x4 bv = *(const u32x4*)(Bg + (size_t)(32*q)*K3 + k0);
      int rr = srow + 32*q;
      *(u32x4*)&As[(sc8*128 + (rr ^ sc8))*8] = av;
      *(u32x4*)&Bs[(sc8*128 + (rr ^ sc8))*8] = bv;
    }
    __syncthreads();
    #pragma unroll
    for (int s = 0; s < 2; s++){
      int cb = s*4 + (lane >> 4);
      s16x8 af[4], bfr[4];
      #pragma unroll
      for (int mt = 0; mt < 4; mt++){
        int row = wy*64 + mt*16 + (lane & 15);
        af[mt] = *(const s16x8*)&As[(cb*128 + (row ^ cb))*8];
      }
      #pragma unroll
      for (int nt = 0; nt < 4; nt++){
        int row = wx*64 + nt*16 + (lane & 15);
        bfr[nt] = *(const s16x8*)&Bs[(cb*128 + (row ^ cb))*8];
      }
      #pragma unroll
      for (int mt = 0; mt < 4; mt++)
        #pragma unroll
        for (int nt = 0; nt < 4; nt++)
          acc[mt][nt] = __builtin_amdgcn_mfma_f32_16x16x32_bf16(af[mt], bfr[nt], acc[mt][nt], 0, 0, 0);
    }
    __syncthreads();
  }

  #pragma unroll
  for (int mt = 0; mt < 4; mt++){
    #pragma unroll
    for (int r = 0; r < 4; r++){
      int oc = oc0 + wy*64 + mt*16 + (lane >> 4)*4 + r;
      float bv2 = bias[oc];
      float* ob = out + ((size_t)b*2048 + oc)*Wp*Wp;
      #pragma unroll
      for (int nt = 0; nt < 4; nt++){
        int pix = px0 + wx*64 + nt*16 + (lane & 15);
        int ph = pix / H, pw2 = pix % H;
        float v = acc[mt][nt][r] + bv2;
        v = (v >= 0.f) ? v : 0.2f*v;
        ob[(size_t)(ph + 1)*Wp + pw2 + 1] = v;
      }
    }
  }
}

// =================== grouped 3x3 conv as bf16x2-split MFMA GEMM (conv5/conv6) ===================
// K-split across blockIdx.z; XOR-swizzled LDS (write & read use the same involution).
template<int K3, int COUT_G, int CTOT, int KSPLIT>
__global__ __launch_bounds__(256) void grouped_mfma(const unsigned short* __restrict__ XT,
                                                    const unsigned short* __restrict__ WT,
                                                    float* __restrict__ out, size_t pstride){
  constexpr int NKT = K3 / 64;
  constexpr int SPK = NKT / KSPLIT;
  __shared__ unsigned short As[8*128*8];
  __shared__ unsigned short Bs[8*128*8];
  int tid = threadIdx.x;
  int oc0 = blockIdx.y * 128;
  int g = oc0 / COUT_G;
  int px0 = blockIdx.x * 128;      // row within group's 512
  int ks = blockIdx.z;
  out += (size_t)ks * pstride;
  int lane = tid & 63;
  int wv = tid >> 6;
  int wy = wv >> 1, wx = wv & 1;

  int srow = tid >> 3;
  int sc8  = tid & 7;
  const unsigned short* Ag = WT + (size_t)(oc0 + srow)*K3 + sc8*8;
  const unsigned short* Bg = XT + ((size_t)g*512 + px0 + srow)*K3 + sc8*8;

  f32x4 acc[4][4];
  #pragma unroll
  for (int i = 0; i < 4; i++)
    #pragma unroll
    for (int j = 0; j < 4; j++) acc[i][j] = (f32x4){0.f,0.f,0.f,0.f};

  for (int kt = ks*SPK; kt < (ks+1)*SPK; kt++){
    int k0 = kt * 64;
    #pragma unroll
    for (int q = 0; q < 4; q++){
      u32x4 av = *(const u32x4*)(Ag + (size_t)(32*q)*K3 + k0);
      u32x4 bv = *(const u32x4*)(Bg + (size_t)(32*q)*K3 + k0);
      int rr = srow + 32*q;
      *(u32x4*)&As[(sc8*128 + (rr ^ sc8))*8] = av;
      *(u32x4*)&Bs[(sc8*128 + (rr ^ sc8))*8] = bv;
    }
    __syncthreads();
    #pragma unroll
    for (int s = 0; s < 2; s++){
      int cb = s*4 + (lane >> 4);
      s16x8 af[4], bfr[4];
      #pragma unroll
      for (int mt = 0; mt < 4; mt++){
        int row = wy*64 + mt*16 + (lane & 15);
        af[mt] = *(const s16x8*)&As[(cb*128 + (row ^ cb))*8];
      }
      #pragma unroll
      for (int nt = 0; nt < 4; nt++){
        int row = wx*64 + nt*16 + (lane & 15);
        bfr[nt] = *(const s16x8*)&Bs[(cb*128 + (row ^ cb))*8];
      }
      #pragma unroll
      for (int mt = 0; mt < 4; mt++)
        #pragma unroll
        for (int nt = 0; nt < 4; nt++)
          acc[mt][nt] = __builtin_amdgcn_mfma_f32_16x16x32_bf16(af[mt], bfr[nt], acc[mt][nt], 0, 0, 0);
    }
    __syncthreads();
  }

  #pragma unroll
  for (int mt = 0; mt < 4; mt++){
    #pragma unroll
    for (int r = 0; r < 4; r++){
      int oc = oc0 + wy*64 + mt*16 + (lane >> 4)*4 + r;
      #pragma unroll
      for (int nt = 0; nt < 4; nt++){
        int row = px0 + wx*64 + nt*16 + (lane & 15);
        int b = row >> 6, p = row & 63;
        out[((size_t)(b*CTOT + oc))*64 + p] = acc[mt][nt][r];
      }
    }
  }
}

// =================== small-M grouped MFMA GEMM (conv2/conv3/conv4): tile = COUT_G x 128 px ===================
// XOR-swizzled LDS on both operands; optional K-split (blockIdx.z) writing full partial buffers.
template<int K3PAD, int COUT_G, int CTOT, int HW, int NROWS, int KSPLIT>
__global__ __launch_bounds__(256) void gconv_mfma(const unsigned short* __restrict__ XT,
                                                  const unsigned short* __restrict__ WT,
                                                  float* __restrict__ out, int b0, size_t pstride){
  constexpr int NKT = K3PAD / 64;
  constexpr int SPK = NKT / KSPLIT;
  constexpr int MF = COUT_G / 16;
  __shared__ unsigned short As[8*COUT_G*8];   // [c8][oc_row][8]
  __shared__ unsigned short Bs[8*128*8];      // [c8][px_row][8]
  int tid = threadIdx.x;
  int g = blockIdx.y;
  int px0 = blockIdx.x * 128;
  int ks = blockIdx.z;
  out += (size_t)ks * pstride;
  int lane = tid & 63;
  int wv = tid >> 6;               // wave -> 32-px slice

  int srow = tid >> 3;             // 0..31
  int sc8  = tid & 7;
  const unsigned short* Agb = WT + (size_t)(g*COUT_G)*K3PAD + sc8*8;
  const unsigned short* Bg  = XT + ((size_t)g*NROWS + px0 + srow)*K3PAD + sc8*8;

  f32x4 acc[MF][2];
  #pragma unroll
  for (int i = 0; i < MF; i++)
    #pragma unroll
    for (int j = 0; j < 2; j++) acc[i][j] = (f32x4){0.f,0.f,0.f,0.f};

  for (int kt = ks*SPK; kt < (ks+1)*SPK; kt++){
    int k0 = kt * 64;
    #pragma unroll
    for (int q = 0; q < (COUT_G + 31)/32; q++){
      int rr = srow + 32*q;
      if (rr < COUT_G)
        *(u32x4*)&As[(sc8*COUT_G + (rr ^ sc8))*8] = *(const u32x4*)(Agb + (size_t)rr*K3PAD + k0);
    }
    #pragma unroll
    for (int q = 0; q < 4; q++){
      int rr = srow + 32*q;
      *(u32x4*)&Bs[(sc8*128 + (rr ^ sc8))*8] = *(const u32x4*)(Bg + (size_t)(32*q)*K3PAD + k0);
    }
    __syncthreads();
    #pragma unroll
    for (int s = 0; s < 2; s++){
      int cb = s*4 + (lane >> 4);
      s16x8 af[MF], bfr[2];
      #pragma unroll
      for (int mt = 0; mt < MF; mt++){
        int row = mt*16 + (lane & 15);
        af[mt] = *(const s16x8*)&As[(cb*COUT_G + (row ^ cb))*8];
      }
      #pragma unroll
      for (int nt = 0; nt < 2; nt++){
        int row = wv*32 + nt*16 + (lane & 15);
        bfr[nt] = *(const s16x8*)&Bs[(cb*128 + (row ^ cb))*8];
      }
      #pragma unroll
      for (int mt = 0; mt < MF; mt++)
        #pragma unroll
        for (int nt = 0; nt < 2; nt++)
          acc[mt][nt] = __builtin_amdgcn_mfma_f32_16x16x32_bf16(af[mt], bfr[nt], acc[mt][nt], 0, 0, 0);
    }
    __syncthreads();
  }

  #pragma unroll
  for (int mt = 0; mt < MF; mt++){
    #pragma unroll
    for (int r = 0; r < 4; r++){
      int oc = g*COUT_G + mt*16 + (lane >> 4)*4 + r;
      #pragma unroll
      for (int nt = 0; nt < 2; nt++){
        int rowg = px0 + wv*32 + nt*16 + (lane & 15);
        int bl = rowg / HW, px = rowg - bl*HW;
        out[((size_t)((b0 + bl)*CTOT + oc))*HW + px] = acc[mt][nt][r];
      }
    }
  }
}

// border cells only: out[b][oc][border of (H+2)x(H+2)] = lrelu(bias[oc])
__global__ void border_kernel(const float* __restrict__ bias, float* __restrict__ out, int H){
  int Wp = H + 2, perim = 4*Wp - 4;
  int p = threadIdx.x;
  if (p >= perim) return;
  int oc = blockIdx.y, b = blockIdx.z;
  int ph, pw;
  if (p < Wp){ ph = 0; pw = p; }
  else if (p < 2*Wp){ ph = Wp - 1; pw = p - Wp; }
  else { int q = p - 2*Wp; ph = 1 + (q >> 1); pw = (q & 1) ? (Wp - 1) : 0; }
  float bv = bias[oc];
  bv = (bv >= 0.f) ? bv : 0.2f*bv;
  out[(((size_t)b*2048 + oc)*Wp + ph)*Wp + pw] = bv;
}

// =================== host ===================
extern "C" void kernel_launch(void* const* d_in, const int* in_sizes, int n_in,
                              void* d_out, int out_size, void* d_ws, size_t ws_size,
                              hipStream_t stream){
  const float* img = (const float*)d_in[0];
  const float* sem = (const float*)d_in[1];
  Ptr6 wp;
  for (int l = 0; l < 6; l++) wp.p[l] = (const float*)d_in[2 + l];
  const float* gw1 = (const float*)d_in[8];
  const float* gb1 = (const float*)d_in[9];
  const float* gw2 = (const float*)d_in[10];
  const float* gb2 = (const float*)d_in[11];
  float* out = (float*)d_out;
  float* ws  = (float*)d_ws;

  float* bufA = out + OUT_X2;
  float* bufB = bufA + 8388608;
  float* bufC = ws + WS_OFF_C;
  float* bufD = ws + WS_OFF_D;
  int* bbox = (int*)(ws + WS_OFF_BBOX);
  // bbox flag scratch: spare tail of OUT_X2 region (used before x_2 is written)
  int* colpart = (int*)(bufB + 8388608);          // 64*8*256 ints
  int* rowflag = colpart + 64*8*256;              // 64*256 ints

  // bf16 GEMM scratch (1x1 convs):
  unsigned short* XT2 = (unsigned short*)(out + OUT_X1);             // 8*1024*768 bf16
  unsigned short* W2  = (unsigned short*)(out + OUT_X1 + 3145728);   // 2048*768 bf16
  unsigned short* XT1 = (unsigned short*)(ws + WS_OFF_W);            // 8*256*1536 bf16
  unsigned short* W1  = (unsigned short*)(ws + WS_OFF_W + 1572864);  // 2048*1536 bf16

  // bf16 GEMM scratch (grouped convs 5/6):
  unsigned short* XT5 = (unsigned short*)(bufA + 1048576);   // 8g*512*1728 bf16
  unsigned short* W5s = (unsigned short*)(bufB);             // 1024*1728 bf16
  unsigned short* XT6 = (unsigned short*)(bufA + 1048576);   // 8g*512*3456 bf16
  unsigned short* W6s = (unsigned short*)(bufB + 1048576);   // 2048*3456 bf16

  // dead tail of OUT_X2 region (past bufB; 2.16M floats, dead after bbox_stage2):
  unsigned short* W3s = (unsigned short*)(bufB + 8388608);              // 256*448 bf16 = 57,344 floats
  unsigned short* W2s = (unsigned short*)(bufB + 8388608 + 57344);      // 128*256 bf16 = 16,384 floats
  unsigned short* W4s = (unsigned short*)(bufB + 8388608 + 73728);      // 512*896 bf16 = 229,376 floats

  // conv2/conv3/conv4 X + raw-out scratch:
  unsigned short* X2i = (unsigned short*)bufA;               // 8g*8192*256 bf16 = 8.39M floats
  float* out2raw = out + OUT_X1;                             // 8*128*4096 = 4.19M floats
  unsigned short* X3i = (unsigned short*)bufA;               // 8g*4096*448 bf16 = 7.34M floats/slice
  float* out3raw = out + OUT_X1;                             // 8*256*1024 = 2.1M floats
  unsigned short* X4i = (unsigned short*)bufA;               // 8g*2048*896 bf16 = 7.34M floats
  float* out4raw = out + OUT_X1;                             // 2 partials x 8*512*256 = 2x1.05M floats

  static const int kWOff[6]  = {0,1728,10944,47808,195264,785088};
  static const int kWSize[6] = {1728,9216,36864,147456,589824,2359296};

  hipMemsetAsync(ws + WS_OFF_T, 0, (WS_OFF_S2 + 8 - WS_OFF_T) * sizeof(float), stream);

  gen_u_par<<<6, 256, 0, stream>>>(ws);
  sn_t_kernel<<<252, 256, 0, stream>>>(wp, ws);
  sn_tn_kernel<<<6, 256, 0, stream>>>(ws);
  sn_z_kernel<<<1008, 256, 0, stream>>>(wp, ws);
  for (int l = 0; l < 6; l++)
    wscale_kernel<<<(kWSize[l]+255)/256, 256, 0, stream>>>(wp.p[l], ws + WS_OFF_W + kWOff[l],
                                                           kWSize[l], ws + WS_OFF_TN + l, ws + WS_OFF_S2 + l);

  bbox_stage1<<<dim3(8,8,8), 256, 0, stream>>>(img, sem, colpart, rowflag);
  bbox_stage2<<<64, 256, 0, stream>>>(colpart, rowflag, bbox);
  transimg_kernel<<<49152, 256, 0, stream>>>(img, sem, bbox, out + OUT_IMG);

  // conv1: images(8,24,256,256) -> (8,64,128,128)   [stencil tile, single-stage]
  conv3x3_tile<3,3,8,8,0><<<dim3(16,8,8), 256, 0, stream>>>(out + OUT_IMG, ws + WS_OFF_W + kWOff[0],
                                                            bufA, 256, 128);
  inorm_kernel<<<512, 256, 0, stream>>>(bufA, bufB, 16384, 0);

  // conv2 -> (8,128,64,64)   [bf16-split MFMA, 4 slices of 2 batches]
  cvt_w_pad<72,256><<<(128*256+255)/256, 256, 0, stream>>>(ws + WS_OFF_W + kWOff[1], W2s, 128*256);
  for (int s = 0; s < 4; s++){
    cvt_im2col_g<8,128,6,2,256,2><<<dim3(8,2,64), 256, 0, stream>>>(bufB, X2i, 2*s);
    gconv_mfma<256,16,128,4096,8192,1><<<dim3(64,8), 256, 0, stream>>>(X2i, W2s, out2raw, 2*s, 0);
  }
  inorm_kernel<<<1024, 256, 0, stream>>>(out2raw, bufB, 4096, 0);

  // conv3 -> out_8 (8,256,32,32)   [bf16-split MFMA, 2 slices of 4 batches]
  cvt_w_pad<144,448><<<(256*448+255)/256, 256, 0, stream>>>(ws + WS_OFF_W + kWOff[2], W3s, 256*448);
  for (int s = 0; s < 2; s++){
    cvt_im2col_g<16,64,5,2,448,4><<<dim3(8,4,16), 256, 0, stream>>>(bufB, X3i, 4*s);
    gconv_mfma<448,32,256,1024,4096,1><<<dim3(32,8), 256, 0, stream>>>(X3i, W3s, out3raw, 4*s, 0);
  }
  inorm_kernel<<<2048, 256, 0, stream>>>(out3raw, bufC, 1024, 0);

  // conv4 -> out_16 (8,512,16,16)   [bf16-split MFMA, single slice of all 8 batches, K-split x2]
  cvt_w_pad<288,896><<<(512*896+255)/256, 256, 0, stream>>>(ws + WS_OFF_W + kWOff[3], W4s, 512*896);
  cvt_im2col_g<32,32,4,2,896,8><<<dim3(8,8,4), 256, 0, stream>>>(bufC, X4i, 0);
  gconv_mfma<896,64,512,256,2048,2><<<dim3(16,8,2), 256, 0, stream>>>(X4i, W4s, out4raw, 0, 1048576);
  inorm_sum<2><<<4096, 256, 0, stream>>>(out4raw, bufD, 256, 1048576, 0);

  // conv5 -> out_32 (8,1024,8,8)   [bf16-split MFMA, K-split x3 -> 96 blocks]
  cvt_im2col<64,16,2><<<dim3(8,8,4), 256, 0, stream>>>(bufD, XT5);
  cvt_w_g<576><<<2304, 256, 0, stream>>>(ws + WS_OFF_W + kWOff[4], W5s, 589824);
  grouped_mfma<1728,128,1024,3><<<dim3(4,8,3), 256, 0, stream>>>(XT5, W5s, out + OUT_X1, 524288);
  inorm_sum<3><<<8192, 64, 0, stream>>>(out + OUT_X1, bufB, 64, 524288, 0);

  // conv6 -> (8,2048,8,8), stride 1   [bf16-split MFMA, K-split x6 -> 384 blocks]
  cvt_im2col<128,8,1><<<dim3(8,8,4), 256, 0, stream>>>(bufB, XT6);
  cvt_w_g<1152><<<9216, 256, 0, stream>>>(ws + WS_OFF_W + kWOff[5], W6s, 2359296);
  grouped_mfma<3456,256,2048,6><<<dim3(4,16,6), 256, 0, stream>>>(XT6, W6s, out, 1048576);
  inorm_sum<6><<<16384, 64, 0, stream>>>(out, out + OUT_X, 64, 1048576, 1);   // x

  // ---- bf16x2-split conversions for 1x1 convs (spectral weights + bufA/bufB now dead) ----
  cvt_x_kernel<256,1024><<<dim3(16,4,8), 256, 0, stream>>>(bufC, XT2);   // reads bufC first
  cvt_w_kernel<256><<<2048, 256, 0, stream>>>(gw2, W2);
  cvt_x_kernel<512,256><<<dim3(4,8,8), 256, 0, stream>>>(bufD, XT1);
  cvt_w_kernel<512><<<4096, 256, 0, stream>>>(gw1, W1);                  // may touch bufC head (dead now)

  // x_2 -> (8,2048,34,34): reads OUT_X1-region scratch, writes OUT_X2
  border_kernel<<<dim3(1,2048,8), 256, 0, stream>>>(gb2, out + OUT_X2, 32);
  conv1x1_mfma<768,1024,32><<<dim3(8,16,8), 256, 0, stream>>>(XT2, W2, gb2, out + OUT_X2);
  // x_1 -> (8,2048,18,18): reads ws scratch, overwrites OUT_X1 (XT2/W2 dead)
  border_kernel<<<dim3(1,2048,8), 256, 0, stream>>>(gb1, out + OUT_X1, 16);
  conv1x1_mfma<1536,256,16><<<dim3(2,16,8), 256, 0, stream>>>(XT1, W1, gb1, out + OUT_X1);
}

// Round 14
// 631.685 us; speedup vs baseline: 1.0481x; 1.0481x over previous
//
#include <hip/hip_runtime.h>
#include <math.h>

// ---------------- workspace layout (float indices) ----------------
#define WS_OFF_U     0
#define WS_OFF_T     4096
#define WS_OFF_TN    6400
#define WS_OFF_S2    6408
#define WS_OFF_BBOX  6416
#define WS_OFF_W     8192
#define WS_OFF_C     3152896  // out_8 normalized (2,097,152)
#define WS_OFF_D     5250048  // out_16 normalized (1,048,576)

// ---------------- d_out layout (float offsets) ----------------
#define OUT_X    0          // 8*2048*8*8     = 1,048,576
#define OUT_X1   1048576    // 8*2048*18*18   = 5,308,416
#define OUT_X2   6356992    // 8*2048*34*34   = 18,939,904 (hosts bufA/bufB scratch)
#define OUT_IMG  25296896   // 8*24*256*256   = 12,582,912

struct Ptr6 { const float* p[6]; };

typedef short s16x8 __attribute__((ext_vector_type(8)));
typedef float f32x4 __attribute__((ext_vector_type(4)));
typedef unsigned int u32x4 __attribute__((ext_vector_type(4)));

// =================== parallel MT19937 + Marsaglia polar (numpy RandomState) ===================
#define MT_UP 0x80000000u
#define MT_LO 0x7fffffffu

__global__ __launch_bounds__(256) void gen_u_par(float* ws){
  const int os[6]   = {64,128,256,512,1024,2048};
  const int uoff[6] = {0,64,192,448,960,1984};
  int l = blockIdx.x;
  int n = os[l];
  int tid = threadIdx.x;

  __shared__ unsigned mt[624];
  __shared__ unsigned draws[8192];
  __shared__ float px[2048], py[2048];
  __shared__ unsigned char accf[2048];
  __shared__ int scan[256];

  if (tid == 0){
    unsigned seed = (unsigned)(l + 1);
    for (int i = 0; i < 624; i++){
      mt[i] = seed;
      seed = 1812433253u * (seed ^ (seed >> 30)) + (unsigned)(i + 1);
    }
  }
  __syncthreads();

  int need = 4 * n;
  int twists = (need + 623) / 624;
  for (int t = 0; t < twists; t++){
    unsigned yA = 0, vA = 0;
    if (tid < 227){ yA = (mt[tid] & MT_UP) | (mt[tid+1] & MT_LO); vA = mt[tid+397]; }
    __syncthreads();
    if (tid < 227){ mt[tid] = vA ^ (yA >> 1) ^ ((yA & 1u) ? 0x9908b0dfu : 0u); }
    __syncthreads();
    unsigned yB = 0, vB = 0; int iB = 227 + tid;
    if (tid < 227){ yB = (mt[iB] & MT_UP) | (mt[iB+1] & MT_LO); vB = mt[iB-227]; }
    __syncthreads();
    if (tid < 227){ mt[iB] = vB ^ (yB >> 1) ^ ((yB & 1u) ? 0x9908b0dfu : 0u); }
    __syncthreads();
    unsigned yC = 0, vC = 0; int iC = 454 + tid;
    if (tid < 169){ yC = (mt[iC] & MT_UP) | (mt[iC+1] & MT_LO); vC = mt[iC-227]; }
    __syncthreads();
    if (tid < 169){ mt[iC] = vC ^ (yC >> 1) ^ ((yC & 1u) ? 0x9908b0dfu : 0u); }
    __syncthreads();
    if (tid == 0){
      unsigned y = (mt[623] & MT_UP) | (mt[0] & MT_LO);
      mt[623] = mt[396] ^ (y >> 1) ^ ((y & 1u) ? 0x9908b0dfu : 0u);
    }
    __syncthreads();
    for (int i = tid; i < 624; i += 256){
      int pos = t * 624 + i;
      if (pos < need){
        unsigned y = mt[i];
        y ^= y >> 11; y ^= (y << 7) & 0x9d2c5680u; y ^= (y << 15) & 0xefc60000u; y ^= y >> 18;
        draws[pos] = y;
      }
    }
    __syncthreads();
  }

  int A = (n + 255) / 256;
  int local = 0;
  for (int a = 0; a < A; a++){
    int k = tid * A + a;
    if (k < n){
      double u1 = ((draws[4*k]   >> 5) * 67108864.0 + (draws[4*k+1] >> 6)) / 9007199254740992.0;
      double u2 = ((draws[4*k+2] >> 5) * 67108864.0 + (draws[4*k+3] >> 6)) / 9007199254740992.0;
      double x1 = 2.0*u1 - 1.0, x2 = 2.0*u2 - 1.0;
      double r2 = x1*x1 + x2*x2;
      int ok = (r2 < 1.0 && r2 != 0.0);
      accf[k] = (unsigned char)ok;
      if (ok){
        double f = sqrt(-2.0 * log(r2) / r2);
        px[k] = (float)(f * x2);
        py[k] = (float)(f * x1);
      }
      local += ok;
    }
  }
  scan[tid] = local;
  __syncthreads();
  if (tid == 0){
    int run = 0;
    for (int i = 0; i < 256; i++){ int c = scan[i]; scan[i] = run; run += c; }
  }
  __syncthreads();
  int j = scan[tid];
  float* u = ws + WS_OFF_U + uoff[l];
  for (int a = 0; a < A; a++){
    int k = tid * A + a;
    if (k < n && accf[k]){
      if (2*j + 1 < n){ u[2*j] = px[k]; u[2*j+1] = py[k]; }
      j++;
    }
  }
}

// =================== spectral norm: t = M^T u ===================
__global__ __launch_bounds__(256) void sn_t_kernel(Ptr6 wp, float* ws){
  const int cols[6] = {27,72,144,288,576,1152};
  const int uoff[6] = {0,64,192,448,960,1984};
  const int toff[6] = {0,27,99,243,531,1107};
  const int cstart[7] = {0,4,12,28,60,124,252};   // 16-row chunks per layer
  int b = blockIdx.x;
  int l = 0; while (l < 5 && b >= cstart[l+1]) l++;
  int chunk = b - cstart[l];
  int r0 = chunk * 16;
  int C = cols[l];
  const float* m = wp.p[l];
  const float* u = ws + WS_OFF_U + uoff[l];
  float* t = ws + WS_OFF_T + toff[l];
  __shared__ float us[16];
  if (threadIdx.x < 16) us[threadIdx.x] = u[r0 + threadIdx.x];
  __syncthreads();
  for (int j = threadIdx.x; j < C; j += 256){
    float acc = 0.f;
    #pragma unroll
    for (int r = 0; r < 16; r++) acc += m[(size_t)(r0 + r) * C + j] * us[r];
    atomicAdd(&t[j], acc);
  }
}

__global__ void sn_tn_kernel(float* ws){
  const int cols[6] = {27,72,144,288,576,1152};
  const int toff[6] = {0,27,99,243,531,1107};
  int l = blockIdx.x;
  const float* t = ws + WS_OFF_T + toff[l];
  float s = 0.f;
  for (int j = threadIdx.x; j < cols[l]; j += 256){ float v = t[j]; s += v*v; }
  __shared__ float sb[4];
  int lane = threadIdx.x & 63, wid = threadIdx.x >> 6;
  for (int o = 32; o; o >>= 1) s += __shfl_down(s, o, 64);
  if (lane == 0) sb[wid] = s;
  __syncthreads();
  if (threadIdx.x == 0) ws[WS_OFF_TN + l] = sb[0] + sb[1] + sb[2] + sb[3];
}

// =================== spectral norm: s2 += ||M t||^2, wave-per-row ===================
__global__ __launch_bounds__(256) void sn_z_kernel(Ptr6 wp, float* ws){
  const int cols[6] = {27,72,144,288,576,1152};
  const int toff[6] = {0,27,99,243,531,1107};
  const int rstart[7] = {0,64,192,448,960,1984,4032};
  __shared__ float part[6];
  if (threadIdx.x < 6) part[threadIdx.x] = 0.f;
  __syncthreads();
  int gr = blockIdx.x * 4 + (threadIdx.x >> 6);
  int lane = threadIdx.x & 63;
  if (gr < 4032){
    int l = 0; while (l < 5 && gr >= rstart[l+1]) l++;
    int row = gr - rstart[l];
    int C = cols[l];
    const float* m = wp.p[l] + (size_t)row * C;
    const float* t = ws + WS_OFF_T + toff[l];
    float acc = 0.f;
    for (int c = lane; c < C; c += 64) acc += m[c] * t[c];
    for (int o = 32; o; o >>= 1) acc += __shfl_down(acc, o, 64);
    if (lane == 0) atomicAdd(&part[l], acc * acc);
  }
  __syncthreads();
  if (threadIdx.x < 6 && part[threadIdx.x] != 0.f)
    atomicAdd(&ws[WS_OFF_S2 + threadIdx.x], part[threadIdx.x]);
}

__global__ void wscale_kernel(const float* __restrict__ src, float* __restrict__ dst,
                              int n, const float* __restrict__ tn, const float* __restrict__ s2){
  int i = blockIdx.x * 256 + threadIdx.x;
  if (i >= n) return;
  float inv = sqrtf(tn[0] / s2[0]);
  dst[i] = src[i] * inv;
}

// =================== crop/resize bbox (2-stage, 512-block streaming) ===================
__global__ __launch_bounds__(256) void bbox_stage1(const float* __restrict__ img,
                                                   const float* __restrict__ sem,
                                                   int* __restrict__ colpart,
                                                   int* __restrict__ rowflag){
  int chunk = blockIdx.x;      // 0..7 -> rows [chunk*32, chunk*32+32)
  int s = blockIdx.y;
  int b = blockIdx.z;
  int w = threadIdx.x;         // column
  int h0 = chunk * 32;
  const float* i0 = img + (size_t)(b*3 + 0) * 65536;
  const float* i1 = i0 + 65536;
  const float* i2 = i1 + 65536;
  const float* mk = sem + (size_t)(b*8 + s) * 65536;
  __shared__ int rflags[32];
  if (w < 32) rflags[w] = 0;
  __syncthreads();
  int lane = w & 63;
  int myflag = 0;
  #pragma unroll 4
  for (int r = 0; r < 32; r++){
    int off = (h0 + r)*256 + w;
    float v = (i0[off] + i1[off] + i2[off]) * mk[off];
    int nz = (v != 0.f);
    myflag |= nz;
    unsigned long long bal = __ballot(nz);
    if (lane == 0 && bal) rflags[r] = 1;
  }
  __syncthreads();
  int bs = b*8 + s;
  colpart[(bs*8 + chunk)*256 + w] = myflag;
  if (w < 32) rowflag[bs*256 + h0 + w] = rflags[w];
}

__global__ __launch_bounds__(256) void bbox_stage2(const int* __restrict__ colpart,
                                                   const int* __restrict__ rowflag,
                                                   int* __restrict__ bbox){
  int bs = blockIdx.x;
  int w = threadIdx.x;
  int colnz = 0;
  #pragma unroll
  for (int c = 0; c < 8; c++) colnz |= colpart[(bs*8 + c)*256 + w];
  int rownz = rowflag[bs*256 + w];
  __shared__ int red[256];
  red[w] = colnz ? w : 256; __syncthreads();
  for (int st = 128; st; st >>= 1){ if (w < st) red[w] = min(red[w], red[w+st]); __syncthreads(); }
  int y0 = red[0]; __syncthreads();
  red[w] = colnz ? w : -1; __syncthreads();
  for (int st = 128; st; st >>= 1){ if (w < st) red[w] = max(red[w], red[w+st]); __syncthreads(); }
  int y1 = red[0]; __syncthreads();
  red[w] = rownz ? w : 256; __syncthreads();
  for (int st = 128; st; st >>= 1){ if (w < st) red[w] = min(red[w], red[w+st]); __syncthreads(); }
  int x0 = red[0]; __syncthreads();
  red[w] = rownz ? w : -1; __syncthreads();
  for (int st = 128; st; st >>= 1){ if (w < st) red[w] = max(red[w], red[w+st]); __syncthreads(); }
  int x1 = red[0];
  if (w == 0){
    int ok = (y0 < 256) && (x0 < 256);
    int base = bs * 4;
    bbox[base+0] = ok ? x0 : 0;
    bbox[base+1] = ok ? (x1 - x0 + 1) : 256;
    bbox[base+2] = ok ? y0 : 0;
    bbox[base+3] = ok ? (y1 - y0 + 1) : 256;
  }
}

__global__ void transimg_kernel(const float* __restrict__ img, const float* __restrict__ sem,
                                const int* __restrict__ bbox, float* __restrict__ out){
  int idx = blockIdx.x * 256 + threadIdx.x;
  int j = idx & 255;
  int i = (idx >> 8) & 255;
  int c = idx >> 16;
  int b = c / 24, ch24 = c % 24;
  int s = ch24 / 3, ch = ch24 % 3;
  const int* bb = bbox + (b*8 + s) * 4;
  int ri = bb[0] + ((i * bb[1]) >> 8);
  int cj = bb[2] + ((j * bb[3]) >> 8);
  float m = sem[((size_t)(b*8 + s) * 256 + ri) * 256 + cj];
  float v = img[((size_t)(b*3 + ch) * 256 + ri) * 256 + cj];
  out[idx] = v * m;
}

// =================== stencil-tiled grouped 3x3 conv (conv1, stride 2) ===================
template<int CIN_G, int CIN_CHUNK, int COUT_G, int OCC, int RELU_IN>
__global__ __launch_bounds__(256) void conv3x3_tile(const float* __restrict__ in,
                                                    const float* __restrict__ wt,
                                                    float* __restrict__ out,
                                                    int Hin, int Hout){
  constexpr int TIH = 65, TIW = 65, RS = 66;
  constexpr int NOC = COUT_G / OCC;
  constexpr int NSTAGE = CIN_G / CIN_CHUNK;
  __shared__ float xs[CIN_CHUNK][TIH][RS];
  __shared__ float wsh[OCC][CIN_CHUNK*9];
  int tid = threadIdx.x;
  int g = blockIdx.y, b = blockIdx.z;
  int ocChunk = blockIdx.x % NOC;
  int tileId  = blockIdx.x / NOC;
  int tilesX = Hout >> 5;
  int tileX = tileId % tilesX, tileY = tileId / tilesX;
  int oh0 = tileY*32, ow0 = tileX*32;
  int ih0 = oh0*2 - 1, iw0 = ow0*2 - 1;
  int sx = tid & 15, sy = tid >> 4;
  const int Cin_tot = CIN_G*8;

  float acc[OCC][2][2];
  #pragma unroll
  for (int o = 0; o < OCC; o++)
    #pragma unroll
    for (int i2 = 0; i2 < 2; i2++)
      #pragma unroll
      for (int j2 = 0; j2 < 2; j2++) acc[o][i2][j2] = 0.f;

  for (int st = 0; st < NSTAGE; st++){
    int icb = st*CIN_CHUNK;
    for (int i = tid; i < CIN_CHUNK*TIH*TIW; i += 256){
      int ic = i / (TIH*TIW);
      int rem = i - ic*(TIH*TIW);
      int r = rem / TIW, c = rem - r*TIW;
      int ih = ih0 + r, iw = iw0 + c;
      float v = 0.f;
      if ((unsigned)ih < (unsigned)Hin && (unsigned)iw < (unsigned)Hin){
        v = in[((size_t)(b*Cin_tot + g*CIN_G + icb + ic)*Hin + ih)*Hin + iw];
        if (RELU_IN) v = (v >= 0.f) ? v : 0.2f*v;
      }
      xs[ic][r][c] = v;
    }
    for (int i = tid; i < OCC*CIN_CHUNK*9; i += 256){
      int o = i / (CIN_CHUNK*9);
      int rr = i - o*(CIN_CHUNK*9);
      int ic = rr / 9, tap = rr - ic*9;
      wsh[o][rr] = wt[((size_t)(g*COUT_G + ocChunk*OCC + o)*CIN_G + icb + ic)*9 + tap];
    }
    __syncthreads();
    #pragma unroll
    for (int ic = 0; ic < CIN_CHUNK; ic++){
      #pragma unroll
      for (int kh = 0; kh < 3; kh++){
        #pragma unroll
        for (int kw = 0; kw < 3; kw++){
          float wv[OCC];
          #pragma unroll
          for (int o = 0; o < OCC; o++) wv[o] = wsh[o][ic*9 + kh*3 + kw];
          #pragma unroll
          for (int i2 = 0; i2 < 2; i2++){
            #pragma unroll
            for (int j2 = 0; j2 < 2; j2++){
              float x = xs[ic][2*(sy + 16*i2) + kh][2*(sx + 16*j2) + kw];
              #pragma unroll
              for (int o = 0; o < OCC; o++) acc[o][i2][j2] += wv[o]*x;
            }
          }
        }
      }
    }
    if (st + 1 < NSTAGE) __syncthreads();
  }

  #pragma unroll
  for (int o = 0; o < OCC; o++){
    int oc = g*COUT_G + ocChunk*OCC + o;
    #pragma unroll
    for (int i2 = 0; i2 < 2; i2++)
      #pragma unroll
      for (int j2 = 0; j2 < 2; j2++){
        int oh = oh0 + sy + 16*i2, ow = ow0 + sx + 16*j2;
        out[((size_t)(b*COUT_G*8 + oc)*Hout + oh)*Hout + ow] = acc[o][i2][j2];
      }
  }
}

// =================== im2col-GEMM grouped 3x3 conv (conv4, fp32) ===================
template<int STRIDE, int CIN_G, int COUT_G, int HSH>
__global__ __launch_bounds__(256) void conv3x3_gemm(const float* __restrict__ in,
                                                    const float* __restrict__ wt,
                                                    float* __restrict__ out,
                                                    int Hin){
  constexpr int K = CIN_G*9;
  const int Hout = 1 << HSH;
  int z = blockIdx.z; int b = z >> 3, g = z & 7;
  int n0 = blockIdx.x * 64, oc0 = blockIdx.y * 64;
  __shared__ float Ws[16][68];
  __shared__ float Xs[16][68];
  int tid = threadIdx.x;
  int tx = tid & 15, ty = tid >> 4;
  int pixl = tid & 63;
  int kkb = (tid >> 6) << 2;
  float acc[4][4];
  #pragma unroll
  for (int i = 0; i < 4; i++)
    #pragma unroll
    for (int j = 0; j < 4; j++) acc[i][j] = 0.f;

  for (int k0 = 0; k0 < K; k0 += 16){
    #pragma unroll
    for (int r = 0; r < 4; r++){
      int oc_l = (tid >> 4) + 16*r;
      int kk = tid & 15;
      Ws[kk][oc_l] = wt[((size_t)(g*COUT_G + oc0 + oc_l))*K + k0 + kk];
    }
    #pragma unroll
    for (int r = 0; r < 4; r++){
      int kk = kkb + r;
      int k = k0 + kk;
      int ic = k / 9, tap = k - ic*9;
      int dh = tap / 3, dw = tap - dh*3;
      int n = n0 + pixl;
      int oh = n >> HSH, ow = n & (Hout - 1);
      int ih = oh*STRIDE - 1 + dh, iw = ow*STRIDE - 1 + dw;
      float v = 0.f;
      if ((unsigned)ih < (unsigned)Hin && (unsigned)iw < (unsigned)Hin){
        v = in[((size_t)(b*CIN_G*8 + g*CIN_G + ic)*Hin + ih)*Hin + iw];
        v = (v >= 0.f) ? v : 0.2f*v;
      }
      Xs[kk][pixl] = v;
    }
    __syncthreads();
    #pragma unroll
    for (int kk = 0; kk < 16; kk++){
      float4 wv = *(const float4*)&Ws[kk][ty*4];
      float4 xv = *(const float4*)&Xs[kk][tx*4];
      acc[0][0] += wv.x*xv.x; acc[0][1] += wv.x*xv.y; acc[0][2] += wv.x*xv.z; acc[0][3] += wv.x*xv.w;
      acc[1][0] += wv.y*xv.x; acc[1][1] += wv.y*xv.y; acc[1][2] += wv.y*xv.z; acc[1][3] += wv.y*xv.w;
      acc[2][0] += wv.z*xv.x; acc[2][1] += wv.z*xv.y; acc[2][2] += wv.z*xv.z; acc[2][3] += wv.z*xv.w;
      acc[3][0] += wv.w*xv.x; acc[3][1] += wv.w*xv.y; acc[3][2] += wv.w*xv.z; acc[3][3] += wv.w*xv.w;
    }
    __syncthreads();
  }

  #pragma unroll
  for (int i = 0; i < 4; i++){
    int oc = g*COUT_G + oc0 + ty*4 + i;
    #pragma unroll
    for (int j = 0; j < 4; j++){
      int n = n0 + tx*4 + j;
      int oh = n >> HSH, ow = n & (Hout - 1);
      out[((size_t)(b*COUT_G*8 + oc)*Hout + oh)*Hout + ow] = acc[i][j];
    }
  }
}

// =================== instance norm ===================
__global__ void inorm_kernel(const float* __restrict__ in, float* __restrict__ out,
                             int N, int relu_out){
  int bc = blockIdx.x;
  const float* p = in + (size_t)bc * N;
  float* q = out + (size_t)bc * N;
  float s = 0.f, ss = 0.f;
  for (int i = threadIdx.x; i < N; i += blockDim.x){ float x = p[i]; s += x; ss += x*x; }
  __shared__ float sb[8];
  int lane = threadIdx.x & 63, wid = threadIdx.x >> 6;
  for (int o = 32; o; o >>= 1){ s += __shfl_down(s, o, 64); ss += __shfl_down(ss, o, 64); }
  if (lane == 0){ sb[wid] = s; sb[4 + wid] = ss; }
  __syncthreads();
  if (threadIdx.x == 0){
    int nw = blockDim.x >> 6;
    float S = 0.f, SS = 0.f;
    for (int i = 0; i < nw; i++){ S += sb[i]; SS += sb[4+i]; }
    float mean = S / N;
    float var = SS / N - mean*mean;
    sb[0] = mean;
    sb[4] = rsqrtf(var + 1e-5f);
  }
  __syncthreads();
  float mean = sb[0], r = sb[4];
  for (int i = threadIdx.x; i < N; i += blockDim.x){
    float y = (p[i] - mean) * r;
    if (relu_out) y = (y >= 0.f) ? y : 0.2f*y;
    q[i] = y;
  }
}

// instance norm over the sum of P partial buffers (K-split reduction folded in)
template<int P>
__global__ void inorm_sum(const float* __restrict__ in, float* __restrict__ out,
                          int N, size_t pstride, int relu_out){
  int bc = blockIdx.x;
  const float* p = in + (size_t)bc * N;
  float* q = out + (size_t)bc * N;
  float s = 0.f, ss = 0.f;
  for (int i = threadIdx.x; i < N; i += blockDim.x){
    float x = 0.f;
    #pragma unroll
    for (int pp = 0; pp < P; pp++) x += p[(size_t)pp*pstride + i];
    q[i] = x;                 // stash sum; normalized in second pass
    s += x; ss += x*x;
  }
  __shared__ float sb[8];
  int lane = threadIdx.x & 63, wid = threadIdx.x >> 6;
  for (int o = 32; o; o >>= 1){ s += __shfl_down(s, o, 64); ss += __shfl_down(ss, o, 64); }
  if (lane == 0){ sb[wid] = s; sb[4 + wid] = ss; }
  __syncthreads();
  if (threadIdx.x == 0){
    int nw = blockDim.x >> 6;
    float S = 0.f, SS = 0.f;
    for (int i = 0; i < nw; i++){ S += sb[i]; SS += sb[4+i]; }
    float mean = S / N;
    float var = SS / N - mean*mean;
    sb[0] = mean;
    sb[4] = rsqrtf(var + 1e-5f);
  }
  __syncthreads();
  float mean = sb[0], r = sb[4];
  for (int i = threadIdx.x; i < N; i += blockDim.x){
    float y = (q[i] - mean) * r;
    if (relu_out) y = (y >= 0.f) ? y : 0.2f*y;
    q[i] = y;
  }
}

// =================== bf16 hi/lo split helpers & conversion pre-passes ===================
__device__ __forceinline__ void split_bf16(float v, unsigned short& h, unsigned short& l){
  unsigned u = __float_as_uint(v);
  unsigned r = (u + 0x7FFFu + ((u >> 16) & 1u)) >> 16;   // RNE to bf16
  h = (unsigned short)r;
  float hf = __uint_as_float(r << 16);
  float lo = v - hf;
  unsigned u2 = __float_as_uint(lo);
  unsigned r2 = (u2 + 0x7FFFu + ((u2 >> 16) & 1u)) >> 16;
  l = (unsigned short)r2;
}

// src [8][C][HW] f32 -> dst [8][HW][3C] bf16, lrelu applied. blocks: 64ch x 64pix tiles
template<int C, int HW>
__global__ __launch_bounds__(256) void cvt_x_kernel(const float* __restrict__ src,
                                                    unsigned short* __restrict__ dst){
  __shared__ float tile[64][65];
  int b = blockIdx.z;
  int c0 = blockIdx.y * 64, p0 = blockIdx.x * 64;
  const float* sp = src + ((size_t)b*C + c0)*HW + p0;
  for (int i = threadIdx.x; i < 64*64; i += 256){
    int ch = i >> 6, px = i & 63;
    float v = sp[(size_t)ch*HW + px];
    tile[ch][px] = (v >= 0.f) ? v : 0.2f*v;
  }
  __syncthreads();
  unsigned short* dp = dst + ((size_t)b*HW + p0)*(3*C) + c0;
  for (int i = threadIdx.x; i < 64*64; i += 256){
    int px = i >> 6, ch = i & 63;
    float v = tile[ch][px];
    unsigned short h, l; split_bf16(v, h, l);
    unsigned short* row = dp + (size_t)px*(3*C);
    row[ch] = h; row[C + ch] = l; row[2*C + ch] = h;
  }
}

// wt [2048][C] f32 -> dst [2048][3C] bf16: [k]=h, [C+k]=h, [2C+k]=l   (C pow2)
template<int C>
__global__ __launch_bounds__(256) void cvt_w_kernel(const float* __restrict__ wt,
                                                    unsigned short* __restrict__ dst){
  int i = blockIdx.x * 256 + threadIdx.x;
  int oc = i / C, k = i & (C - 1);
  float v = wt[i];
  unsigned short h, l; split_bf16(v, h, l);
  unsigned short* row = dst + (size_t)oc * 3 * C;
  row[k] = h; row[C + k] = h; row[2*C + k] = l;
}

// grouped-conv weight split, K not pow2: wt [Ctot][K] -> dst [Ctot][3K]
template<int K>
__global__ __launch_bounds__(256) void cvt_w_g(const float* __restrict__ wt,
                                               unsigned short* __restrict__ dst, int total){
  int i = blockIdx.x * 256 + threadIdx.x;
  if (i >= total) return;
  int oc = i / K, k = i - oc*K;
  float v = wt[i];
  unsigned short h, l; split_bf16(v, h, l);
  unsigned short* row = dst + (size_t)oc * 3 * K;
  row[k] = h; row[K + k] = h; row[2*K + k] = l;
}

// gather-form padded weight split: dst[oc][kk] for kk<K:h, <2K:h, <3K:l, else 0
template<int K, int K3PAD>
__global__ __launch_bounds__(256) void cvt_w_pad(const float* __restrict__ wt,
                                                 unsigned short* __restrict__ dst, int total){
  int i = blockIdx.x * 256 + threadIdx.x;
  if (i >= total) return;
  int oc = i / K3PAD, kk = i - oc*K3PAD;
  unsigned short o = 0;
  if (kk < 3*K){
    int which = kk / K, k = kk - which*K;
    float v = wt[(size_t)oc*K + k];
    unsigned short h, l; split_bf16(v, h, l);
    o = (which == 2) ? l : h;
  }
  dst[i] = o;
}

// im2col + lrelu + hi/lo split: in [b][CIN_G*8][Hin][Hin] -> XT[g][b*64+pix][3K], Hout=8
template<int CIN_G, int Hin, int STRIDE>
__global__ __launch_bounds__(256) void cvt_im2col(const float* __restrict__ in,
                                                  unsigned short* __restrict__ dst){
  constexpr int K = CIN_G*9;
  constexpr int K3 = 3*K;
  int g = blockIdx.x, b = blockIdx.y, pc = blockIdx.z;   // pc: 16-pixel chunk
  const float* src = in + (size_t)(b*CIN_G*8 + g*CIN_G)*Hin*Hin;
  unsigned short* drow = dst + ((size_t)g*512 + b*64 + pc*16)*K3;
  for (int idx = threadIdx.x; idx < 16*K; idx += 256){
    int pixl = idx / K, k = idx - pixl*K;
    int ic = k / 9, tap = k - ic*9;
    int dh = tap / 3, dw = tap - dh*3;
    int gp = pc*16 + pixl;
    int oh = gp >> 3, ow = gp & 7;
    int ih = oh*STRIDE - 1 + dh, iw = ow*STRIDE - 1 + dw;
    float v = 0.f;
    if ((unsigned)ih < (unsigned)Hin && (unsigned)iw < (unsigned)Hin){
      v = src[((size_t)ic*Hin + ih)*Hin + iw];
      v = (v >= 0.f) ? v : 0.2f*v;
    }
    unsigned short h, l; split_bf16(v, h, l);
    unsigned short* row = drow + (size_t)pixl*K3;
    row[k] = h; row[K + k] = l; row[2*K + k] = h;
  }
}

// general im2col + lrelu + hi/lo split with K-pad, batch-sliced:
// in [b][CIN_G*8][Hin][Hin] -> dst[g][(b-b0)*HW + px][K3PAD];  grid (8, NB, HW/64)
template<int CIN_G, int Hin, int HOSH, int STRIDE, int K3PAD, int NB>
__global__ __launch_bounds__(256) void cvt_im2col_g(const float* __restrict__ in,
                                                    unsigned short* __restrict__ dst, int b0){
  constexpr int K = CIN_G*9;
  constexpr int Hout = 1 << HOSH;
  constexpr int HW = Hout*Hout;
  int g = blockIdx.x, bl = blockIdx.y, pc = blockIdx.z;   // pc: 64-px chunk
  int b = b0 + bl;
  const float* src = in + (size_t)(b*CIN_G*8 + g*CIN_G)*Hin*Hin;
  unsigned short* drow = dst + ((size_t)g*(NB*HW) + (size_t)bl*HW + pc*64)*K3PAD;
  for (int idx = threadIdx.x; idx < 64*K; idx += 256){
    int pixl = idx / K, k = idx - pixl*K;
    int ic = k / 9, tap = k - ic*9;
    int dh = tap / 3, dw = tap - dh*3;
    int gp = pc*64 + pixl;
    int oh = gp >> HOSH, ow = gp & (Hout - 1);
    int ih = oh*STRIDE - 1 + dh, iw = ow*STRIDE - 1 + dw;
    float v = 0.f;
    if ((unsigned)ih < (unsigned)Hin && (unsigned)iw < (unsigned)Hin){
      v = src[((size_t)ic*Hin + ih)*Hin + iw];
      v = (v >= 0.f) ? v : 0.2f*v;
    }
    unsigned short h, l; split_bf16(v, h, l);
    unsigned short* row = drow + (size_t)pixl*K3PAD;
    row[k] = h; row[K + k] = l; row[2*K + k] = h;
  }
  // zero the pad region [3K, K3PAD)
  for (int idx = threadIdx.x; idx < 64*(K3PAD - 3*K); idx += 256){
    int pixl = idx / (K3PAD - 3*K), k = idx - pixl*(K3PAD - 3*K);
    drow[(size_t)pixl*K3PAD + 3*K + k] = 0;
  }
}

// =================== 1x1 conv as bf16x2-split MFMA GEMM (128x128 tile) ===================
// XOR-swizzled LDS (write rr^sc8 / read row^cb, same involution both sides).
template<int K3, int HW, int H>
__global__ __launch_bounds__(256) void conv1x1_mfma(const unsigned short* __restrict__ XT,
                                                    const unsigned short* __restrict__ WT,
                                                    const float* __restrict__ bias,
                                                    float* __restrict__ out){
  constexpr int Wp = H + 2;
  constexpr int NKT = K3 / 64;
  __shared__ unsigned short As[8*128*8];   // [c8][row(oc)^c8][8k]
  __shared__ unsigned short Bs[8*128*8];   // [c8][row(pix)^c8][8k]
  int tid = threadIdx.x;
  int b = blockIdx.z;
  int oc0 = blockIdx.y * 128;
  int px0 = blockIdx.x * 128;
  int lane = tid & 63;
  int wv = tid >> 6;
  int wy = wv >> 1, wx = wv & 1;

  int srow = tid >> 3;       // 0..31, +32 per pass
  int sc8  = tid & 7;
  const unsigned short* Ag = WT + (size_t)(oc0 + srow)*K3 + sc8*8;
  const unsigned short* Bg = XT + ((size_t)b*HW + px0 + srow)*K3 + sc8*8;

  f32x4 acc[4][4];
  #pragma unroll
  for (int i = 0; i < 4; i++)
    #pragma unroll
    for (int j = 0; j < 4; j++) acc[i][j] = (f32x4){0.f,0.f,0.f,0.f};

  for (int kt = 0; kt < NKT; kt++){
    int k0 = kt * 64;
    #pragma unroll
    for (int q = 0; q < 4; q++){
      u32x4 av = *(const u32x4*)(Ag + (size_t)(32*q)*K3 + k0);
      u32x4 bv = *(const u32x4*)(Bg + (size_t)(32*q)*K3 + k0);
      int rr = srow + 32*q;
      *(u32x4*)&As[(sc8*128 + (rr ^ sc8))*8] = av;
      *(u32x4*)&Bs[(sc8*128 + (rr ^ sc8))*8] = bv;
    }
    __syncthreads();
    #pragma unroll
    for (int s = 0; s < 2; s++){
      int cb = s*4 + (lane >> 4);
      s16x8 af[4], bfr[4];
      #pragma unroll
      for (int mt = 0; mt < 4; mt++){
        int row = wy*64 + mt*16 + (lane & 15);
        af[mt] = *(const s16x8*)&As[(cb*128 + (row ^ cb))*8];
      }
      #pragma unroll
      for (int nt = 0; nt < 4; nt++){
        int row = wx*64 + nt*16 + (lane & 15);
        bfr[nt] = *(const s16x8*)&Bs[(cb*128 + (row ^ cb))*8];
      }
      #pragma unroll
      for (int mt = 0; mt < 4; mt++)
        #pragma unroll
        for (int nt = 0; nt < 4; nt++)
          acc[mt][nt] = __builtin_amdgcn_mfma_f32_16x16x32_bf16(af[mt], bfr[nt], acc[mt][nt], 0, 0, 0);
    }
    __syncthreads();
  }

  #pragma unroll
  for (int mt = 0; mt < 4; mt++){
    #pragma unroll
    for (int r = 0; r < 4; r++){
      int oc = oc0 + wy*64 + mt*16 + (lane >> 4)*4 + r;
      float bv2 = bias[oc];
      float* ob = out + ((size_t)b*2048 + oc)*Wp*Wp;
      #pragma unroll
      for (int nt = 0; nt < 4; nt++){
        int pix = px0 + wx*64 + nt*16 + (lane & 15);
        int ph = pix / H, pw2 = pix % H;
        float v = acc[mt][nt][r] + bv2;
        v = (v >= 0.f) ? v : 0.2f*v;
        ob[(size_t)(ph + 1)*Wp + pw2 + 1] = v;
      }
    }
  }
}

// =================== grouped 3x3 conv as bf16x2-split MFMA GEMM (conv5/conv6) ===================
// K-split across blockIdx.z; XOR-swizzled LDS (write & read use the same involution).
template<int K3, int COUT_G, int CTOT, int KSPLIT>
__global__ __launch_bounds__(256) void grouped_mfma(const unsigned short* __restrict__ XT,
                                                    const unsigned short* __restrict__ WT,
                                                    float* __restrict__ out, size_t pstride){
  constexpr int NKT = K3 / 64;
  constexpr int SPK = NKT / KSPLIT;
  __shared__ unsigned short As[8*128*8];
  __shared__ unsigned short Bs[8*128*8];
  int tid = threadIdx.x;
  int oc0 = blockIdx.y * 128;
  int g = oc0 / COUT_G;
  int px0 = blockIdx.x * 128;      // row within group's 512
  int ks = blockIdx.z;
  out += (size_t)ks * pstride;
  int lane = tid & 63;
  int wv = tid >> 6;
  int wy = wv >> 1, wx = wv & 1;

  int srow = tid >> 3;
  int sc8  = tid & 7;
  const unsigned short* Ag = WT + (size_t)(oc0 + srow)*K3 + sc8*8;
  const unsigned short* Bg = XT + ((size_t)g*512 + px0 + srow)*K3 + sc8*8;

  f32x4 acc[4][4];
  #pragma unroll
  for (int i = 0; i < 4; i++)
    #pragma unroll
    for (int j = 0; j < 4; j++) acc[i][j] = (f32x4){0.f,0.f,0.f,0.f};

  for (int kt = ks*SPK; kt < (ks+1)*SPK; kt++){
    int k0 = kt * 64;
    #pragma unroll
    for (int q = 0; q < 4; q++){
      u32x4 av = *(const u32x4*)(Ag + (size_t)(32*q)*K3 + k0);
      u32x4 bv = *(const u32x4*)(Bg + (size_t)(32*q)*K3 + k0);
      int rr = srow + 32*q;
      *(u32x4*)&As[(sc8*128 + (rr ^ sc8))*8] = av;
      *(u32x4*)&Bs[(sc8*128 + (rr ^ sc8))*8] = bv;
    }
    __syncthreads();
    #pragma unroll
    for (int s = 0; s < 2; s++){
      int cb = s*4 + (lane >> 4);
      s16x8 af[4], bfr[4];
      #pragma unroll
      for (int mt = 0; mt < 4; mt++){
        int row = wy*64 + mt*16 + (lane & 15);
        af[mt] = *(const s16x8*)&As[(cb*128 + (row ^ cb))*8];
      }
      #pragma unroll
      for (int nt = 0; nt < 4; nt++){
        int row = wx*64 + nt*16 + (lane & 15);
        bfr[nt] = *(const s16x8*)&Bs[(cb*128 + (row ^ cb))*8];
      }
      #pragma unroll
      for (int mt = 0; mt < 4; mt++)
        #pragma unroll
        for (int nt = 0; nt < 4; nt++)
          acc[mt][nt] = __builtin_amdgcn_mfma_f32_16x16x32_bf16(af[mt], bfr[nt], acc[mt][nt], 0, 0, 0);
    }
    __syncthreads();
  }

  #pragma unroll
  for (int mt = 0; mt < 4; mt++){
    #pragma unroll
    for (int r = 0; r < 4; r++){
      int oc = oc0 + wy*64 + mt*16 + (lane >> 4)*4 + r;
      #pragma unroll
      for (int nt = 0; nt < 4; nt++){
        int row = px0 + wx*64 + nt*16 + (lane & 15);
        int b = row >> 6, p = row & 63;
        out[((size_t)(b*CTOT + oc))*64 + p] = acc[mt][nt][r];
      }
    }
  }
}

// =================== small-M grouped MFMA GEMM (conv2/conv3): tile = COUT_G x 128 px ===================
// XOR-swizzled LDS on both operands; optional K-split (blockIdx.z) writing full partial buffers.
template<int K3PAD, int COUT_G, int CTOT, int HW, int NROWS, int KSPLIT>
__global__ __launch_bounds__(256) void gconv_mfma(const unsigned short* __restrict__ XT,
                                                  const unsigned short* __restrict__ WT,
                                                  float* __restrict__ out, int b0, size_t pstride){
  constexpr int NKT = K3PAD / 64;
  constexpr int SPK = NKT / KSPLIT;
  constexpr int MF = COUT_G / 16;
  __shared__ unsigned short As[8*COUT_G*8];   // [c8][oc_row][8]
  __shared__ unsigned short Bs[8*128*8];      // [c8][px_row][8]
  int tid = threadIdx.x;
  int g = blockIdx.y;
  int px0 = blockIdx.x * 128;
  int ks = blockIdx.z;
  out += (size_t)ks * pstride;
  int lane = tid & 63;
  int wv = tid >> 6;               // wave -> 32-px slice

  int srow = tid >> 3;             // 0..31
  int sc8  = tid & 7;
  const unsigned short* Agb = WT + (size_t)(g*COUT_G)*K3PAD + sc8*8;
  const unsigned short* Bg  = XT + ((size_t)g*NROWS + px0 + srow)*K3PAD + sc8*8;

  f32x4 acc[MF][2];
  #pragma unroll
  for (int i = 0; i < MF; i++)
    #pragma unroll
    for (int j = 0; j < 2; j++) acc[i][j] = (f32x4){0.f,0.f,0.f,0.f};

  for (int kt = ks*SPK; kt < (ks+1)*SPK; kt++){
    int k0 = kt * 64;
    #pragma unroll
    for (int q = 0; q < (COUT_G + 31)/32; q++){
      int rr = srow + 32*q;
      if (rr < COUT_G)
        *(u32x4*)&As[(sc8*COUT_G + (rr ^ sc8))*8] = *(const u32x4*)(Agb + (size_t)rr*K3PAD + k0);
    }
    #pragma unroll
    for (int q = 0; q < 4; q++){
      int rr = srow + 32*q;
      *(u32x4*)&Bs[(sc8*128 + (rr ^ sc8))*8] = *(const u32x4*)(Bg + (size_t)(32*q)*K3PAD + k0);
    }
    __syncthreads();
    #pragma unroll
    for (int s = 0; s < 2; s++){
      int cb = s*4 + (lane >> 4);
      s16x8 af[MF], bfr[2];
      #pragma unroll
      for (int mt = 0; mt < MF; mt++){
        int row = mt*16 + (lane & 15);
        af[mt] = *(const s16x8*)&As[(cb*COUT_G + (row ^ cb))*8];
      }
      #pragma unroll
      for (int nt = 0; nt < 2; nt++){
        int row = wv*32 + nt*16 + (lane & 15);
        bfr[nt] = *(const s16x8*)&Bs[(cb*128 + (row ^ cb))*8];
      }
      #pragma unroll
      for (int mt = 0; mt < MF; mt++)
        #pragma unroll
        for (int nt = 0; nt < 2; nt++)
          acc[mt][nt] = __builtin_amdgcn_mfma_f32_16x16x32_bf16(af[mt], bfr[nt], acc[mt][nt], 0, 0, 0);
    }
    __syncthreads();
  }

  #pragma unroll
  for (int mt = 0; mt < MF; mt++){
    #pragma unroll
    for (int r = 0; r < 4; r++){
      int oc = g*COUT_G + mt*16 + (lane >> 4)*4 + r;
      #pragma unroll
      for (int nt = 0; nt < 2; nt++){
        int rowg = px0 + wv*32 + nt*16 + (lane & 15);
        int bl = rowg / HW, px = rowg - bl*HW;
        out[((size_t)((b0 + bl)*CTOT + oc))*HW + px] = acc[mt][nt][r];
      }
    }
  }
}

// border cells only: out[b][oc][border of (H+2)x(H+2)] = lrelu(bias[oc])
__global__ void border_kernel(const float* __restrict__ bias, float* __restrict__ out, int H){
  int Wp = H + 2, perim = 4*Wp - 4;
  int p = threadIdx.x;
  if (p >= perim) return;
  int oc = blockIdx.y, b = blockIdx.z;
  int ph, pw;
  if (p < Wp){ ph = 0; pw = p; }
  else if (p < 2*Wp){ ph = Wp - 1; pw = p - Wp; }
  else { int q = p - 2*Wp; ph = 1 + (q >> 1); pw = (q & 1) ? (Wp - 1) : 0; }
  float bv = bias[oc];
  bv = (bv >= 0.f) ? bv : 0.2f*bv;
  out[(((size_t)b*2048 + oc)*Wp + ph)*Wp + pw] = bv;
}

// =================== host ===================
extern "C" void kernel_launch(void* const* d_in, const int* in_sizes, int n_in,
                              void* d_out, int out_size, void* d_ws, size_t ws_size,
                              hipStream_t stream){
  const float* img = (const float*)d_in[0];
  const float* sem = (const float*)d_in[1];
  Ptr6 wp;
  for (int l = 0; l < 6; l++) wp.p[l] = (const float*)d_in[2 + l];
  const float* gw1 = (const float*)d_in[8];
  const float* gb1 = (const float*)d_in[9];
  const float* gw2 = (const float*)d_in[10];
  const float* gb2 = (const float*)d_in[11];
  float* out = (float*)d_out;
  float* ws  = (float*)d_ws;

  float* bufA = out + OUT_X2;
  float* bufB = bufA + 8388608;
  float* bufC = ws + WS_OFF_C;
  float* bufD = ws + WS_OFF_D;
  int* bbox = (int*)(ws + WS_OFF_BBOX);
  // bbox flag scratch: spare tail of OUT_X2 region (used before x_2 is written)
  int* colpart = (int*)(bufB + 8388608);          // 64*8*256 ints
  int* rowflag = colpart + 64*8*256;              // 64*256 ints

  // bf16 GEMM scratch (1x1 convs):
  unsigned short* XT2 = (unsigned short*)(out + OUT_X1);             // 8*1024*768 bf16
  unsigned short* W2  = (unsigned short*)(out + OUT_X1 + 3145728);   // 2048*768 bf16
  unsigned short* XT1 = (unsigned short*)(ws + WS_OFF_W);            // 8*256*1536 bf16
  unsigned short* W1  = (unsigned short*)(ws + WS_OFF_W + 1572864);  // 2048*1536 bf16

  // bf16 GEMM scratch (grouped convs 5/6):
  unsigned short* XT5 = (unsigned short*)(bufA + 1048576);   // 8g*512*1728 bf16
  unsigned short* W5s = (unsigned short*)(bufB);             // 1024*1728 bf16
  unsigned short* XT6 = (unsigned short*)(bufA + 1048576);   // 8g*512*3456 bf16
  unsigned short* W6s = (unsigned short*)(bufB + 1048576);   // 2048*3456 bf16

  // dead tail of OUT_X2 region (past bufB; 2.16M floats, dead after bbox_stage2):
  unsigned short* W3s = (unsigned short*)(bufB + 8388608);              // 256*448 bf16 = 57,344 floats
  unsigned short* W2s = (unsigned short*)(bufB + 8388608 + 57344);      // 128*256 bf16 = 16,384 floats

  // conv2/conv3 X + raw-out scratch:
  unsigned short* X2i = (unsigned short*)bufA;               // 8g*8192*256 bf16 = 8.39M floats
  float* out2raw = out + OUT_X1;                             // 8*128*4096 = 4.19M floats
  unsigned short* X3i = (unsigned short*)bufA;               // 8g*4096*448 bf16 = 7.34M floats/slice
  float* out3raw = out + OUT_X1;                             // 8*256*1024 = 2.1M floats

  static const int kWOff[6]  = {0,1728,10944,47808,195264,785088};
  static const int kWSize[6] = {1728,9216,36864,147456,589824,2359296};

  hipMemsetAsync(ws + WS_OFF_T, 0, (WS_OFF_S2 + 8 - WS_OFF_T) * sizeof(float), stream);

  gen_u_par<<<6, 256, 0, stream>>>(ws);
  sn_t_kernel<<<252, 256, 0, stream>>>(wp, ws);
  sn_tn_kernel<<<6, 256, 0, stream>>>(ws);
  sn_z_kernel<<<1008, 256, 0, stream>>>(wp, ws);
  for (int l = 0; l < 6; l++)
    wscale_kernel<<<(kWSize[l]+255)/256, 256, 0, stream>>>(wp.p[l], ws + WS_OFF_W + kWOff[l],
                                                           kWSize[l], ws + WS_OFF_TN + l, ws + WS_OFF_S2 + l);

  bbox_stage1<<<dim3(8,8,8), 256, 0, stream>>>(img, sem, colpart, rowflag);
  bbox_stage2<<<64, 256, 0, stream>>>(colpart, rowflag, bbox);
  transimg_kernel<<<49152, 256, 0, stream>>>(img, sem, bbox, out + OUT_IMG);

  // conv1: images(8,24,256,256) -> (8,64,128,128)   [stencil tile, single-stage]
  conv3x3_tile<3,3,8,8,0><<<dim3(16,8,8), 256, 0, stream>>>(out + OUT_IMG, ws + WS_OFF_W + kWOff[0],
                                                            bufA, 256, 128);
  inorm_kernel<<<512, 256, 0, stream>>>(bufA, bufB, 16384, 0);

  // conv2 -> (8,128,64,64)   [bf16-split MFMA, 4 slices of 2 batches]
  cvt_w_pad<72,256><<<(128*256+255)/256, 256, 0, stream>>>(ws + WS_OFF_W + kWOff[1], W2s, 128*256);
  for (int s = 0; s < 4; s++){
    cvt_im2col_g<8,128,6,2,256,2><<<dim3(8,2,64), 256, 0, stream>>>(bufB, X2i, 2*s);
    gconv_mfma<256,16,128,4096,8192,1><<<dim3(64,8), 256, 0, stream>>>(X2i, W2s, out2raw, 2*s, 0);
  }
  inorm_kernel<<<1024, 256, 0, stream>>>(out2raw, bufB, 4096, 0);

  // conv3 -> out_8 (8,256,32,32)   [bf16-split MFMA, 2 slices of 4 batches]
  cvt_w_pad<144,448><<<(256*448+255)/256, 256, 0, stream>>>(ws + WS_OFF_W + kWOff[2], W3s, 256*448);
  for (int s = 0; s < 2; s++){
    cvt_im2col_g<16,64,5,2,448,4><<<dim3(8,4,16), 256, 0, stream>>>(bufB, X3i, 4*s);
    gconv_mfma<448,32,256,1024,4096,1><<<dim3(32,8), 256, 0, stream>>>(X3i, W3s, out3raw, 4*s, 0);
  }
  inorm_kernel<<<2048, 256, 0, stream>>>(out3raw, bufC, 1024, 0);

  // conv4 -> out_16 (8,512,16,16)   [im2col gemm, fp32 — r13's MFMA port regressed, reverted]
  conv3x3_gemm<2,32,64,4><<<dim3(4,1,64), 256, 0, stream>>>(bufC, ws + WS_OFF_W + kWOff[3], bufA, 32);
  inorm_kernel<<<4096, 256, 0, stream>>>(bufA, bufD, 256, 0);

  // conv5 -> out_32 (8,1024,8,8)   [bf16-split MFMA, K-split x3 -> 96 blocks]
  cvt_im2col<64,16,2><<<dim3(8,8,4), 256, 0, stream>>>(bufD, XT5);
  cvt_w_g<576><<<2304, 256, 0, stream>>>(ws + WS_OFF_W + kWOff[4], W5s, 589824);
  grouped_mfma<1728,128,1024,3><<<dim3(4,8,3), 256, 0, stream>>>(XT5, W5s, out + OUT_X1, 524288);
  inorm_sum<3><<<8192, 64, 0, stream>>>(out + OUT_X1, bufB, 64, 524288, 0);

  // conv6 -> (8,2048,8,8), stride 1   [bf16-split MFMA, K-split x6 -> 384 blocks]
  cvt_im2col<128,8,1><<<dim3(8,8,4), 256, 0, stream>>>(bufB, XT6);
  cvt_w_g<1152><<<9216, 256, 0, stream>>>(ws + WS_OFF_W + kWOff[5], W6s, 2359296);
  grouped_mfma<3456,256,2048,6><<<dim3(4,16,6), 256, 0, stream>>>(XT6, W6s, out, 1048576);
  inorm_sum<6><<<16384, 64, 0, stream>>>(out, out + OUT_X, 64, 1048576, 1);   // x

  // ---- bf16x2-split conversions for 1x1 convs (spectral weights + bufA/bufB now dead) ----
  cvt_x_kernel<256,1024><<<dim3(16,4,8), 256, 0, stream>>>(bufC, XT2);   // reads bufC first
  cvt_w_kernel<256><<<2048, 256, 0, stream>>>(gw2, W2);
  cvt_x_kernel<512,256><<<dim3(4,8,8), 256, 0, stream>>>(bufD, XT1);
  cvt_w_kernel<512><<<4096, 256, 0, stream>>>(gw1, W1);                  // may touch bufC head (dead now)

  // x_2 -> (8,2048,34,34): reads OUT_X1-region scratch, writes OUT_X2
  border_kernel<<<dim3(1,2048,8), 256, 0, stream>>>(gb2, out + OUT_X2, 32);
  conv1x1_mfma<768,1024,32><<<dim3(8,16,8), 256, 0, stream>>>(XT2, W2, gb2, out + OUT_X2);
  // x_1 -> (8,2048,18,18): reads ws scratch, overwrites OUT_X1 (XT2/W2 dead)
  border_kernel<<<dim3(1,2048,8), 256, 0, stream>>>(gb1, out + OUT_X1, 16);
  conv1x1_mfma<1536,256,16><<<dim3(2,16,8), 256, 0, stream>>>(XT1, W1, gb1, out + OUT_X1);
}

// Round 15
// 594.323 us; speedup vs baseline: 1.1140x; 1.0629x over previous
//
#include <hip/hip_runtime.h>
#include <math.h>

// ---------------- workspace layout (float indices) ----------------
#define WS_OFF_U     0
#define WS_OFF_T     4096
#define WS_OFF_TN    6400
#define WS_OFF_S2    6408
#define WS_OFF_BBOX  6416
#define WS_OFF_W     8192
#define WS_OFF_C     3152896  // out_8 normalized (2,097,152)
#define WS_OFF_D     5250048  // out_16 normalized (1,048,576)

// ---------------- d_out layout (float offsets) ----------------
#define OUT_X    0          // 8*2048*8*8     = 1,048,576
#define OUT_X1   1048576    // 8*2048*18*18   = 5,308,416
#define OUT_X2   6356992    // 8*2048*34*34   = 18,939,904 (hosts bufA/bufB scratch)
#define OUT_IMG  25296896   // 8*24*256*256   = 12,582,912

struct Ptr6 { const float* p[6]; };

typedef short s16x8 __attribute__((ext_vector_type(8)));
typedef float f32x4 __attribute__((ext_vector_type(4)));
typedef unsigned int u32x4 __attribute__((ext_vector_type(4)));

// =================== parallel MT19937 + Marsaglia polar (numpy RandomState) ===================
#define MT_UP 0x80000000u
#define MT_LO 0x7fffffffu

__global__ __launch_bounds__(256) void gen_u_par(float* ws){
  const int os[6]   = {64,128,256,512,1024,2048};
  const int uoff[6] = {0,64,192,448,960,1984};
  int l = blockIdx.x;
  int n = os[l];
  int tid = threadIdx.x;

  __shared__ unsigned mt[624];
  __shared__ unsigned draws[8192];
  __shared__ float px[2048], py[2048];
  __shared__ unsigned char accf[2048];
  __shared__ int scan[256];

  if (tid == 0){
    unsigned seed = (unsigned)(l + 1);
    for (int i = 0; i < 624; i++){
      mt[i] = seed;
      seed = 1812433253u * (seed ^ (seed >> 30)) + (unsigned)(i + 1);
    }
  }
  __syncthreads();

  int need = 4 * n;
  int twists = (need + 623) / 624;
  for (int t = 0; t < twists; t++){
    unsigned yA = 0, vA = 0;
    if (tid < 227){ yA = (mt[tid] & MT_UP) | (mt[tid+1] & MT_LO); vA = mt[tid+397]; }
    __syncthreads();
    if (tid < 227){ mt[tid] = vA ^ (yA >> 1) ^ ((yA & 1u) ? 0x9908b0dfu : 0u); }
    __syncthreads();
    unsigned yB = 0, vB = 0; int iB = 227 + tid;
    if (tid < 227){ yB = (mt[iB] & MT_UP) | (mt[iB+1] & MT_LO); vB = mt[iB-227]; }
    __syncthreads();
    if (tid < 227){ mt[iB] = vB ^ (yB >> 1) ^ ((yB & 1u) ? 0x9908b0dfu : 0u); }
    __syncthreads();
    unsigned yC = 0, vC = 0; int iC = 454 + tid;
    if (tid < 169){ yC = (mt[iC] & MT_UP) | (mt[iC+1] & MT_LO); vC = mt[iC-227]; }
    __syncthreads();
    if (tid < 169){ mt[iC] = vC ^ (yC >> 1) ^ ((yC & 1u) ? 0x9908b0dfu : 0u); }
    __syncthreads();
    if (tid == 0){
      unsigned y = (mt[623] & MT_UP) | (mt[0] & MT_LO);
      mt[623] = mt[396] ^ (y >> 1) ^ ((y & 1u) ? 0x9908b0dfu : 0u);
    }
    __syncthreads();
    for (int i = tid; i < 624; i += 256){
      int pos = t * 624 + i;
      if (pos < need){
        unsigned y = mt[i];
        y ^= y >> 11; y ^= (y << 7) & 0x9d2c5680u; y ^= (y << 15) & 0xefc60000u; y ^= y >> 18;
        draws[pos] = y;
      }
    }
    __syncthreads();
  }

  int A = (n + 255) / 256;
  int local = 0;
  for (int a = 0; a < A; a++){
    int k = tid * A + a;
    if (k < n){
      double u1 = ((draws[4*k]   >> 5) * 67108864.0 + (draws[4*k+1] >> 6)) / 9007199254740992.0;
      double u2 = ((draws[4*k+2] >> 5) * 67108864.0 + (draws[4*k+3] >> 6)) / 9007199254740992.0;
      double x1 = 2.0*u1 - 1.0, x2 = 2.0*u2 - 1.0;
      double r2 = x1*x1 + x2*x2;
      int ok = (r2 < 1.0 && r2 != 0.0);
      accf[k] = (unsigned char)ok;
      if (ok){
        double f = sqrt(-2.0 * log(r2) / r2);
        px[k] = (float)(f * x2);
        py[k] = (float)(f * x1);
      }
      local += ok;
    }
  }
  scan[tid] = local;
  __syncthreads();
  if (tid == 0){
    int run = 0;
    for (int i = 0; i < 256; i++){ int c = scan[i]; scan[i] = run; run += c; }
  }
  __syncthreads();
  int j = scan[tid];
  float* u = ws + WS_OFF_U + uoff[l];
  for (int a = 0; a < A; a++){
    int k = tid * A + a;
    if (k < n && accf[k]){
      if (2*j + 1 < n){ u[2*j] = px[k]; u[2*j+1] = py[k]; }
      j++;
    }
  }
}

// =================== spectral norm: t = M^T u ===================
__global__ __launch_bounds__(256) void sn_t_kernel(Ptr6 wp, float* ws){
  const int cols[6] = {27,72,144,288,576,1152};
  const int uoff[6] = {0,64,192,448,960,1984};
  const int toff[6] = {0,27,99,243,531,1107};
  const int cstart[7] = {0,4,12,28,60,124,252};   // 16-row chunks per layer
  int b = blockIdx.x;
  int l = 0; while (l < 5 && b >= cstart[l+1]) l++;
  int chunk = b - cstart[l];
  int r0 = chunk * 16;
  int C = cols[l];
  const float* m = wp.p[l];
  const float* u = ws + WS_OFF_U + uoff[l];
  float* t = ws + WS_OFF_T + toff[l];
  __shared__ float us[16];
  if (threadIdx.x < 16) us[threadIdx.x] = u[r0 + threadIdx.x];
  __syncthreads();
  for (int j = threadIdx.x; j < C; j += 256){
    float acc = 0.f;
    #pragma unroll
    for (int r = 0; r < 16; r++) acc += m[(size_t)(r0 + r) * C + j] * us[r];
    atomicAdd(&t[j], acc);
  }
}

__global__ void sn_tn_kernel(float* ws){
  const int cols[6] = {27,72,144,288,576,1152};
  const int toff[6] = {0,27,99,243,531,1107};
  int l = blockIdx.x;
  const float* t = ws + WS_OFF_T + toff[l];
  float s = 0.f;
  for (int j = threadIdx.x; j < cols[l]; j += 256){ float v = t[j]; s += v*v; }
  __shared__ float sb[4];
  int lane = threadIdx.x & 63, wid = threadIdx.x >> 6;
  for (int o = 32; o; o >>= 1) s += __shfl_down(s, o, 64);
  if (lane == 0) sb[wid] = s;
  __syncthreads();
  if (threadIdx.x == 0) ws[WS_OFF_TN + l] = sb[0] + sb[1] + sb[2] + sb[3];
}

// =================== spectral norm: s2 += ||M t||^2, wave-per-row ===================
__global__ __launch_bounds__(256) void sn_z_kernel(Ptr6 wp, float* ws){
  const int cols[6] = {27,72,144,288,576,1152};
  const int toff[6] = {0,27,99,243,531,1107};
  const int rstart[7] = {0,64,192,448,960,1984,4032};
  __shared__ float part[6];
  if (threadIdx.x < 6) part[threadIdx.x] = 0.f;
  __syncthreads();
  int gr = blockIdx.x * 4 + (threadIdx.x >> 6);
  int lane = threadIdx.x & 63;
  if (gr < 4032){
    int l = 0; while (l < 5 && gr >= rstart[l+1]) l++;
    int row = gr - rstart[l];
    int C = cols[l];
    const float* m = wp.p[l] + (size_t)row * C;
    const float* t = ws + WS_OFF_T + toff[l];
    float acc = 0.f;
    for (int c = lane; c < C; c += 64) acc += m[c] * t[c];
    for (int o = 32; o; o >>= 1) acc += __shfl_down(acc, o, 64);
    if (lane == 0) atomicAdd(&part[l], acc * acc);
  }
  __syncthreads();
  if (threadIdx.x < 6 && part[threadIdx.x] != 0.f)
    atomicAdd(&ws[WS_OFF_S2 + threadIdx.x], part[threadIdx.x]);
}

// all 6 layers' weight scaling in one launch (layer lookup by cumulative offset)
__global__ __launch_bounds__(256) void wscale_all(Ptr6 wp, float* ws){
  const int st[7] = {0,1728,10944,47808,195264,785088,3144384};
  int i = blockIdx.x * 256 + threadIdx.x;
  if (i >= 3144384) return;
  int l = 0;
  while (l < 5 && i >= st[l+1]) l++;
  int k = i - st[l];
  float inv = sqrtf(ws[WS_OFF_TN + l] / ws[WS_OFF_S2 + l]);
  ws[WS_OFF_W + i] = wp.p[l][k] * inv;
}

// =================== crop/resize bbox (2-stage, 512-block streaming) ===================
__global__ __launch_bounds__(256) void bbox_stage1(const float* __restrict__ img,
                                                   const float* __restrict__ sem,
                                                   int* __restrict__ colpart,
                                                   int* __restrict__ rowflag){
  int chunk = blockIdx.x;      // 0..7 -> rows [chunk*32, chunk*32+32)
  int s = blockIdx.y;
  int b = blockIdx.z;
  int w = threadIdx.x;         // column
  int h0 = chunk * 32;
  const float* i0 = img + (size_t)(b*3 + 0) * 65536;
  const float* i1 = i0 + 65536;
  const float* i2 = i1 + 65536;
  const float* mk = sem + (size_t)(b*8 + s) * 65536;
  __shared__ int rflags[32];
  if (w < 32) rflags[w] = 0;
  __syncthreads();
  int lane = w & 63;
  int myflag = 0;
  #pragma unroll 4
  for (int r = 0; r < 32; r++){
    int off = (h0 + r)*256 + w;
    float v = (i0[off] + i1[off] + i2[off]) * mk[off];
    int nz = (v != 0.f);
    myflag |= nz;
    unsigned long long bal = __ballot(nz);
    if (lane == 0 && bal) rflags[r] = 1;
  }
  __syncthreads();
  int bs = b*8 + s;
  colpart[(bs*8 + chunk)*256 + w] = myflag;
  if (w < 32) rowflag[bs*256 + h0 + w] = rflags[w];
}

__global__ __launch_bounds__(256) void bbox_stage2(const int* __restrict__ colpart,
                                                   const int* __restrict__ rowflag,
                                                   int* __restrict__ bbox){
  int bs = blockIdx.x;
  int w = threadIdx.x;
  int colnz = 0;
  #pragma unroll
  for (int c = 0; c < 8; c++) colnz |= colpart[(bs*8 + c)*256 + w];
  int rownz = rowflag[bs*256 + w];
  __shared__ int red[256];
  red[w] = colnz ? w : 256; __syncthreads();
  for (int st = 128; st; st >>= 1){ if (w < st) red[w] = min(red[w], red[w+st]); __syncthreads(); }
  int y0 = red[0]; __syncthreads();
  red[w] = colnz ? w : -1; __syncthreads();
  for (int st = 128; st; st >>= 1){ if (w < st) red[w] = max(red[w], red[w+st]); __syncthreads(); }
  int y1 = red[0]; __syncthreads();
  red[w] = rownz ? w : 256; __syncthreads();
  for (int st = 128; st; st >>= 1){ if (w < st) red[w] = min(red[w], red[w+st]); __syncthreads(); }
  int x0 = red[0]; __syncthreads();
  red[w] = rownz ? w : -1; __syncthreads();
  for (int st = 128; st; st >>= 1){ if (w < st) red[w] = max(red[w], red[w+st]); __syncthreads(); }
  int x1 = red[0];
  if (w == 0){
    int ok = (y0 < 256) && (x0 < 256);
    int base = bs * 4;
    bbox[base+0] = ok ? x0 : 0;
    bbox[base+1] = ok ? (x1 - x0 + 1) : 256;
    bbox[base+2] = ok ? y0 : 0;
    bbox[base+3] = ok ? (y1 - y0 + 1) : 256;
  }
}

__global__ void transimg_kernel(const float* __restrict__ img, const float* __restrict__ sem,
                                const int* __restrict__ bbox, float* __restrict__ out){
  int idx = blockIdx.x * 256 + threadIdx.x;
  int j = idx & 255;
  int i = (idx >> 8) & 255;
  int c = idx >> 16;
  int b = c / 24, ch24 = c % 24;
  int s = ch24 / 3, ch = ch24 % 3;
  const int* bb = bbox + (b*8 + s) * 4;
  int ri = bb[0] + ((i * bb[1]) >> 8);
  int cj = bb[2] + ((j * bb[3]) >> 8);
  float m = sem[((size_t)(b*8 + s) * 256 + ri) * 256 + cj];
  float v = img[((size_t)(b*3 + ch) * 256 + ri) * 256 + cj];
  out[idx] = v * m;
}

// =================== stencil-tiled grouped 3x3 conv (conv1, stride 2) ===================
template<int CIN_G, int CIN_CHUNK, int COUT_G, int OCC, int RELU_IN>
__global__ __launch_bounds__(256) void conv3x3_tile(const float* __restrict__ in,
                                                    const float* __restrict__ wt,
                                                    float* __restrict__ out,
                                                    int Hin, int Hout){
  constexpr int TIH = 65, TIW = 65, RS = 66;
  constexpr int NOC = COUT_G / OCC;
  constexpr int NSTAGE = CIN_G / CIN_CHUNK;
  __shared__ float xs[CIN_CHUNK][TIH][RS];
  __shared__ float wsh[OCC][CIN_CHUNK*9];
  int tid = threadIdx.x;
  int g = blockIdx.y, b = blockIdx.z;
  int ocChunk = blockIdx.x % NOC;
  int tileId  = blockIdx.x / NOC;
  int tilesX = Hout >> 5;
  int tileX = tileId % tilesX, tileY = tileId / tilesX;
  int oh0 = tileY*32, ow0 = tileX*32;
  int ih0 = oh0*2 - 1, iw0 = ow0*2 - 1;
  int sx = tid & 15, sy = tid >> 4;
  const int Cin_tot = CIN_G*8;

  float acc[OCC][2][2];
  #pragma unroll
  for (int o = 0; o < OCC; o++)
    #pragma unroll
    for (int i2 = 0; i2 < 2; i2++)
      #pragma unroll
      for (int j2 = 0; j2 < 2; j2++) acc[o][i2][j2] = 0.f;

  for (int st = 0; st < NSTAGE; st++){
    int icb = st*CIN_CHUNK;
    for (int i = tid; i < CIN_CHUNK*TIH*TIW; i += 256){
      int ic = i / (TIH*TIW);
      int rem = i - ic*(TIH*TIW);
      int r = rem / TIW, c = rem - r*TIW;
      int ih = ih0 + r, iw = iw0 + c;
      float v = 0.f;
      if ((unsigned)ih < (unsigned)Hin && (unsigned)iw < (unsigned)Hin){
        v = in[((size_t)(b*Cin_tot + g*CIN_G + icb + ic)*Hin + ih)*Hin + iw];
        if (RELU_IN) v = (v >= 0.f) ? v : 0.2f*v;
      }
      xs[ic][r][c] = v;
    }
    for (int i = tid; i < OCC*CIN_CHUNK*9; i += 256){
      int o = i / (CIN_CHUNK*9);
      int rr = i - o*(CIN_CHUNK*9);
      int ic = rr / 9, tap = rr - ic*9;
      wsh[o][rr] = wt[((size_t)(g*COUT_G + ocChunk*OCC + o)*CIN_G + icb + ic)*9 + tap];
    }
    __syncthreads();
    #pragma unroll
    for (int ic = 0; ic < CIN_CHUNK; ic++){
      #pragma unroll
      for (int kh = 0; kh < 3; kh++){
        #pragma unroll
        for (int kw = 0; kw < 3; kw++){
          float wv[OCC];
          #pragma unroll
          for (int o = 0; o < OCC; o++) wv[o] = wsh[o][ic*9 + kh*3 + kw];
          #pragma unroll
          for (int i2 = 0; i2 < 2; i2++){
            #pragma unroll
            for (int j2 = 0; j2 < 2; j2++){
              float x = xs[ic][2*(sy + 16*i2) + kh][2*(sx + 16*j2) + kw];
              #pragma unroll
              for (int o = 0; o < OCC; o++) acc[o][i2][j2] += wv[o]*x;
            }
          }
        }
      }
    }
    if (st + 1 < NSTAGE) __syncthreads();
  }

  #pragma unroll
  for (int o = 0; o < OCC; o++){
    int oc = g*COUT_G + ocChunk*OCC + o;
    #pragma unroll
    for (int i2 = 0; i2 < 2; i2++)
      #pragma unroll
      for (int j2 = 0; j2 < 2; j2++){
        int oh = oh0 + sy + 16*i2, ow = ow0 + sx + 16*j2;
        out[((size_t)(b*COUT_G*8 + oc)*Hout + oh)*Hout + ow] = acc[o][i2][j2];
      }
  }
}

// =================== im2col-GEMM grouped 3x3 conv (conv4, fp32) ===================
template<int STRIDE, int CIN_G, int COUT_G, int HSH>
__global__ __launch_bounds__(256) void conv3x3_gemm(const float* __restrict__ in,
                                                    const float* __restrict__ wt,
                                                    float* __restrict__ out,
                                                    int Hin){
  constexpr int K = CIN_G*9;
  const int Hout = 1 << HSH;
  int z = blockIdx.z; int b = z >> 3, g = z & 7;
  int n0 = blockIdx.x * 64, oc0 = blockIdx.y * 64;
  __shared__ float Ws[16][68];
  __shared__ float Xs[16][68];
  int tid = threadIdx.x;
  int tx = tid & 15, ty = tid >> 4;
  int pixl = tid & 63;
  int kkb = (tid >> 6) << 2;
  float acc[4][4];
  #pragma unroll
  for (int i = 0; i < 4; i++)
    #pragma unroll
    for (int j = 0; j < 4; j++) acc[i][j] = 0.f;

  for (int k0 = 0; k0 < K; k0 += 16){
    #pragma unroll
    for (int r = 0; r < 4; r++){
      int oc_l = (tid >> 4) + 16*r;
      int kk = tid & 15;
      Ws[kk][oc_l] = wt[((size_t)(g*COUT_G + oc0 + oc_l))*K + k0 + kk];
    }
    #pragma unroll
    for (int r = 0; r < 4; r++){
      int kk = kkb + r;
      int k = k0 + kk;
      int ic = k / 9, tap = k - ic*9;
      int dh = tap / 3, dw = tap - dh*3;
      int n = n0 + pixl;
      int oh = n >> HSH, ow = n & (Hout - 1);
      int ih = oh*STRIDE - 1 + dh, iw = ow*STRIDE - 1 + dw;
      float v = 0.f;
      if ((unsigned)ih < (unsigned)Hin && (unsigned)iw < (unsigned)Hin){
        v = in[((size_t)(b*CIN_G*8 + g*CIN_G + ic)*Hin + ih)*Hin + iw];
        v = (v >= 0.f) ? v : 0.2f*v;
      }
      Xs[kk][pixl] = v;
    }
    __syncthreads();
    #pragma unroll
    for (int kk = 0; kk < 16; kk++){
      float4 wv = *(const float4*)&Ws[kk][ty*4];
      float4 xv = *(const float4*)&Xs[kk][tx*4];
      acc[0][0] += wv.x*xv.x; acc[0][1] += wv.x*xv.y; acc[0][2] += wv.x*xv.z; acc[0][3] += wv.x*xv.w;
      acc[1][0] += wv.y*xv.x; acc[1][1] += wv.y*xv.y; acc[1][2] += wv.y*xv.z; acc[1][3] += wv.y*xv.w;
      acc[2][0] += wv.z*xv.x; acc[2][1] += wv.z*xv.y; acc[2][2] += wv.z*xv.z; acc[2][3] += wv.z*xv.w;
      acc[3][0] += wv.w*xv.x; acc[3][1] += wv.w*xv.y; acc[3][2] += wv.w*xv.z; acc[3][3] += wv.w*xv.w;
    }
    __syncthreads();
  }

  #pragma unroll
  for (int i = 0; i < 4; i++){
    int oc = g*COUT_G + oc0 + ty*4 + i;
    #pragma unroll
    for (int j = 0; j < 4; j++){
      int n = n0 + tx*4 + j;
      int oh = n >> HSH, ow = n & (Hout - 1);
      out[((size_t)(b*COUT_G*8 + oc)*Hout + oh)*Hout + ow] = acc[i][j];
    }
  }
}

// =================== instance norm (float4-vectorized when N allows) ===================
__global__ void inorm_kernel(const float* __restrict__ in, float* __restrict__ out,
                             int N, int relu_out){
  int bc = blockIdx.x;
  const float* p = in + (size_t)bc * N;
  float* q = out + (size_t)bc * N;
  float s = 0.f, ss = 0.f;
  bool vec = ((N & 3) == 0) && (N >= (int)blockDim.x * 4);
  if (vec){
    for (int i = threadIdx.x*4; i < N; i += blockDim.x*4){
      float4 x = *(const float4*)(p + i);
      s += x.x + x.y + x.z + x.w;
      ss += x.x*x.x + x.y*x.y + x.z*x.z + x.w*x.w;
    }
  } else {
    for (int i = threadIdx.x; i < N; i += blockDim.x){ float x = p[i]; s += x; ss += x*x; }
  }
  __shared__ float sb[8];
  int lane = threadIdx.x & 63, wid = threadIdx.x >> 6;
  for (int o = 32; o; o >>= 1){ s += __shfl_down(s, o, 64); ss += __shfl_down(ss, o, 64); }
  if (lane == 0){ sb[wid] = s; sb[4 + wid] = ss; }
  __syncthreads();
  if (threadIdx.x == 0){
    int nw = blockDim.x >> 6;
    float S = 0.f, SS = 0.f;
    for (int i = 0; i < nw; i++){ S += sb[i]; SS += sb[4+i]; }
    float mean = S / N;
    float var = SS / N - mean*mean;
    sb[0] = mean;
    sb[4] = rsqrtf(var + 1e-5f);
  }
  __syncthreads();
  float mean = sb[0], r = sb[4];
  if (vec){
    for (int i = threadIdx.x*4; i < N; i += blockDim.x*4){
      float4 x = *(const float4*)(p + i);
      x.x = (x.x - mean) * r; x.y = (x.y - mean) * r;
      x.z = (x.z - mean) * r; x.w = (x.w - mean) * r;
      if (relu_out){
        x.x = (x.x >= 0.f) ? x.x : 0.2f*x.x;
        x.y = (x.y >= 0.f) ? x.y : 0.2f*x.y;
        x.z = (x.z >= 0.f) ? x.z : 0.2f*x.z;
        x.w = (x.w >= 0.f) ? x.w : 0.2f*x.w;
      }
      *(float4*)(q + i) = x;
    }
  } else {
    for (int i = threadIdx.x; i < N; i += blockDim.x){
      float y = (p[i] - mean) * r;
      if (relu_out) y = (y >= 0.f) ? y : 0.2f*y;
      q[i] = y;
    }
  }
}

// instance norm over the sum of P partial buffers (K-split reduction folded in)
template<int P>
__global__ void inorm_sum(const float* __restrict__ in, float* __restrict__ out,
                          int N, size_t pstride, int relu_out){
  int bc = blockIdx.x;
  const float* p = in + (size_t)bc * N;
  float* q = out + (size_t)bc * N;
  float s = 0.f, ss = 0.f;
  for (int i = threadIdx.x; i < N; i += blockDim.x){
    float x = 0.f;
    #pragma unroll
    for (int pp = 0; pp < P; pp++) x += p[(size_t)pp*pstride + i];
    q[i] = x;                 // stash sum; normalized in second pass
    s += x; ss += x*x;
  }
  __shared__ float sb[8];
  int lane = threadIdx.x & 63, wid = threadIdx.x >> 6;
  for (int o = 32; o; o >>= 1){ s += __shfl_down(s, o, 64); ss += __shfl_down(ss, o, 64); }
  if (lane == 0){ sb[wid] = s; sb[4 + wid] = ss; }
  __syncthreads();
  if (threadIdx.x == 0){
    int nw = blockDim.x >> 6;
    float S = 0.f, SS = 0.f;
    for (int i = 0; i < nw; i++){ S += sb[i]; SS += sb[4+i]; }
    float mean = S / N;
    float var = SS / N - mean*mean;
    sb[0] = mean;
    sb[4] = rsqrtf(var + 1e-5f);
  }
  __syncthreads();
  float mean = sb[0], r = sb[4];
  for (int i = threadIdx.x; i < N; i += blockDim.x){
    float y = (q[i] - mean) * r;
    if (relu_out) y = (y >= 0.f) ? y : 0.2f*y;
    q[i] = y;
  }
}

// =================== bf16 hi/lo split helpers & conversion pre-passes ===================
__device__ __forceinline__ void split_bf16(float v, unsigned short& h, unsigned short& l){
  unsigned u = __float_as_uint(v);
  unsigned r = (u + 0x7FFFu + ((u >> 16) & 1u)) >> 16;   // RNE to bf16
  h = (unsigned short)r;
  float hf = __uint_as_float(r << 16);
  float lo = v - hf;
  unsigned u2 = __float_as_uint(lo);
  unsigned r2 = (u2 + 0x7FFFu + ((u2 >> 16) & 1u)) >> 16;
  l = (unsigned short)r2;
}

// src [8][C][HW] f32 -> dst [8][HW][3C] bf16, lrelu applied. blocks: 64ch x 64pix tiles
template<int C, int HW>
__global__ __launch_bounds__(256) void cvt_x_kernel(const float* __restrict__ src,
                                                    unsigned short* __restrict__ dst){
  __shared__ float tile[64][65];
  int b = blockIdx.z;
  int c0 = blockIdx.y * 64, p0 = blockIdx.x * 64;
  const float* sp = src + ((size_t)b*C + c0)*HW + p0;
  for (int i = threadIdx.x; i < 64*64; i += 256){
    int ch = i >> 6, px = i & 63;
    float v = sp[(size_t)ch*HW + px];
    tile[ch][px] = (v >= 0.f) ? v : 0.2f*v;
  }
  __syncthreads();
  unsigned short* dp = dst + ((size_t)b*HW + p0)*(3*C) + c0;
  for (int i = threadIdx.x; i < 64*64; i += 256){
    int px = i >> 6, ch = i & 63;
    float v = tile[ch][px];
    unsigned short h, l; split_bf16(v, h, l);
    unsigned short* row = dp + (size_t)px*(3*C);
    row[ch] = h; row[C + ch] = l; row[2*C + ch] = h;
  }
}

// wt [2048][C] f32 -> dst [2048][3C] bf16: [k]=h, [C+k]=h, [2C+k]=l   (C pow2)
template<int C>
__global__ __launch_bounds__(256) void cvt_w_kernel(const float* __restrict__ wt,
                                                    unsigned short* __restrict__ dst){
  int i = blockIdx.x * 256 + threadIdx.x;
  int oc = i / C, k = i & (C - 1);
  float v = wt[i];
  unsigned short h, l; split_bf16(v, h, l);
  unsigned short* row = dst + (size_t)oc * 3 * C;
  row[k] = h; row[C + k] = h; row[2*C + k] = l;
}

// grouped-conv weight split, K not pow2: wt [Ctot][K] -> dst [Ctot][3K]
template<int K>
__global__ __launch_bounds__(256) void cvt_w_g(const float* __restrict__ wt,
                                               unsigned short* __restrict__ dst, int total){
  int i = blockIdx.x * 256 + threadIdx.x;
  if (i >= total) return;
  int oc = i / K, k = i - oc*K;
  float v = wt[i];
  unsigned short h, l; split_bf16(v, h, l);
  unsigned short* row = dst + (size_t)oc * 3 * K;
  row[k] = h; row[K + k] = h; row[2*K + k] = l;
}

// gather-form padded weight split: dst[oc][kk] for kk<K:h, <2K:h, <3K:l, else 0
template<int K, int K3PAD>
__global__ __launch_bounds__(256) void cvt_w_pad(const float* __restrict__ wt,
                                                 unsigned short* __restrict__ dst, int total){
  int i = blockIdx.x * 256 + threadIdx.x;
  if (i >= total) return;
  int oc = i / K3PAD, kk = i - oc*K3PAD;
  unsigned short o = 0;
  if (kk < 3*K){
    int which = kk / K, k = kk - which*K;
    float v = wt[(size_t)oc*K + k];
    unsigned short h, l; split_bf16(v, h, l);
    o = (which == 2) ? l : h;
  }
  dst[i] = o;
}

// im2col + lrelu + hi/lo split: in [b][CIN_G*8][Hin][Hin] -> XT[g][b*64+pix][3K], Hout=8
template<int CIN_G, int Hin, int STRIDE>
__global__ __launch_bounds__(256) void cvt_im2col(const float* __restrict__ in,
                                                  unsigned short* __restrict__ dst){
  constexpr int K = CIN_G*9;
  constexpr int K3 = 3*K;
  int g = blockIdx.x, b = blockIdx.y, pc = blockIdx.z;   // pc: 16-pixel chunk
  const float* src = in + (size_t)(b*CIN_G*8 + g*CIN_G)*Hin*Hin;
  unsigned short* drow = dst + ((size_t)g*512 + b*64 + pc*16)*K3;
  for (int idx = threadIdx.x; idx < 16*K; idx += 256){
    int pixl = idx / K, k = idx - pixl*K;
    int ic = k / 9, tap = k - ic*9;
    int dh = tap / 3, dw = tap - dh*3;
    int gp = pc*16 + pixl;
    int oh = gp >> 3, ow = gp & 7;
    int ih = oh*STRIDE - 1 + dh, iw = ow*STRIDE - 1 + dw;
    float v = 0.f;
    if ((unsigned)ih < (unsigned)Hin && (unsigned)iw < (unsigned)Hin){
      v = src[((size_t)ic*Hin + ih)*Hin + iw];
      v = (v >= 0.f) ? v : 0.2f*v;
    }
    unsigned short h, l; split_bf16(v, h, l);
    unsigned short* row = drow + (size_t)pixl*K3;
    row[k] = h; row[K + k] = l; row[2*K + k] = h;
  }
}

// general im2col + lrelu + hi/lo split with K-pad, batch-sliced:
// in [b][CIN_G*8][Hin][Hin] -> dst[g][(b-b0)*HW + px][K3PAD];  grid (8, NB, HW/64)
template<int CIN_G, int Hin, int HOSH, int STRIDE, int K3PAD, int NB>
__global__ __launch_bounds__(256) void cvt_im2col_g(const float* __restrict__ in,
                                                    unsigned short* __restrict__ dst, int b0){
  constexpr int K = CIN_G*9;
  constexpr int Hout = 1 << HOSH;
  constexpr int HW = Hout*Hout;
  int g = blockIdx.x, bl = blockIdx.y, pc = blockIdx.z;   // pc: 64-px chunk
  int b = b0 + bl;
  const float* src = in + (size_t)(b*CIN_G*8 + g*CIN_G)*Hin*Hin;
  unsigned short* drow = dst + ((size_t)g*(NB*HW) + (size_t)bl*HW + pc*64)*K3PAD;
  for (int idx = threadIdx.x; idx < 64*K; idx += 256){
    int pixl = idx / K, k = idx - pixl*K;
    int ic = k / 9, tap = k - ic*9;
    int dh = tap / 3, dw = tap - dh*3;
    int gp = pc*64 + pixl;
    int oh = gp >> HOSH, ow = gp & (Hout - 1);
    int ih = oh*STRIDE - 1 + dh, iw = ow*STRIDE - 1 + dw;
    float v = 0.f;
    if ((unsigned)ih < (unsigned)Hin && (unsigned)iw < (unsigned)Hin){
      v = src[((size_t)ic*Hin + ih)*Hin + iw];
      v = (v >= 0.f) ? v : 0.2f*v;
    }
    unsigned short h, l; split_bf16(v, h, l);
    unsigned short* row = drow + (size_t)pixl*K3PAD;
    row[k] = h; row[K + k] = l; row[2*K + k] = h;
  }
  // zero the pad region [3K, K3PAD)
  for (int idx = threadIdx.x; idx < 64*(K3PAD - 3*K); idx += 256){
    int pixl = idx / (K3PAD - 3*K), k = idx - pixl*(K3PAD - 3*K);
    drow[(size_t)pixl*K3PAD + 3*K + k] = 0;
  }
}

// =================== 1x1 conv as bf16x2-split MFMA GEMM (128x128 tile) ===================
// XOR-swizzled LDS (write rr^sc8 / read row^cb, same involution both sides).
template<int K3, int HW, int H>
__global__ __launch_bounds__(256) void conv1x1_mfma(const unsigned short* __restrict__ XT,
                                                    const unsigned short* __restrict__ WT,
                                                    const float* __restrict__ bias,
                                                    float* __restrict__ out){
  constexpr int Wp = H + 2;
  constexpr int NKT = K3 / 64;
  __shared__ unsigned short As[8*128*8];   // [c8][row(oc)^c8][8k]
  __shared__ unsigned short Bs[8*128*8];   // [c8][row(pix)^c8][8k]
  int tid = threadIdx.x;
  int b = blockIdx.z;
  int oc0 = blockIdx.y * 128;
  int px0 = blockIdx.x * 128;
  int lane = tid & 63;
  int wv = tid >> 6;
  int wy = wv >> 1, wx = wv & 1;

  int srow = tid >> 3;       // 0..31, +32 per pass
  int sc8  = tid & 7;
  const unsigned short* Ag = WT + (size_t)(oc0 + srow)*K3 + sc8*8;
  const unsigned short* Bg = XT + ((size_t)b*HW + px0 + srow)*K3 + sc8*8;

  f32x4 acc[4][4];
  #pragma unroll
  for (int i = 0; i < 4; i++)
    #pragma unroll
    for (int j = 0; j < 4; j++) acc[i][j] = (f32x4){0.f,0.f,0.f,0.f};

  for (int kt = 0; kt < NKT; kt++){
    int k0 = kt * 64;
    #pragma unroll
    for (int q = 0; q < 4; q++){
      u32x4 av = *(const u32x4*)(Ag + (size_t)(32*q)*K3 + k0);
      u32x4 bv = *(const u32x4*)(Bg + (size_t)(32*q)*K3 + k0);
      int rr = srow + 32*q;
      *(u32x4*)&As[(sc8*128 + (rr ^ sc8))*8] = av;
      *(u32x4*)&Bs[(sc8*128 + (rr ^ sc8))*8] = bv;
    }
    __syncthreads();
    #pragma unroll
    for (int s = 0; s < 2; s++){
      int cb = s*4 + (lane >> 4);
      s16x8 af[4], bfr[4];
      #pragma unroll
      for (int mt = 0; mt < 4; mt++){
        int row = wy*64 + mt*16 + (lane & 15);
        af[mt] = *(const s16x8*)&As[(cb*128 + (row ^ cb))*8];
      }
      #pragma unroll
      for (int nt = 0; nt < 4; nt++){
        int row = wx*64 + nt*16 + (lane & 15);
        bfr[nt] = *(const s16x8*)&Bs[(cb*128 + (row ^ cb))*8];
      }
      #pragma unroll
      for (int mt = 0; mt < 4; mt++)
        #pragma unroll
        for (int nt = 0; nt < 4; nt++)
          acc[mt][nt] = __builtin_amdgcn_mfma_f32_16x16x32_bf16(af[mt], bfr[nt], acc[mt][nt], 0, 0, 0);
    }
    __syncthreads();
  }

  #pragma unroll
  for (int mt = 0; mt < 4; mt++){
    #pragma unroll
    for (int r = 0; r < 4; r++){
      int oc = oc0 + wy*64 + mt*16 + (lane >> 4)*4 + r;
      float bv2 = bias[oc];
      float* ob = out + ((size_t)b*2048 + oc)*Wp*Wp;
      #pragma unroll
      for (int nt = 0; nt < 4; nt++){
        int pix = px0 + wx*64 + nt*16 + (lane & 15);
        int ph = pix / H, pw2 = pix % H;
        float v = acc[mt][nt][r] + bv2;
        v = (v >= 0.f) ? v : 0.2f*v;
        ob[(size_t)(ph + 1)*Wp + pw2 + 1] = v;
      }
    }
  }
}

// =================== grouped 3x3 conv as bf16x2-split MFMA GEMM (conv5/conv6) ===================
// K-split across blockIdx.z; XOR-swizzled LDS (write & read use the same involution).
template<int K3, int COUT_G, int CTOT, int KSPLIT>
__global__ __launch_bounds__(256) void grouped_mfma(const unsigned short* __restrict__ XT,
                                                    const unsigned short* __restrict__ WT,
                                                    float* __restrict__ out, size_t pstride){
  constexpr int NKT = K3 / 64;
  constexpr int SPK = NKT / KSPLIT;
  __shared__ unsigned short As[8*128*8];
  __shared__ unsigned short Bs[8*128*8];
  int tid = threadIdx.x;
  int oc0 = blockIdx.y * 128;
  int g = oc0 / COUT_G;
  int px0 = blockIdx.x * 128;      // row within group's 512
  int ks = blockIdx.z;
  out += (size_t)ks * pstride;
  int lane = tid & 63;
  int wv = tid >> 6;
  int wy = wv >> 1, wx = wv & 1;

  int srow = tid >> 3;
  int sc8  = tid & 7;
  const unsigned short* Ag = WT + (size_t)(oc0 + srow)*K3 + sc8*8;
  const unsigned short* Bg = XT + ((size_t)g*512 + px0 + srow)*K3 + sc8*8;

  f32x4 acc[4][4];
  #pragma unroll
  for (int i = 0; i < 4; i++)
    #pragma unroll
    for (int j = 0; j < 4; j++) acc[i][j] = (f32x4){0.f,0.f,0.f,0.f};

  for (int kt = ks*SPK; kt < (ks+1)*SPK; kt++){
    int k0 = kt * 64;
    #pragma unroll
    for (int q = 0; q < 4; q++){
      u32x4 av = *(const u32x4*)(Ag + (size_t)(32*q)*K3 + k0);
      u32x4 bv = *(const u32x4*)(Bg + (size_t)(32*q)*K3 + k0);
      int rr = srow + 32*q;
      *(u32x4*)&As[(sc8*128 + (rr ^ sc8))*8] = av;
      *(u32x4*)&Bs[(sc8*128 + (rr ^ sc8))*8] = bv;
    }
    __syncthreads();
    #pragma unroll
    for (int s = 0; s < 2; s++){
      int cb = s*4 + (lane >> 4);
      s16x8 af[4], bfr[4];
      #pragma unroll
      for (int mt = 0; mt < 4; mt++){
        int row = wy*64 + mt*16 + (lane & 15);
        af[mt] = *(const s16x8*)&As[(cb*128 + (row ^ cb))*8];
      }
      #pragma unroll
      for (int nt = 0; nt < 4; nt++){
        int row = wx*64 + nt*16 + (lane & 15);
        bfr[nt] = *(const s16x8*)&Bs[(cb*128 + (row ^ cb))*8];
      }
      #pragma unroll
      for (int mt = 0; mt < 4; mt++)
        #pragma unroll
        for (int nt = 0; nt < 4; nt++)
          acc[mt][nt] = __builtin_amdgcn_mfma_f32_16x16x32_bf16(af[mt], bfr[nt], acc[mt][nt], 0, 0, 0);
    }
    __syncthreads();
  }

  #pragma unroll
  for (int mt = 0; mt < 4; mt++){
    #pragma unroll
    for (int r = 0; r < 4; r++){
      int oc = oc0 + wy*64 + mt*16 + (lane >> 4)*4 + r;
      #pragma unroll
      for (int nt = 0; nt < 4; nt++){
        int row = px0 + wx*64 + nt*16 + (lane & 15);
        int b = row >> 6, p = row & 63;
        out[((size_t)(b*CTOT + oc))*64 + p] = acc[mt][nt][r];
      }
    }
  }
}

// =================== small-M grouped MFMA GEMM (conv2/conv3): tile = COUT_G x 128 px ===================
// XOR-swizzled LDS on both operands; optional K-split (blockIdx.z) writing full partial buffers.
template<int K3PAD, int COUT_G, int CTOT, int HW, int NROWS, int KSPLIT>
__global__ __launch_bounds__(256) void gconv_mfma(const unsigned short* __restrict__ XT,
                                                  const unsigned short* __restrict__ WT,
                                                  float* __restrict__ out, int b0, size_t pstride){
  constexpr int NKT = K3PAD / 64;
  constexpr int SPK = NKT / KSPLIT;
  constexpr int MF = COUT_G / 16;
  __shared__ unsigned short As[8*COUT_G*8];   // [c8][oc_row][8]
  __shared__ unsigned short Bs[8*128*8];      // [c8][px_row][8]
  int tid = threadIdx.x;
  int g = blockIdx.y;
  int px0 = blockIdx.x * 128;
  int ks = blockIdx.z;
  out += (size_t)ks * pstride;
  int lane = tid & 63;
  int wv = tid >> 6;               // wave -> 32-px slice

  int srow = tid >> 3;             // 0..31
  int sc8  = tid & 7;
  const unsigned short* Agb = WT + (size_t)(g*COUT_G)*K3PAD + sc8*8;
  const unsigned short* Bg  = XT + ((size_t)g*NROWS + px0 + srow)*K3PAD + sc8*8;

  f32x4 acc[MF][2];
  #pragma unroll
  for (int i = 0; i < MF; i++)
    #pragma unroll
    for (int j = 0; j < 2; j++) acc[i][j] = (f32x4){0.f,0.f,0.f,0.f};

  for (int kt = ks*SPK; kt < (ks+1)*SPK; kt++){
    int k0 = kt * 64;
    #pragma unroll
    for (int q = 0; q < (COUT_G + 31)/32; q++){
      int rr = srow + 32*q;
      if (rr < COUT_G)
        *(u32x4*)&As[(sc8*COUT_G + (rr ^ sc8))*8] = *(const u32x4*)(Agb + (size_t)rr*K3PAD + k0);
    }
    #pragma unroll
    for (int q = 0; q < 4; q++){
      int rr = srow + 32*q;
      *(u32x4*)&Bs[(sc8*128 + (rr ^ sc8))*8] = *(const u32x4*)(Bg + (size_t)(32*q)*K3PAD + k0);
    }
    __syncthreads();
    #pragma unroll
    for (int s = 0; s < 2; s++){
      int cb = s*4 + (lane >> 4);
      s16x8 af[MF], bfr[2];
      #pragma unroll
      for (int mt = 0; mt < MF; mt++){
        int row = mt*16 + (lane & 15);
        af[mt] = *(const s16x8*)&As[(cb*COUT_G + (row ^ cb))*8];
      }
      #pragma unroll
      for (int nt = 0; nt < 2; nt++){
        int row = wv*32 + nt*16 + (lane & 15);
        bfr[nt] = *(const s16x8*)&Bs[(cb*128 + (row ^ cb))*8];
      }
      #pragma unroll
      for (int mt = 0; mt < MF; mt++)
        #pragma unroll
        for (int nt = 0; nt < 2; nt++)
          acc[mt][nt] = __builtin_amdgcn_mfma_f32_16x16x32_bf16(af[mt], bfr[nt], acc[mt][nt], 0, 0, 0);
    }
    __syncthreads();
  }

  #pragma unroll
  for (int mt = 0; mt < MF; mt++){
    #pragma unroll
    for (int r = 0; r < 4; r++){
      int oc = g*COUT_G + mt*16 + (lane >> 4)*4 + r;
      #pragma unroll
      for (int nt = 0; nt < 2; nt++){
        int rowg = px0 + wv*32 + nt*16 + (lane & 15);
        int bl = rowg / HW, px = rowg - bl*HW;
        out[((size_t)((b0 + bl)*CTOT + oc))*HW + px] = acc[mt][nt][r];
      }
    }
  }
}

// border cells only, flat indexing: 1 thread per (b, oc, perim-cell)
__global__ void border_kernel(const float* __restrict__ bias, float* __restrict__ out, int H){
  int Wp = H + 2, perim = 4*Wp - 4;
  int total = 8 * 2048 * perim;
  int idx = blockIdx.x * 256 + threadIdx.x;
  if (idx >= total) return;
  int p = idx % perim;
  int rest = idx / perim;
  int oc = rest & 2047;
  int b = rest >> 11;
  int ph, pw;
  if (p < Wp){ ph = 0; pw = p; }
  else if (p < 2*Wp){ ph = Wp - 1; pw = p - Wp; }
  else { int q = p - 2*Wp; ph = 1 + (q >> 1); pw = (q & 1) ? (Wp - 1) : 0; }
  float bv = bias[oc];
  bv = (bv >= 0.f) ? bv : 0.2f*bv;
  out[(((size_t)b*2048 + oc)*Wp + ph)*Wp + pw] = bv;
}

// =================== host ===================
extern "C" void kernel_launch(void* const* d_in, const int* in_sizes, int n_in,
                              void* d_out, int out_size, void* d_ws, size_t ws_size,
                              hipStream_t stream){
  const float* img = (const float*)d_in[0];
  const float* sem = (const float*)d_in[1];
  Ptr6 wp;
  for (int l = 0; l < 6; l++) wp.p[l] = (const float*)d_in[2 + l];
  const float* gw1 = (const float*)d_in[8];
  const float* gb1 = (const float*)d_in[9];
  const float* gw2 = (const float*)d_in[10];
  const float* gb2 = (const float*)d_in[11];
  float* out = (float*)d_out;
  float* ws  = (float*)d_ws;

  float* bufA = out + OUT_X2;
  float* bufB = bufA + 8388608;
  float* bufC = ws + WS_OFF_C;
  float* bufD = ws + WS_OFF_D;
  int* bbox = (int*)(ws + WS_OFF_BBOX);
  // bbox flag scratch: spare tail of OUT_X2 region (used before x_2 is written)
  int* colpart = (int*)(bufB + 8388608);          // 64*8*256 ints
  int* rowflag = colpart + 64*8*256;              // 64*256 ints

  // bf16 GEMM scratch (1x1 convs):
  unsigned short* XT2 = (unsigned short*)(out + OUT_X1);             // 8*1024*768 bf16
  unsigned short* W2  = (unsigned short*)(out + OUT_X1 + 3145728);   // 2048*768 bf16
  unsigned short* XT1 = (unsigned short*)(ws + WS_OFF_W);            // 8*256*1536 bf16
  unsigned short* W1  = (unsigned short*)(ws + WS_OFF_W + 1572864);  // 2048*1536 bf16

  // bf16 GEMM scratch (grouped convs 5/6):
  unsigned short* XT5 = (unsigned short*)(bufA + 1048576);   // 8g*512*1728 bf16
  unsigned short* W5s = (unsigned short*)(bufB);             // 1024*1728 bf16
  unsigned short* XT6 = (unsigned short*)(bufA + 1048576);   // 8g*512*3456 bf16
  unsigned short* W6s = (unsigned short*)(bufB + 1048576);   // 2048*3456 bf16

  // dead tail of OUT_X2 region (past bufB; 2.16M floats, dead after bbox_stage2):
  unsigned short* W3s = (unsigned short*)(bufB + 8388608);              // 256*448 bf16 = 57,344 floats
  unsigned short* W2s = (unsigned short*)(bufB + 8388608 + 57344);      // 128*256 bf16 = 16,384 floats

  // conv2/conv3 X + raw-out scratch:
  unsigned short* X2i = (unsigned short*)bufA;               // 8g*8192*256 bf16 = 8.39M floats
  float* out2raw = out + OUT_X1;                             // 8*128*4096 = 4.19M floats
  unsigned short* X3i = (unsigned short*)bufA;               // 8g*4096*448 bf16 = 7.34M floats/slice
  float* out3raw = out + OUT_X1;                             // 8*256*1024 = 2.1M floats

  static const int kWOff[6]  = {0,1728,10944,47808,195264,785088};

  hipMemsetAsync(ws + WS_OFF_T, 0, (WS_OFF_S2 + 8 - WS_OFF_T) * sizeof(float), stream);

  gen_u_par<<<6, 256, 0, stream>>>(ws);
  sn_t_kernel<<<252, 256, 0, stream>>>(wp, ws);
  sn_tn_kernel<<<6, 256, 0, stream>>>(ws);
  sn_z_kernel<<<1008, 256, 0, stream>>>(wp, ws);
  wscale_all<<<(3144384 + 255)/256, 256, 0, stream>>>(wp, ws);

  bbox_stage1<<<dim3(8,8,8), 256, 0, stream>>>(img, sem, colpart, rowflag);
  bbox_stage2<<<64, 256, 0, stream>>>(colpart, rowflag, bbox);
  transimg_kernel<<<49152, 256, 0, stream>>>(img, sem, bbox, out + OUT_IMG);

  // conv1: images(8,24,256,256) -> (8,64,128,128)   [stencil tile, single-stage]
  conv3x3_tile<3,3,8,8,0><<<dim3(16,8,8), 256, 0, stream>>>(out + OUT_IMG, ws + WS_OFF_W + kWOff[0],
                                                            bufA, 256, 128);
  inorm_kernel<<<512, 256, 0, stream>>>(bufA, bufB, 16384, 0);

  // conv2 -> (8,128,64,64)   [bf16-split MFMA, 4 slices of 2 batches]
  cvt_w_pad<72,256><<<(128*256+255)/256, 256, 0, stream>>>(ws + WS_OFF_W + kWOff[1], W2s, 128*256);
  for (int s = 0; s < 4; s++){
    cvt_im2col_g<8,128,6,2,256,2><<<dim3(8,2,64), 256, 0, stream>>>(bufB, X2i, 2*s);
    gconv_mfma<256,16,128,4096,8192,1><<<dim3(64,8), 256, 0, stream>>>(X2i, W2s, out2raw, 2*s, 0);
  }
  inorm_kernel<<<1024, 256, 0, stream>>>(out2raw, bufB, 4096, 0);

  // conv3 -> out_8 (8,256,32,32)   [bf16-split MFMA, 2 slices of 4 batches]
  cvt_w_pad<144,448><<<(256*448+255)/256, 256, 0, stream>>>(ws + WS_OFF_W + kWOff[2], W3s, 256*448);
  for (int s = 0; s < 2; s++){
    cvt_im2col_g<16,64,5,2,448,4><<<dim3(8,4,16), 256, 0, stream>>>(bufB, X3i, 4*s);
    gconv_mfma<448,32,256,1024,4096,1><<<dim3(32,8), 256, 0, stream>>>(X3i, W3s, out3raw, 4*s, 0);
  }
  inorm_kernel<<<2048, 256, 0, stream>>>(out3raw, bufC, 1024, 0);

  // conv4 -> out_16 (8,512,16,16)   [im2col gemm, fp32]
  conv3x3_gemm<2,32,64,4><<<dim3(4,1,64), 256, 0, stream>>>(bufC, ws + WS_OFF_W + kWOff[3], bufA, 32);
  inorm_kernel<<<4096, 256, 0, stream>>>(bufA, bufD, 256, 0);

  // conv5 -> out_32 (8,1024,8,8)   [bf16-split MFMA, K-split x3 -> 96 blocks]
  cvt_im2col<64,16,2><<<dim3(8,8,4), 256, 0, stream>>>(bufD, XT5);
  cvt_w_g<576><<<2304, 256, 0, stream>>>(ws + WS_OFF_W + kWOff[4], W5s, 589824);
  grouped_mfma<1728,128,1024,3><<<dim3(4,8,3), 256, 0, stream>>>(XT5, W5s, out + OUT_X1, 524288);
  inorm_sum<3><<<8192, 64, 0, stream>>>(out + OUT_X1, bufB, 64, 524288, 0);

  // conv6 -> (8,2048,8,8), stride 1   [bf16-split MFMA, K-split x6 -> 384 blocks]
  cvt_im2col<128,8,1><<<dim3(8,8,4), 256, 0, stream>>>(bufB, XT6);
  cvt_w_g<1152><<<9216, 256, 0, stream>>>(ws + WS_OFF_W + kWOff[5], W6s, 2359296);
  grouped_mfma<3456,256,2048,6><<<dim3(4,16,6), 256, 0, stream>>>(XT6, W6s, out, 1048576);
  inorm_sum<6><<<16384, 64, 0, stream>>>(out, out + OUT_X, 64, 1048576, 1);   // x

  // ---- bf16x2-split conversions for 1x1 convs (spectral weights + bufA/bufB now dead) ----
  cvt_x_kernel<256,1024><<<dim3(16,4,8), 256, 0, stream>>>(bufC, XT2);   // reads bufC first
  cvt_w_kernel<256><<<2048, 256, 0, stream>>>(gw2, W2);
  cvt_x_kernel<512,256><<<dim3(4,8,8), 256, 0, stream>>>(bufD, XT1);
  cvt_w_kernel<512><<<4096, 256, 0, stream>>>(gw1, W1);                  // may touch bufC head (dead now)

  // x_2 -> (8,2048,34,34): reads OUT_X1-region scratch, writes OUT_X2
  border_kernel<<<(8*2048*132 + 255)/256, 256, 0, stream>>>(gb2, out + OUT_X2, 32);
  conv1x1_mfma<768,1024,32><<<dim3(8,16,8), 256, 0, stream>>>(XT2, W2, gb2, out + OUT_X2);
  // x_1 -> (8,2048,18,18): reads ws scratch, overwrites OUT_X1 (XT2/W2 dead)
  border_kernel<<<(8*2048*68 + 255)/256, 256, 0, stream>>>(gb1, out + OUT_X1, 16);
  conv1x1_mfma<1536,256,16><<<dim3(2,16,8), 256, 0, stream>>>(XT1, W1, gb1, out + OUT_X1);
}

// Round 16
// 563.738 us; speedup vs baseline: 1.1745x; 1.0543x over previous
//
#include <hip/hip_runtime.h>
#include <math.h>

// ---------------- workspace layout (float indices) ----------------
#define WS_OFF_U     0
#define WS_OFF_T     4096
#define WS_OFF_TN    6400
#define WS_OFF_S2    6408
#define WS_OFF_BBOX  6416
#define WS_OFF_W     8192
#define WS_OFF_C     3152896  // out_8 normalized (2,097,152)
#define WS_OFF_D     5250048  // out_16 normalized (1,048,576)

// ---------------- d_out layout (float offsets) ----------------
#define OUT_X    0          // 8*2048*8*8     = 1,048,576
#define OUT_X1   1048576    // 8*2048*18*18   = 5,308,416
#define OUT_X2   6356992    // 8*2048*34*34   = 18,939,904 (hosts bufA/bufB scratch)
#define OUT_IMG  25296896   // 8*24*256*256   = 12,582,912

struct Ptr6 { const float* p[6]; };

typedef short s16x8 __attribute__((ext_vector_type(8)));
typedef float f32x4 __attribute__((ext_vector_type(4)));
typedef unsigned int u32x4 __attribute__((ext_vector_type(4)));

#define MT_UP 0x80000000u
#define MT_LO 0x7fffffffu

// =================== spectral norm: t = M^T u ===================
__global__ __launch_bounds__(256) void sn_t_kernel(Ptr6 wp, float* ws){
  const int cols[6] = {27,72,144,288,576,1152};
  const int uoff[6] = {0,64,192,448,960,1984};
  const int toff[6] = {0,27,99,243,531,1107};
  const int cstart[7] = {0,4,12,28,60,124,252};   // 16-row chunks per layer
  int b = blockIdx.x;
  int l = 0; while (l < 5 && b >= cstart[l+1]) l++;
  int chunk = b - cstart[l];
  int r0 = chunk * 16;
  int C = cols[l];
  const float* m = wp.p[l];
  const float* u = ws + WS_OFF_U + uoff[l];
  float* t = ws + WS_OFF_T + toff[l];
  __shared__ float us[16];
  if (threadIdx.x < 16) us[threadIdx.x] = u[r0 + threadIdx.x];
  __syncthreads();
  for (int j = threadIdx.x; j < C; j += 256){
    float acc = 0.f;
    #pragma unroll
    for (int r = 0; r < 16; r++) acc += m[(size_t)(r0 + r) * C + j] * us[r];
    atomicAdd(&t[j], acc);
  }
}

__global__ void sn_tn_kernel(float* ws){
  const int cols[6] = {27,72,144,288,576,1152};
  const int toff[6] = {0,27,99,243,531,1107};
  int l = blockIdx.x;
  const float* t = ws + WS_OFF_T + toff[l];
  float s = 0.f;
  for (int j = threadIdx.x; j < cols[l]; j += 256){ float v = t[j]; s += v*v; }
  __shared__ float sb[4];
  int lane = threadIdx.x & 63, wid = threadIdx.x >> 6;
  for (int o = 32; o; o >>= 1) s += __shfl_down(s, o, 64);
  if (lane == 0) sb[wid] = s;
  __syncthreads();
  if (threadIdx.x == 0) ws[WS_OFF_TN + l] = sb[0] + sb[1] + sb[2] + sb[3];
}

// =================== spectral norm: s2 += ||M t||^2, wave-per-row ===================
__global__ __launch_bounds__(256) void sn_z_kernel(Ptr6 wp, float* ws){
  const int cols[6] = {27,72,144,288,576,1152};
  const int toff[6] = {0,27,99,243,531,1107};
  const int rstart[7] = {0,64,192,448,960,1984,4032};
  __shared__ float part[6];
  if (threadIdx.x < 6) part[threadIdx.x] = 0.f;
  __syncthreads();
  int gr = blockIdx.x * 4 + (threadIdx.x >> 6);
  int lane = threadIdx.x & 63;
  if (gr < 4032){
    int l = 0; while (l < 5 && gr >= rstart[l+1]) l++;
    int row = gr - rstart[l];
    int C = cols[l];
    const float* m = wp.p[l] + (size_t)row * C;
    const float* t = ws + WS_OFF_T + toff[l];
    float acc = 0.f;
    for (int c = lane; c < C; c += 64) acc += m[c] * t[c];
    for (int o = 32; o; o >>= 1) acc += __shfl_down(acc, o, 64);
    if (lane == 0) atomicAdd(&part[l], acc * acc);
  }
  __syncthreads();
  if (threadIdx.x < 6 && part[threadIdx.x] != 0.f)
    atomicAdd(&ws[WS_OFF_S2 + threadIdx.x], part[threadIdx.x]);
}

// all 6 layers' weight scaling in one launch (layer lookup by cumulative offset)
__global__ __launch_bounds__(256) void wscale_all(Ptr6 wp, float* ws){
  const int st[7] = {0,1728,10944,47808,195264,785088,3144384};
  int i = blockIdx.x * 256 + threadIdx.x;
  if (i >= 3144384) return;
  int l = 0;
  while (l < 5 && i >= st[l+1]) l++;
  int k = i - st[l];
  float inv = sqrtf(ws[WS_OFF_TN + l] / ws[WS_OFF_S2 + l]);
  ws[WS_OFF_W + i] = wp.p[l][k] * inv;
}

// =================== crop/resize bbox (2-stage, 512-block streaming) ===================
__global__ __launch_bounds__(256) void bbox_stage1(const float* __restrict__ img,
                                                   const float* __restrict__ sem,
                                                   int* __restrict__ colpart,
                                                   int* __restrict__ rowflag){
  int chunk = blockIdx.x;      // 0..7 -> rows [chunk*32, chunk*32+32)
  int s = blockIdx.y;
  int b = blockIdx.z;
  int w = threadIdx.x;         // column
  int h0 = chunk * 32;
  const float* i0 = img + (size_t)(b*3 + 0) * 65536;
  const float* i1 = i0 + 65536;
  const float* i2 = i1 + 65536;
  const float* mk = sem + (size_t)(b*8 + s) * 65536;
  __shared__ int rflags[32];
  if (w < 32) rflags[w] = 0;
  __syncthreads();
  int lane = w & 63;
  int myflag = 0;
  #pragma unroll 4
  for (int r = 0; r < 32; r++){
    int off = (h0 + r)*256 + w;
    float v = (i0[off] + i1[off] + i2[off]) * mk[off];
    int nz = (v != 0.f);
    myflag |= nz;
    unsigned long long bal = __ballot(nz);
    if (lane == 0 && bal) rflags[r] = 1;
  }
  __syncthreads();
  int bs = b*8 + s;
  colpart[(bs*8 + chunk)*256 + w] = myflag;
  if (w < 32) rowflag[bs*256 + h0 + w] = rflags[w];
}

__global__ __launch_bounds__(256) void bbox_stage2(const int* __restrict__ colpart,
                                                   const int* __restrict__ rowflag,
                                                   int* __restrict__ bbox){
  int bs = blockIdx.x;
  int w = threadIdx.x;
  int colnz = 0;
  #pragma unroll
  for (int c = 0; c < 8; c++) colnz |= colpart[(bs*8 + c)*256 + w];
  int rownz = rowflag[bs*256 + w];
  __shared__ int red[256];
  red[w] = colnz ? w : 256; __syncthreads();
  for (int st = 128; st; st >>= 1){ if (w < st) red[w] = min(red[w], red[w+st]); __syncthreads(); }
  int y0 = red[0]; __syncthreads();
  red[w] = colnz ? w : -1; __syncthreads();
  for (int st = 128; st; st >>= 1){ if (w < st) red[w] = max(red[w], red[w+st]); __syncthreads(); }
  int y1 = red[0]; __syncthreads();
  red[w] = rownz ? w : 256; __syncthreads();
  for (int st = 128; st; st >>= 1){ if (w < st) red[w] = min(red[w], red[w+st]); __syncthreads(); }
  int x0 = red[0]; __syncthreads();
  red[w] = rownz ? w : -1; __syncthreads();
  for (int st = 128; st; st >>= 1){ if (w < st) red[w] = max(red[w], red[w+st]); __syncthreads(); }
  int x1 = red[0];
  if (w == 0){
    int ok = (y0 < 256) && (x0 < 256);
    int base = bs * 4;
    bbox[base+0] = ok ? x0 : 0;
    bbox[base+1] = ok ? (x1 - x0 + 1) : 256;
    bbox[base+2] = ok ? y0 : 0;
    bbox[base+3] = ok ? (y1 - y0 + 1) : 256;
  }
}

__global__ void transimg_kernel(const float* __restrict__ img, const float* __restrict__ sem,
                                const int* __restrict__ bbox, float* __restrict__ out){
  int idx = blockIdx.x * 256 + threadIdx.x;
  int j = idx & 255;
  int i = (idx >> 8) & 255;
  int c = idx >> 16;
  int b = c / 24, ch24 = c % 24;
  int s = ch24 / 3, ch = ch24 % 3;
  const int* bb = bbox + (b*8 + s) * 4;
  int ri = bb[0] + ((i * bb[1]) >> 8);
  int cj = bb[2] + ((j * bb[3]) >> 8);
  float m = sem[((size_t)(b*8 + s) * 256 + ri) * 256 + cj];
  float v = img[((size_t)(b*3 + ch) * 256 + ri) * 256 + cj];
  out[idx] = v * m;
}

// =================== stencil-tiled grouped 3x3 conv (conv1, stride 2) ===================
template<int CIN_G, int CIN_CHUNK, int COUT_G, int OCC, int RELU_IN>
__global__ __launch_bounds__(256) void conv3x3_tile(const float* __restrict__ in,
                                                    const float* __restrict__ wt,
                                                    float* __restrict__ out,
                                                    int Hin, int Hout){
  constexpr int TIH = 65, TIW = 65, RS = 66;
  constexpr int NOC = COUT_G / OCC;
  constexpr int NSTAGE = CIN_G / CIN_CHUNK;
  __shared__ float xs[CIN_CHUNK][TIH][RS];
  __shared__ float wsh[OCC][CIN_CHUNK*9];
  int tid = threadIdx.x;
  int g = blockIdx.y, b = blockIdx.z;
  int ocChunk = blockIdx.x % NOC;
  int tileId  = blockIdx.x / NOC;
  int tilesX = Hout >> 5;
  int tileX = tileId % tilesX, tileY = tileId / tilesX;
  int oh0 = tileY*32, ow0 = tileX*32;
  int ih0 = oh0*2 - 1, iw0 = ow0*2 - 1;
  int sx = tid & 15, sy = tid >> 4;
  const int Cin_tot = CIN_G*8;

  float acc[OCC][2][2];
  #pragma unroll
  for (int o = 0; o < OCC; o++)
    #pragma unroll
    for (int i2 = 0; i2 < 2; i2++)
      #pragma unroll
      for (int j2 = 0; j2 < 2; j2++) acc[o][i2][j2] = 0.f;

  for (int st = 0; st < NSTAGE; st++){
    int icb = st*CIN_CHUNK;
    for (int i = tid; i < CIN_CHUNK*TIH*TIW; i += 256){
      int ic = i / (TIH*TIW);
      int rem = i - ic*(TIH*TIW);
      int r = rem / TIW, c = rem - r*TIW;
      int ih = ih0 + r, iw = iw0 + c;
      float v = 0.f;
      if ((unsigned)ih < (unsigned)Hin && (unsigned)iw < (unsigned)Hin){
        v = in[((size_t)(b*Cin_tot + g*CIN_G + icb + ic)*Hin + ih)*Hin + iw];
        if (RELU_IN) v = (v >= 0.f) ? v : 0.2f*v;
      }
      xs[ic][r][c] = v;
    }
    for (int i = tid; i < OCC*CIN_CHUNK*9; i += 256){
      int o = i / (CIN_CHUNK*9);
      int rr = i - o*(CIN_CHUNK*9);
      int ic = rr / 9, tap = rr - ic*9;
      wsh[o][rr] = wt[((size_t)(g*COUT_G + ocChunk*OCC + o)*CIN_G + icb + ic)*9 + tap];
    }
    __syncthreads();
    #pragma unroll
    for (int ic = 0; ic < CIN_CHUNK; ic++){
      #pragma unroll
      for (int kh = 0; kh < 3; kh++){
        #pragma unroll
        for (int kw = 0; kw < 3; kw++){
          float wv[OCC];
          #pragma unroll
          for (int o = 0; o < OCC; o++) wv[o] = wsh[o][ic*9 + kh*3 + kw];
          #pragma unroll
          for (int i2 = 0; i2 < 2; i2++){
            #pragma unroll
            for (int j2 = 0; j2 < 2; j2++){
              float x = xs[ic][2*(sy + 16*i2) + kh][2*(sx + 16*j2) + kw];
              #pragma unroll
              for (int o = 0; o < OCC; o++) acc[o][i2][j2] += wv[o]*x;
            }
          }
        }
      }
    }
    if (st + 1 < NSTAGE) __syncthreads();
  }

  #pragma unroll
  for (int o = 0; o < OCC; o++){
    int oc = g*COUT_G + ocChunk*OCC + o;
    #pragma unroll
    for (int i2 = 0; i2 < 2; i2++)
      #pragma unroll
      for (int j2 = 0; j2 < 2; j2++){
        int oh = oh0 + sy + 16*i2, ow = ow0 + sx + 16*j2;
        out[((size_t)(b*COUT_G*8 + oc)*Hout + oh)*Hout + ow] = acc[o][i2][j2];
      }
  }
}

// =================== im2col-GEMM grouped 3x3 conv (conv4, fp32) ===================
template<int STRIDE, int CIN_G, int COUT_G, int HSH>
__global__ __launch_bounds__(256) void conv3x3_gemm(const float* __restrict__ in,
                                                    const float* __restrict__ wt,
                                                    float* __restrict__ out,
                                                    int Hin){
  constexpr int K = CIN_G*9;
  const int Hout = 1 << HSH;
  int z = blockIdx.z; int b = z >> 3, g = z & 7;
  int n0 = blockIdx.x * 64, oc0 = blockIdx.y * 64;
  __shared__ float Ws[16][68];
  __shared__ float Xs[16][68];
  int tid = threadIdx.x;
  int tx = tid & 15, ty = tid >> 4;
  int pixl = tid & 63;
  int kkb = (tid >> 6) << 2;
  float acc[4][4];
  #pragma unroll
  for (int i = 0; i < 4; i++)
    #pragma unroll
    for (int j = 0; j < 4; j++) acc[i][j] = 0.f;

  for (int k0 = 0; k0 < K; k0 += 16){
    #pragma unroll
    for (int r = 0; r < 4; r++){
      int oc_l = (tid >> 4) + 16*r;
      int kk = tid & 15;
      Ws[kk][oc_l] = wt[((size_t)(g*COUT_G + oc0 + oc_l))*K + k0 + kk];
    }
    #pragma unroll
    for (int r = 0; r < 4; r++){
      int kk = kkb + r;
      int k = k0 + kk;
      int ic = k / 9, tap = k - ic*9;
      int dh = tap / 3, dw = tap - dh*3;
      int n = n0 + pixl;
      int oh = n >> HSH, ow = n & (Hout - 1);
      int ih = oh*STRIDE - 1 + dh, iw = ow*STRIDE - 1 + dw;
      float v = 0.f;
      if ((unsigned)ih < (unsigned)Hin && (unsigned)iw < (unsigned)Hin){
        v = in[((size_t)(b*CIN_G*8 + g*CIN_G + ic)*Hin + ih)*Hin + iw];
        v = (v >= 0.f) ? v : 0.2f*v;
      }
      Xs[kk][pixl] = v;
    }
    __syncthreads();
    #pragma unroll
    for (int kk = 0; kk < 16; kk++){
      float4 wv = *(const float4*)&Ws[kk][ty*4];
      float4 xv = *(const float4*)&Xs[kk][tx*4];
      acc[0][0] += wv.x*xv.x; acc[0][1] += wv.x*xv.y; acc[0][2] += wv.x*xv.z; acc[0][3] += wv.x*xv.w;
      acc[1][0] += wv.y*xv.x; acc[1][1] += wv.y*xv.y; acc[1][2] += wv.y*xv.z; acc[1][3] += wv.y*xv.w;
      acc[2][0] += wv.z*xv.x; acc[2][1] += wv.z*xv.y; acc[2][2] += wv.z*xv.z; acc[2][3] += wv.z*xv.w;
      acc[3][0] += wv.w*xv.x; acc[3][1] += wv.w*xv.y; acc[3][2] += wv.w*xv.z; acc[3][3] += wv.w*xv.w;
    }
    __syncthreads();
  }

  #pragma unroll
  for (int i = 0; i < 4; i++){
    int oc = g*COUT_G + oc0 + ty*4 + i;
    #pragma unroll
    for (int j = 0; j < 4; j++){
      int n = n0 + tx*4 + j;
      int oh = n >> HSH, ow = n & (Hout - 1);
      out[((size_t)(b*COUT_G*8 + oc)*Hout + oh)*Hout + ow] = acc[i][j];
    }
  }
}

// =================== instance norm (float4-vectorized when N allows) ===================
__global__ void inorm_kernel(const float* __restrict__ in, float* __restrict__ out,
                             int N, int relu_out){
  int bc = blockIdx.x;
  const float* p = in + (size_t)bc * N;
  float* q = out + (size_t)bc * N;
  float s = 0.f, ss = 0.f;
  bool vec = ((N & 3) == 0) && (N >= (int)blockDim.x * 4);
  if (vec){
    for (int i = threadIdx.x*4; i < N; i += blockDim.x*4){
      float4 x = *(const float4*)(p + i);
      s += x.x + x.y + x.z + x.w;
      ss += x.x*x.x + x.y*x.y + x.z*x.z + x.w*x.w;
    }
  } else {
    for (int i = threadIdx.x; i < N; i += blockDim.x){ float x = p[i]; s += x; ss += x*x; }
  }
  __shared__ float sb[8];
  int lane = threadIdx.x & 63, wid = threadIdx.x >> 6;
  for (int o = 32; o; o >>= 1){ s += __shfl_down(s, o, 64); ss += __shfl_down(ss, o, 64); }
  if (lane == 0){ sb[wid] = s; sb[4 + wid] = ss; }
  __syncthreads();
  if (threadIdx.x == 0){
    int nw = blockDim.x >> 6;
    float S = 0.f, SS = 0.f;
    for (int i = 0; i < nw; i++){ S += sb[i]; SS += sb[4+i]; }
    float mean = S / N;
    float var = SS / N - mean*mean;
    sb[0] = mean;
    sb[4] = rsqrtf(var + 1e-5f);
  }
  __syncthreads();
  float mean = sb[0], r = sb[4];
  if (vec){
    for (int i = threadIdx.x*4; i < N; i += blockDim.x*4){
      float4 x = *(const float4*)(p + i);
      x.x = (x.x - mean) * r; x.y = (x.y - mean) * r;
      x.z = (x.z - mean) * r; x.w = (x.w - mean) * r;
      if (relu_out){
        x.x = (x.x >= 0.f) ? x.x : 0.2f*x.x;
        x.y = (x.y >= 0.f) ? x.y : 0.2f*x.y;
        x.z = (x.z >= 0.f) ? x.z : 0.2f*x.z;
        x.w = (x.w >= 0.f) ? x.w : 0.2f*x.w;
      }
      *(float4*)(q + i) = x;
    }
  } else {
    for (int i = threadIdx.x; i < N; i += blockDim.x){
      float y = (p[i] - mean) * r;
      if (relu_out) y = (y >= 0.f) ? y : 0.2f*y;
      q[i] = y;
    }
  }
}

// instance norm over the sum of P partial buffers (K-split reduction folded in)
template<int P>
__global__ void inorm_sum(const float* __restrict__ in, float* __restrict__ out,
                          int N, size_t pstride, int relu_out){
  int bc = blockIdx.x;
  const float* p = in + (size_t)bc * N;
  float* q = out + (size_t)bc * N;
  float s = 0.f, ss = 0.f;
  for (int i = threadIdx.x; i < N; i += blockDim.x){
    float x = 0.f;
    #pragma unroll
    for (int pp = 0; pp < P; pp++) x += p[(size_t)pp*pstride + i];
    q[i] = x;                 // stash sum; normalized in second pass
    s += x; ss += x*x;
  }
  __shared__ float sb[8];
  int lane = threadIdx.x & 63, wid = threadIdx.x >> 6;
  for (int o = 32; o; o >>= 1){ s += __shfl_down(s, o, 64); ss += __shfl_down(ss, o, 64); }
  if (lane == 0){ sb[wid] = s; sb[4 + wid] = ss; }
  __syncthreads();
  if (threadIdx.x == 0){
    int nw = blockDim.x >> 6;
    float S = 0.f, SS = 0.f;
    for (int i = 0; i < nw; i++){ S += sb[i]; SS += sb[4+i]; }
    float mean = S / N;
    float var = SS / N - mean*mean;
    sb[0] = mean;
    sb[4] = rsqrtf(var + 1e-5f);
  }
  __syncthreads();
  float mean = sb[0], r = sb[4];
  for (int i = threadIdx.x; i < N; i += blockDim.x){
    float y = (q[i] - mean) * r;
    if (relu_out) y = (y >= 0.f) ? y : 0.2f*y;
    q[i] = y;
  }
}

// =================== bf16 hi/lo split helpers & conversion pre-passes ===================
__device__ __forceinline__ void split_bf16(float v, unsigned short& h, unsigned short& l){
  unsigned u = __float_as_uint(v);
  unsigned r = (u + 0x7FFFu + ((u >> 16) & 1u)) >> 16;   // RNE to bf16
  h = (unsigned short)r;
  float hf = __uint_as_float(r << 16);
  float lo = v - hf;
  unsigned u2 = __float_as_uint(lo);
  unsigned r2 = (u2 + 0x7FFFu + ((u2 >> 16) & 1u)) >> 16;
  l = (unsigned short)r2;
}

// src [8][C][HW] f32 -> dst [8][HW][3C] bf16, lrelu applied. blocks: 64ch x 64pix tiles
template<int C, int HW>
__global__ __launch_bounds__(256) void cvt_x_kernel(const float* __restrict__ src,
                                                    unsigned short* __restrict__ dst){
  __shared__ float tile[64][65];
  int b = blockIdx.z;
  int c0 = blockIdx.y * 64, p0 = blockIdx.x * 64;
  const float* sp = src + ((size_t)b*C + c0)*HW + p0;
  for (int i = threadIdx.x; i < 64*64; i += 256){
    int ch = i >> 6, px = i & 63;
    float v = sp[(size_t)ch*HW + px];
    tile[ch][px] = (v >= 0.f) ? v : 0.2f*v;
  }
  __syncthreads();
  unsigned short* dp = dst + ((size_t)b*HW + p0)*(3*C) + c0;
  for (int i = threadIdx.x; i < 64*64; i += 256){
    int px = i >> 6, ch = i & 63;
    float v = tile[ch][px];
    unsigned short h, l; split_bf16(v, h, l);
    unsigned short* row = dp + (size_t)px*(3*C);
    row[ch] = h; row[C + ch] = l; row[2*C + ch] = h;
  }
}

// wt [2048][C] f32 -> dst [2048][3C] bf16: [k]=h, [C+k]=h, [2C+k]=l   (C pow2)
template<int C>
__global__ __launch_bounds__(256) void cvt_w_kernel(const float* __restrict__ wt,
                                                    unsigned short* __restrict__ dst){
  int i = blockIdx.x * 256 + threadIdx.x;
  int oc = i / C, k = i & (C - 1);
  float v = wt[i];
  unsigned short h, l; split_bf16(v, h, l);
  unsigned short* row = dst + (size_t)oc * 3 * C;
  row[k] = h; row[C + k] = h; row[2*C + k] = l;
}

// grouped-conv weight split, K not pow2: wt [Ctot][K] -> dst [Ctot][3K]
template<int K>
__global__ __launch_bounds__(256) void cvt_w_g(const float* __restrict__ wt,
                                               unsigned short* __restrict__ dst, int total){
  int i = blockIdx.x * 256 + threadIdx.x;
  if (i >= total) return;
  int oc = i / K, k = i - oc*K;
  float v = wt[i];
  unsigned short h, l; split_bf16(v, h, l);
  unsigned short* row = dst + (size_t)oc * 3 * K;
  row[k] = h; row[K + k] = h; row[2*K + k] = l;
}

// gather-form padded weight split: dst[oc][kk] for kk<K:h, <2K:h, <3K:l, else 0
template<int K, int K3PAD>
__global__ __launch_bounds__(256) void cvt_w_pad(const float* __restrict__ wt,
                                                 unsigned short* __restrict__ dst, int total){
  int i = blockIdx.x * 256 + threadIdx.x;
  if (i >= total) return;
  int oc = i / K3PAD, kk = i - oc*K3PAD;
  unsigned short o = 0;
  if (kk < 3*K){
    int which = kk / K, k = kk - which*K;
    float v = wt[(size_t)oc*K + k];
    unsigned short h, l; split_bf16(v, h, l);
    o = (which == 2) ? l : h;
  }
  dst[i] = o;
}

// im2col + lrelu + hi/lo split: in [b][CIN_G*8][Hin][Hin] -> XT[g][b*64+pix][3K], Hout=8
template<int CIN_G, int Hin, int STRIDE>
__global__ __launch_bounds__(256) void cvt_im2col(const float* __restrict__ in,
                                                  unsigned short* __restrict__ dst){
  constexpr int K = CIN_G*9;
  constexpr int K3 = 3*K;
  int g = blockIdx.x, b = blockIdx.y, pc = blockIdx.z;   // pc: 16-pixel chunk
  const float* src = in + (size_t)(b*CIN_G*8 + g*CIN_G)*Hin*Hin;
  unsigned short* drow = dst + ((size_t)g*512 + b*64 + pc*16)*K3;
  for (int idx = threadIdx.x; idx < 16*K; idx += 256){
    int pixl = idx / K, k = idx - pixl*K;
    int ic = k / 9, tap = k - ic*9;
    int dh = tap / 3, dw = tap - dh*3;
    int gp = pc*16 + pixl;
    int oh = gp >> 3, ow = gp & 7;
    int ih = oh*STRIDE - 1 + dh, iw = ow*STRIDE - 1 + dw;
    float v = 0.f;
    if ((unsigned)ih < (unsigned)Hin && (unsigned)iw < (unsigned)Hin){
      v = src[((size_t)ic*Hin + ih)*Hin + iw];
      v = (v >= 0.f) ? v : 0.2f*v;
    }
    unsigned short h, l; split_bf16(v, h, l);
    unsigned short* row = drow + (size_t)pixl*K3;
    row[k] = h; row[K + k] = l; row[2*K + k] = h;
  }
}

// general im2col + lrelu + hi/lo split with K-pad, batch-sliced:
// in [b][CIN_G*8][Hin][Hin] -> dst[g][(b-b0)*HW + px][K3PAD];  grid (8, NB, HW/64)
template<int CIN_G, int Hin, int HOSH, int STRIDE, int K3PAD, int NB>
__global__ __launch_bounds__(256) void cvt_im2col_g(const float* __restrict__ in,
                                                    unsigned short* __restrict__ dst, int b0){
  constexpr int K = CIN_G*9;
  constexpr int Hout = 1 << HOSH;
  constexpr int HW = Hout*Hout;
  int g = blockIdx.x, bl = blockIdx.y, pc = blockIdx.z;   // pc: 64-px chunk
  int b = b0 + bl;
  const float* src = in + (size_t)(b*CIN_G*8 + g*CIN_G)*Hin*Hin;
  unsigned short* drow = dst + ((size_t)g*(NB*HW) + (size_t)bl*HW + pc*64)*K3PAD;
  for (int idx = threadIdx.x; idx < 64*K; idx += 256){
    int pixl = idx / K, k = idx - pixl*K;
    int ic = k / 9, tap = k - ic*9;
    int dh = tap / 3, dw = tap - dh*3;
    int gp = pc*64 + pixl;
    int oh = gp >> HOSH, ow = gp & (Hout - 1);
    int ih = oh*STRIDE - 1 + dh, iw = ow*STRIDE - 1 + dw;
    float v = 0.f;
    if ((unsigned)ih < (unsigned)Hin && (unsigned)iw < (unsigned)Hin){
      v = src[((size_t)ic*Hin + ih)*Hin + iw];
      v = (v >= 0.f) ? v : 0.2f*v;
    }
    unsigned short h, l; split_bf16(v, h, l);
    unsigned short* row = drow + (size_t)pixl*K3PAD;
    row[k] = h; row[K + k] = l; row[2*K + k] = h;
  }
  // zero the pad region [3K, K3PAD)
  for (int idx = threadIdx.x; idx < 64*(K3PAD - 3*K); idx += 256){
    int pixl = idx / (K3PAD - 3*K), k = idx - pixl*(K3PAD - 3*K);
    drow[(size_t)pixl*K3PAD + 3*K + k] = 0;
  }
}

// =================== 1x1 conv as bf16x2-split MFMA GEMM (128x128 tile) ===================
// XOR-swizzled LDS (write rr^sc8 / read row^cb, same involution both sides).
template<int K3, int HW, int H>
__global__ __launch_bounds__(256) void conv1x1_mfma(const unsigned short* __restrict__ XT,
                                                    const unsigned short* __restrict__ WT,
                                                    const float* __restrict__ bias,
                                                    float* __restrict__ out){
  constexpr int Wp = H + 2;
  constexpr int NKT = K3 / 64;
  __shared__ unsigned short As[8*128*8];   // [c8][row(oc)^c8][8k]
  __shared__ unsigned short Bs[8*128*8];   // [c8][row(pix)^c8][8k]
  int tid = threadIdx.x;
  int b = blockIdx.z;
  int oc0 = blockIdx.y * 128;
  int px0 = blockIdx.x * 128;
  int lane = tid & 63;
  int wv = tid >> 6;
  int wy = wv >> 1, wx = wv & 1;

  int srow = tid >> 3;       // 0..31, +32 per pass
  int sc8  = tid & 7;
  const unsigned short* Ag = WT + (size_t)(oc0 + srow)*K3 + sc8*8;
  const unsigned short* Bg = XT + ((size_t)b*HW + px0 + srow)*K3 + sc8*8;

  f32x4 acc[4][4];
  #pragma unroll
  for (int i = 0; i < 4; i++)
    #pragma unroll
    for (int j = 0; j < 4; j++) acc[i][j] = (f32x4){0.f,0.f,0.f,0.f};

  for (int kt = 0; kt < NKT; kt++){
    int k0 = kt * 64;
    #pragma unroll
    for (int q = 0; q < 4; q++){
      u32x4 av = *(const u32x4*)(Ag + (size_t)(32*q)*K3 + k0);
      u32x4 bv = *(const u32x4*)(Bg + (size_t)(32*q)*K3 + k0);
      int rr = srow + 32*q;
      *(u32x4*)&As[(sc8*128 + (rr ^ sc8))*8] = av;
      *(u32x4*)&Bs[(sc8*128 + (rr ^ sc8))*8] = bv;
    }
    __syncthreads();
    #pragma unroll
    for (int s = 0; s < 2; s++){
      int cb = s*4 + (lane >> 4);
      s16x8 af[4], bfr[4];
      #pragma unroll
      for (int mt = 0; mt < 4; mt++){
        int row = wy*64 + mt*16 + (lane & 15);
        af[mt] = *(const s16x8*)&As[(cb*128 + (row ^ cb))*8];
      }
      #pragma unroll
      for (int nt = 0; nt < 4; nt++){
        int row = wx*64 + nt*16 + (lane & 15);
        bfr[nt] = *(const s16x8*)&Bs[(cb*128 + (row ^ cb))*8];
      }
      #pragma unroll
      for (int mt = 0; mt < 4; mt++)
        #pragma unroll
        for (int nt = 0; nt < 4; nt++)
          acc[mt][nt] = __builtin_amdgcn_mfma_f32_16x16x32_bf16(af[mt], bfr[nt], acc[mt][nt], 0, 0, 0);
    }
    __syncthreads();
  }

  #pragma unroll
  for (int mt = 0; mt < 4; mt++){
    #pragma unroll
    for (int r = 0; r < 4; r++){
      int oc = oc0 + wy*64 + mt*16 + (lane >> 4)*4 + r;
      float bv2 = bias[oc];
      float* ob = out + ((size_t)b*2048 + oc)*Wp*Wp;
      #pragma unroll
      for (int nt = 0; nt < 4; nt++){
        int pix = px0 + wx*64 + nt*16 + (lane & 15);
        int ph = pix / H, pw2 = pix % H;
        float v = acc[mt][nt][r] + bv2;
        v = (v >= 0.f) ? v : 0.2f*v;
        ob[(size_t)(ph + 1)*Wp + pw2 + 1] = v;
      }
    }
  }
}

// =================== grouped 3x3 conv as bf16x2-split MFMA GEMM (conv5/conv6) ===================
// K-split across blockIdx.z; XOR-swizzled LDS (write & read use the same involution).
template<int K3, int COUT_G, int CTOT, int KSPLIT>
__global__ __launch_bounds__(256) void grouped_mfma(const unsigned short* __restrict__ XT,
                                                    const unsigned short* __restrict__ WT,
                                                    float* __restrict__ out, size_t pstride){
  constexpr int NKT = K3 / 64;
  constexpr int SPK = NKT / KSPLIT;
  __shared__ unsigned short As[8*128*8];
  __shared__ unsigned short Bs[8*128*8];
  int tid = threadIdx.x;
  int oc0 = blockIdx.y * 128;
  int g = oc0 / COUT_G;
  int px0 = blockIdx.x * 128;      // row within group's 512
  int ks = blockIdx.z;
  out += (size_t)ks * pstride;
  int lane = tid & 63;
  int wv = tid >> 6;
  int wy = wv >> 1, wx = wv & 1;

  int srow = tid >> 3;
  int sc8  = tid & 7;
  const unsigned short* Ag = WT + (size_t)(oc0 + srow)*K3 + sc8*8;
  const unsigned short* Bg = XT + ((size_t)g*512 + px0 + srow)*K3 + sc8*8;

  f32x4 acc[4][4];
  #pragma unroll
  for (int i = 0; i < 4; i++)
    #pragma unroll
    for (int j = 0; j < 4; j++) acc[i][j] = (f32x4){0.f,0.f,0.f,0.f};

  for (int kt = ks*SPK; kt < (ks+1)*SPK; kt++){
    int k0 = kt * 64;
    #pragma unroll
    for (int q = 0; q < 4; q++){
      u32x4 av = *(const u32x4*)(Ag + (size_t)(32*q)*K3 + k0);
      u32x4 bv = *(const u32x4*)(Bg + (size_t)(32*q)*K3 + k0);
      int rr = srow + 32*q;
      *(u32x4*)&As[(sc8*128 + (rr ^ sc8))*8] = av;
      *(u32x4*)&Bs[(sc8*128 + (rr ^ sc8))*8] = bv;
    }
    __syncthreads();
    #pragma unroll
    for (int s = 0; s < 2; s++){
      int cb = s*4 + (lane >> 4);
      s16x8 af[4], bfr[4];
      #pragma unroll
      for (int mt = 0; mt < 4; mt++){
        int row = wy*64 + mt*16 + (lane & 15);
        af[mt] = *(const s16x8*)&As[(cb*128 + (row ^ cb))*8];
      }
      #pragma unroll
      for (int nt = 0; nt < 4; nt++){
        int row = wx*64 + nt*16 + (lane & 15);
        bfr[nt] = *(const s16x8*)&Bs[(cb*128 + (row ^ cb))*8];
      }
      #pragma unroll
      for (int mt = 0; mt < 4; mt++)
        #pragma unroll
        for (int nt = 0; nt < 4; nt++)
          acc[mt][nt] = __builtin_amdgcn_mfma_f32_16x16x32_bf16(af[mt], bfr[nt], acc[mt][nt], 0, 0, 0);
    }
    __syncthreads();
  }

  #pragma unroll
  for (int mt = 0; mt < 4; mt++){
    #pragma unroll
    for (int r = 0; r < 4; r++){
      int oc = oc0 + wy*64 + mt*16 + (lane >> 4)*4 + r;
      #pragma unroll
      for (int nt = 0; nt < 4; nt++){
        int row = px0 + wx*64 + nt*16 + (lane & 15);
        int b = row >> 6, p = row & 63;
        out[((size_t)(b*CTOT + oc))*64 + p] = acc[mt][nt][r];
      }
    }
  }
}

// =================== small-M grouped MFMA GEMM (conv2/conv3): tile = COUT_G x 128 px ===================
// XOR-swizzled LDS on both operands; optional K-split (blockIdx.z) writing full partial buffers.
template<int K3PAD, int COUT_G, int CTOT, int HW, int NROWS, int KSPLIT>
__global__ __launch_bounds__(256) void gconv_mfma(const unsigned short* __restrict__ XT,
                                                  const unsigned short* __restrict__ WT,
                                                  float* __restrict__ out, int b0, size_t pstride){
  constexpr int NKT = K3PAD / 64;
  constexpr int SPK = NKT / KSPLIT;
  constexpr int MF = COUT_G / 16;
  __shared__ unsigned short As[8*COUT_G*8];   // [c8][oc_row][8]
  __shared__ unsigned short Bs[8*128*8];      // [c8][px_row][8]
  int tid = threadIdx.x;
  int g = blockIdx.y;
  int px0 = blockIdx.x * 128;
  int ks = blockIdx.z;
  out += (size_t)ks * pstride;
  int lane = tid & 63;
  int wv = tid >> 6;               // wave -> 32-px slice

  int srow = tid >> 3;             // 0..31
  int sc8  = tid & 7;
  const unsigned short* Agb = WT + (size_t)(g*COUT_G)*K3PAD + sc8*8;
  const unsigned short* Bg  = XT + ((size_t)g*NROWS + px0 + srow)*K3PAD + sc8*8;

  f32x4 acc[MF][2];
  #pragma unroll
  for (int i = 0; i < MF; i++)
    #pragma unroll
    for (int j = 0; j < 2; j++) acc[i][j] = (f32x4){0.f,0.f,0.f,0.f};

  for (int kt = ks*SPK; kt < (ks+1)*SPK; kt++){
    int k0 = kt * 64;
    #pragma unroll
    for (int q = 0; q < (COUT_G + 31)/32; q++){
      int rr = srow + 32*q;
      if (rr < COUT_G)
        *(u32x4*)&As[(sc8*COUT_G + (rr ^ sc8))*8] = *(const u32x4*)(Agb + (size_t)rr*K3PAD + k0);
    }
    #pragma unroll
    for (int q = 0; q < 4; q++){
      int rr = srow + 32*q;
      *(u32x4*)&Bs[(sc8*128 + (rr ^ sc8))*8] = *(const u32x4*)(Bg + (size_t)(32*q)*K3PAD + k0);
    }
    __syncthreads();
    #pragma unroll
    for (int s = 0; s < 2; s++){
      int cb = s*4 + (lane >> 4);
      s16x8 af[MF], bfr[2];
      #pragma unroll
      for (int mt = 0; mt < MF; mt++){
        int row = mt*16 + (lane & 15);
        af[mt] = *(const s16x8*)&As[(cb*COUT_G + (row ^ cb))*8];
      }
      #pragma unroll
      for (int nt = 0; nt < 2; nt++){
        int row = wv*32 + nt*16 + (lane & 15);
        bfr[nt] = *(const s16x8*)&Bs[(cb*128 + (row ^ cb))*8];
      }
      #pragma unroll
      for (int mt = 0; mt < MF; mt++)
        #pragma unroll
        for (int nt = 0; nt < 2; nt++)
          acc[mt][nt] = __builtin_amdgcn_mfma_f32_16x16x32_bf16(af[mt], bfr[nt], acc[mt][nt], 0, 0, 0);
    }
    __syncthreads();
  }

  #pragma unroll
  for (int mt = 0; mt < MF; mt++){
    #pragma unroll
    for (int r = 0; r < 4; r++){
      int oc = g*COUT_G + mt*16 + (lane >> 4)*4 + r;
      #pragma unroll
      for (int nt = 0; nt < 2; nt++){
        int rowg = px0 + wv*32 + nt*16 + (lane & 15);
        int bl = rowg / HW, px = rowg - bl*HW;
        out[((size_t)((b0 + bl)*CTOT + oc))*HW + px] = acc[mt][nt][r];
      }
    }
  }
}

// border cells only, flat indexing: 1 thread per (b, oc, perim-cell)
__global__ void border_kernel(const float* __restrict__ bias, float* __restrict__ out, int H){
  int Wp = H + 2, perim = 4*Wp - 4;
  int total = 8 * 2048 * perim;
  int idx = blockIdx.x * 256 + threadIdx.x;
  if (idx >= total) return;
  int p = idx % perim;
  int rest = idx / perim;
  int oc = rest & 2047;
  int b = rest >> 11;
  int ph, pw;
  if (p < Wp){ ph = 0; pw = p; }
  else if (p < 2*Wp){ ph = Wp - 1; pw = p - Wp; }
  else { int q = p - 2*Wp; ph = 1 + (q >> 1); pw = (q & 1) ? (Wp - 1) : 0; }
  float bv = bias[oc];
  bv = (bv >= 0.f) ? bv : 0.2f*bv;
  out[(((size_t)b*2048 + oc)*Wp + ph)*Wp + pw] = bv;
}

// =================== host: precomputed spectral-norm u vectors (seed-fixed) ===================
static float g_hu[4032];
static bool g_hu_init = false;

static void init_hu(){
  const int os[6]   = {64,128,256,512,1024,2048};
  const int uoff[6] = {0,64,192,448,960,1984};
  for (int l = 0; l < 6; l++){
    unsigned mt[624];
    unsigned seed = (unsigned)(l + 1);
    for (int i = 0; i < 624; i++){
      mt[i] = seed;
      seed = 1812433253u * (seed ^ (seed >> 30)) + (unsigned)(i + 1);
    }
    int mti = 624;
    auto next32 = [&]() -> unsigned {
      if (mti >= 624){
        for (int i = 0; i < 624; i++){
          unsigned y = (mt[i] & MT_UP) | (mt[(i+1) % 624] & MT_LO);
          mt[i] = mt[(i+397) % 624] ^ (y >> 1) ^ ((y & 1u) ? 0x9908b0dfu : 0u);
        }
        mti = 0;
      }
      unsigned y = mt[mti++];
      y ^= y >> 11; y ^= (y << 7) & 0x9d2c5680u; y ^= (y << 15) & 0xefc60000u; y ^= y >> 18;
      return y;
    };
    int n = os[l];
    float* u = g_hu + uoff[l];
    int j = 0;
    while (2*j + 1 < n + 1){          // generate n values (n even) as pairs
      if (2*j + 1 >= n) break;
      unsigned a = next32(), b = next32(), c = next32(), d = next32();
      double u1 = ((a >> 5) * 67108864.0 + (b >> 6)) / 9007199254740992.0;
      double u2 = ((c >> 5) * 67108864.0 + (d >> 6)) / 9007199254740992.0;
      double x1 = 2.0*u1 - 1.0, x2 = 2.0*u2 - 1.0;
      double r2 = x1*x1 + x2*x2;
      if (r2 < 1.0 && r2 != 0.0){
        double f = sqrt(-2.0 * log(r2) / r2);
        u[2*j]   = (float)(f * x2);
        u[2*j+1] = (float)(f * x1);
        j++;
      }
    }
  }
}

// =================== host ===================
extern "C" void kernel_launch(void* const* d_in, const int* in_sizes, int n_in,
                              void* d_out, int out_size, void* d_ws, size_t ws_size,
                              hipStream_t stream){
  const float* img = (const float*)d_in[0];
  const float* sem = (const float*)d_in[1];
  Ptr6 wp;
  for (int l = 0; l < 6; l++) wp.p[l] = (const float*)d_in[2 + l];
  const float* gw1 = (const float*)d_in[8];
  const float* gb1 = (const float*)d_in[9];
  const float* gw2 = (const float*)d_in[10];
  const float* gb2 = (const float*)d_in[11];
  float* out = (float*)d_out;
  float* ws  = (float*)d_ws;

  float* bufA = out + OUT_X2;
  float* bufB = bufA + 8388608;
  float* bufC = ws + WS_OFF_C;
  float* bufD = ws + WS_OFF_D;
  int* bbox = (int*)(ws + WS_OFF_BBOX);
  // bbox flag scratch: spare tail of OUT_X2 region (used before x_2 is written)
  int* colpart = (int*)(bufB + 8388608);          // 64*8*256 ints
  int* rowflag = colpart + 64*8*256;              // 64*256 ints

  // bf16 GEMM scratch (1x1 convs):
  unsigned short* XT2 = (unsigned short*)(out + OUT_X1);             // 8*1024*768 bf16
  unsigned short* W2  = (unsigned short*)(out + OUT_X1 + 3145728);   // 2048*768 bf16
  unsigned short* XT1 = (unsigned short*)(ws + WS_OFF_W);            // 8*256*1536 bf16
  unsigned short* W1  = (unsigned short*)(ws + WS_OFF_W + 1572864);  // 2048*1536 bf16

  // bf16 GEMM scratch (grouped convs 5/6):
  unsigned short* XT5 = (unsigned short*)(bufA + 1048576);   // 8g*512*1728 bf16
  unsigned short* W5s = (unsigned short*)(bufB);             // 1024*1728 bf16
  unsigned short* XT6 = (unsigned short*)(bufA + 1048576);   // 8g*512*3456 bf16
  unsigned short* W6s = (unsigned short*)(bufB + 1048576);   // 2048*3456 bf16

  // dead tail of OUT_X2 region (past bufB; 2.16M floats, dead after bbox_stage2):
  unsigned short* W3s = (unsigned short*)(bufB + 8388608);              // 256*448 bf16 = 57,344 floats
  unsigned short* W2s = (unsigned short*)(bufB + 8388608 + 57344);      // 128*256 bf16 = 16,384 floats

  // conv2/conv3 X + raw-out scratch:
  unsigned short* X2i = (unsigned short*)bufA;               // 8g*8192*256 bf16 = 8.39M floats
  float* out2raw = out + OUT_X1;                             // 8*128*4096 = 4.19M floats
  unsigned short* X3i = (unsigned short*)bufA;               // 8g*4096*448 bf16 = 7.34M floats/slice
  float* out3raw = out + OUT_X1;                             // 8*256*1024 = 2.1M floats

  static const int kWOff[6]  = {0,1728,10944,47808,195264,785088};

  if (!g_hu_init){ init_hu(); g_hu_init = true; }

  hipMemsetAsync(ws + WS_OFF_T, 0, (WS_OFF_S2 + 8 - WS_OFF_T) * sizeof(float), stream);
  hipMemcpyAsync(ws + WS_OFF_U, g_hu, 4032 * sizeof(float), hipMemcpyHostToDevice, stream);

  sn_t_kernel<<<252, 256, 0, stream>>>(wp, ws);
  sn_tn_kernel<<<6, 256, 0, stream>>>(ws);
  sn_z_kernel<<<1008, 256, 0, stream>>>(wp, ws);
  wscale_all<<<(3144384 + 255)/256, 256, 0, stream>>>(wp, ws);

  bbox_stage1<<<dim3(8,8,8), 256, 0, stream>>>(img, sem, colpart, rowflag);
  bbox_stage2<<<64, 256, 0, stream>>>(colpart, rowflag, bbox);
  transimg_kernel<<<49152, 256, 0, stream>>>(img, sem, bbox, out + OUT_IMG);

  // conv1: images(8,24,256,256) -> (8,64,128,128)   [stencil tile, single-stage]
  conv3x3_tile<3,3,8,8,0><<<dim3(16,8,8), 256, 0, stream>>>(out + OUT_IMG, ws + WS_OFF_W + kWOff[0],
                                                            bufA, 256, 128);
  inorm_kernel<<<512, 256, 0, stream>>>(bufA, bufB, 16384, 0);

  // conv2 -> (8,128,64,64)   [bf16-split MFMA, 4 slices of 2 batches]
  cvt_w_pad<72,256><<<(128*256+255)/256, 256, 0, stream>>>(ws + WS_OFF_W + kWOff[1], W2s, 128*256);
  for (int s = 0; s < 4; s++){
    cvt_im2col_g<8,128,6,2,256,2><<<dim3(8,2,64), 256, 0, stream>>>(bufB, X2i, 2*s);
    gconv_mfma<256,16,128,4096,8192,1><<<dim3(64,8), 256, 0, stream>>>(X2i, W2s, out2raw, 2*s, 0);
  }
  inorm_kernel<<<1024, 256, 0, stream>>>(out2raw, bufB, 4096, 0);

  // conv3 -> out_8 (8,256,32,32)   [bf16-split MFMA, 2 slices of 4 batches]
  cvt_w_pad<144,448><<<(256*448+255)/256, 256, 0, stream>>>(ws + WS_OFF_W + kWOff[2], W3s, 256*448);
  for (int s = 0; s < 2; s++){
    cvt_im2col_g<16,64,5,2,448,4><<<dim3(8,4,16), 256, 0, stream>>>(bufB, X3i, 4*s);
    gconv_mfma<448,32,256,1024,4096,1><<<dim3(32,8), 256, 0, stream>>>(X3i, W3s, out3raw, 4*s, 0);
  }
  inorm_kernel<<<2048, 256, 0, stream>>>(out3raw, bufC, 1024, 0);

  // conv4 -> out_16 (8,512,16,16)   [im2col gemm, fp32]
  conv3x3_gemm<2,32,64,4><<<dim3(4,1,64), 256, 0, stream>>>(bufC, ws + WS_OFF_W + kWOff[3], bufA, 32);
  inorm_kernel<<<4096, 256, 0, stream>>>(bufA, bufD, 256, 0);

  // conv5 -> out_32 (8,1024,8,8)   [bf16-split MFMA, K-split x3 -> 96 blocks]
  cvt_im2col<64,16,2><<<dim3(8,8,4), 256, 0, stream>>>(bufD, XT5);
  cvt_w_g<576><<<2304, 256, 0, stream>>>(ws + WS_OFF_W + kWOff[4], W5s, 589824);
  grouped_mfma<1728,128,1024,3><<<dim3(4,8,3), 256, 0, stream>>>(XT5, W5s, out + OUT_X1, 524288);
  inorm_sum<3><<<8192, 64, 0, stream>>>(out + OUT_X1, bufB, 64, 524288, 0);

  // conv6 -> (8,2048,8,8), stride 1   [bf16-split MFMA, K-split x6 -> 384 blocks]
  cvt_im2col<128,8,1><<<dim3(8,8,4), 256, 0, stream>>>(bufB, XT6);
  cvt_w_g<1152><<<9216, 256, 0, stream>>>(ws + WS_OFF_W + kWOff[5], W6s, 2359296);
  grouped_mfma<3456,256,2048,6><<<dim3(4,16,6), 256, 0, stream>>>(XT6, W6s, out, 1048576);
  inorm_sum<6><<<16384, 64, 0, stream>>>(out, out + OUT_X, 64, 1048576, 1);   // x

  // ---- bf16x2-split conversions for 1x1 convs (spectral weights + bufA/bufB now dead) ----
  cvt_x_kernel<256,1024><<<dim3(16,4,8), 256, 0, stream>>>(bufC, XT2);   // reads bufC first
  cvt_w_kernel<256><<<2048, 256, 0, stream>>>(gw2, W2);
  cvt_x_kernel<512,256><<<dim3(4,8,8), 256, 0, stream>>>(bufD, XT1);
  cvt_w_kernel<512><<<4096, 256, 0, stream>>>(gw1, W1);                  // may touch bufC head (dead now)

  // x_2 -> (8,2048,34,34): reads OUT_X1-region scratch, writes OUT_X2
  border_kernel<<<(8*2048*132 + 255)/256, 256, 0, stream>>>(gb2, out + OUT_X2, 32);
  conv1x1_mfma<768,1024,32><<<dim3(8,16,8), 256, 0, stream>>>(XT2, W2, gb2, out + OUT_X2);
  // x_1 -> (8,2048,18,18): reads ws scratch, overwrites OUT_X1 (XT2/W2 dead)
  border_kernel<<<(8*2048*68 + 255)/256, 256, 0, stream>>>(gb1, out + OUT_X1, 16);
  conv1x1_mfma<1536,256,16><<<dim3(2,16,8), 256, 0, stream>>>(XT1, W1, gb1, out + OUT_X1);
}